// Round 1
// baseline (348.381 us; speedup 1.0000x reference)
//
#include <hip/hip_runtime.h>
#include <math.h>

// ---------- types ----------
typedef __bf16 bf16x8 __attribute__((ext_vector_type(8)));   // MFMA A/B fragment (4 VGPRs)
typedef float  f32x4  __attribute__((ext_vector_type(4)));   // MFMA C/D fragment
typedef short  s16x8  __attribute__((ext_vector_type(8)));   // raw 16B data movement

__device__ __forceinline__ unsigned short f2bf(float f) {
    unsigned int u = __float_as_uint(f);
    u += 0x7fffu + ((u >> 16) & 1u);   // round-to-nearest-even
    return (unsigned short)(u >> 16);
}

__device__ __forceinline__ float gelu_tanh(float x) {
    float x3 = x * x * x;
    float t = tanhf(0.7978845608028654f * (x + 0.044715f * x3));
    return 0.5f * x * (1.0f + t);
}

// ---------- transpose + f32->bf16 convert:  in[K][N] f32  ->  out[N][K] bf16 ----------
__global__ __launch_bounds__(256) void tcvt_kernel(const float* __restrict__ in,
                                                   unsigned short* __restrict__ out,
                                                   int K, int N) {
    __shared__ float tile[32][33];
    int tx = threadIdx.x, ty = threadIdx.y;           // 32 x 8
    int k0 = blockIdx.y * 32, n0 = blockIdx.x * 32;
#pragma unroll
    for (int s = 0; s < 4; ++s)
        tile[ty + s * 8][tx] = in[(size_t)(k0 + ty + s * 8) * N + n0 + tx];
    __syncthreads();
#pragma unroll
    for (int s = 0; s < 4; ++s)
        out[(size_t)(n0 + ty + s * 8) * K + k0 + tx] = f2bf(tile[tx][ty + s * 8]);
}

// ---------- layernorm: x[L][1024] f32 -> out bf16 ----------
__global__ __launch_bounds__(256) void ln_kernel(const float* __restrict__ x,
                                                 const float* __restrict__ g,
                                                 const float* __restrict__ b,
                                                 unsigned short* __restrict__ out) {
    int row = blockIdx.x;
    int tid = threadIdx.x;
    float4 v = ((const float4*)(x + (size_t)row * 1024))[tid];
    float s  = v.x + v.y + v.z + v.w;
    float ss = v.x * v.x + v.y * v.y + v.z * v.z + v.w * v.w;
#pragma unroll
    for (int o = 32; o > 0; o >>= 1) { s += __shfl_down(s, o); ss += __shfl_down(ss, o); }
    __shared__ float red[8];
    if ((tid & 63) == 0) { red[(tid >> 6) * 2] = s; red[(tid >> 6) * 2 + 1] = ss; }
    __syncthreads();
    s  = red[0] + red[2] + red[4] + red[6];
    ss = red[1] + red[3] + red[5] + red[7];
    float mean = s * (1.0f / 1024.0f);
    float var  = ss * (1.0f / 1024.0f) - mean * mean;
    float rs   = rsqrtf(var + 1e-5f);
    float4 gv = ((const float4*)g)[tid];
    float4 bv = ((const float4*)b)[tid];
    ushort4 o4;
    o4.x = f2bf((v.x - mean) * rs * gv.x + bv.x);
    o4.y = f2bf((v.y - mean) * rs * gv.y + bv.y);
    o4.z = f2bf((v.z - mean) * rs * gv.z + bv.z);
    o4.w = f2bf((v.w - mean) * rs * gv.w + bv.w);
    ((ushort4*)(out + (size_t)row * 1024))[tid] = o4;
}

// ---------- transpose V (bf16): qkv v-part [L=4096][ld 3072, off 2048] -> vt[1024][4096] ----------
__global__ __launch_bounds__(256) void tvt_kernel(const unsigned short* __restrict__ in,
                                                  unsigned short* __restrict__ out) {
    __shared__ unsigned short tile[64][72];
    int t = threadIdx.x;
    int l0 = blockIdx.x * 64, c0 = blockIdx.y * 64;
    int tr = t >> 3, tc = (t & 7) * 8;
#pragma unroll
    for (int s = 0; s < 2; ++s) {
        int r = tr + s * 32;
        s16x8 v = *(const s16x8*)(in + (size_t)(l0 + r) * 3072 + 2048 + c0 + tc);
        *(s16x8*)(&tile[r][tc]) = v;
    }
    __syncthreads();
#pragma unroll
    for (int s = 0; s < 2; ++s) {
        int c = tr + s * 32;
        s16x8 w;
#pragma unroll
        for (int e = 0; e < 8; ++e) w[e] = (short)tile[tc + e][c];
        *(s16x8*)(out + (size_t)(c0 + c) * 4096 + l0 + tc) = w;
    }
}

// ---------- GEMM: C[M][N] = A[M][K](bf16) * Bt[N][K](bf16)^T  + epilogue ----------
// EPI 0: store bf16
// EPI 1: store f32, += resid (f32 MxN)
// EPI 2: += bias[col], gelu, store bf16
// EPI 3: += bias[col] + resid, store f32
#define BM 128
#define BN 128
#define BKK 64

template <int EPI>
__global__ __launch_bounds__(256) void gemm_kernel(const unsigned short* __restrict__ A,
                                                   const unsigned short* __restrict__ Bt,
                                                   void* __restrict__ C,
                                                   const float* __restrict__ bias,
                                                   const float* __restrict__ resid,
                                                   int M, int N, int K) {
    __shared__ __align__(16) unsigned short sA[BM * BKK];
    __shared__ __align__(16) unsigned short sB[BN * BKK];

    const int tid  = threadIdx.x;
    const int wv   = tid >> 6;
    const int lane = tid & 63;
    const int wr   = wv >> 1, wc = wv & 1;
    const int lg   = lane >> 4;      // k-group 0..3
    const int l15  = lane & 15;

    const int brow = blockIdx.y * BM;
    const int bcol = blockIdx.x * BN;

    f32x4 acc[4][4] = {};

    const int l8 = lane >> 3;          // row within 8-row chunk
    const int lc = (lane & 7) * 8;     // col element

    for (int kt = 0; kt < K; kt += BKK) {
        __syncthreads();
#pragma unroll
        for (int q = 0; q < 4; ++q) {
            int ch = 4 * wv + q;
            const unsigned short* srcA = A + (size_t)(brow + 8 * ch + l8) * K + kt + lc;
            __builtin_amdgcn_global_load_lds((const __attribute__((address_space(1))) void*)srcA,
                                             (__attribute__((address_space(3))) void*)(sA + ch * 512),
                                             16, 0, 0);
        }
#pragma unroll
        for (int q = 0; q < 4; ++q) {
            int ch = 4 * wv + q;
            const unsigned short* srcB = Bt + (size_t)(bcol + 8 * ch + l8) * K + kt + lc;
            __builtin_amdgcn_global_load_lds((const __attribute__((address_space(1))) void*)srcB,
                                             (__attribute__((address_space(3))) void*)(sB + ch * 512),
                                             16, 0, 0);
        }
        __syncthreads();

        bf16x8 af[4][2], bfr[4][2];
#pragma unroll
        for (int mi = 0; mi < 4; ++mi)
#pragma unroll
            for (int kk = 0; kk < 2; ++kk)
                af[mi][kk] = *(const bf16x8*)(sA + (wr * 64 + mi * 16 + l15) * BKK + lg * 8 + kk * 32);
#pragma unroll
        for (int ni = 0; ni < 4; ++ni)
#pragma unroll
            for (int kk = 0; kk < 2; ++kk)
                bfr[ni][kk] = *(const bf16x8*)(sB + (wc * 64 + ni * 16 + l15) * BKK + lg * 8 + kk * 32);

#pragma unroll
        for (int kk = 0; kk < 2; ++kk)
#pragma unroll
            for (int mi = 0; mi < 4; ++mi)
#pragma unroll
                for (int ni = 0; ni < 4; ++ni)
                    acc[mi][ni] = __builtin_amdgcn_mfma_f32_16x16x32_bf16(af[mi][kk], bfr[ni][kk],
                                                                          acc[mi][ni], 0, 0, 0);
    }

#pragma unroll
    for (int mi = 0; mi < 4; ++mi)
#pragma unroll
        for (int ni = 0; ni < 4; ++ni)
#pragma unroll
            for (int r = 0; r < 4; ++r) {
                int row = brow + wr * 64 + mi * 16 + lg * 4 + r;
                int col = bcol + wc * 64 + ni * 16 + l15;
                size_t idx = (size_t)row * N + col;
                float v = acc[mi][ni][r];
                if (EPI == 0) {
                    ((unsigned short*)C)[idx] = f2bf(v);
                } else if (EPI == 1) {
                    ((float*)C)[idx] = v + resid[idx];
                } else if (EPI == 2) {
                    v += bias[col];
                    ((unsigned short*)C)[idx] = f2bf(gelu_tanh(v));
                } else {
                    ((float*)C)[idx] = v + bias[col] + resid[idx];
                }
            }
}

// ---------- band attention ----------
// grid (NB=64, H=16), 256 threads (4 waves). Each wave owns 16 query rows.
__global__ __launch_bounds__(256) void attn_kernel(const unsigned short* __restrict__ qkv, // [4096][3072]
                                                   const unsigned short* __restrict__ vt,  // [1024][4096]
                                                   const float* __restrict__ rel_emb,      // [258][16]
                                                   unsigned short* __restrict__ outp) {    // [4096][1024]
    const int n = blockIdx.x;
    const int h = blockIdx.y;
    const int tid  = threadIdx.x;
    const int wv   = tid >> 6;
    const int lane = tid & 63;
    const int lg   = lane >> 4;
    const int l15  = lane & 15;

    __shared__ __align__(16) unsigned short sQ[64 * 72];
    __shared__ __align__(16) unsigned short sK[64 * 72];
    __shared__ __align__(16) unsigned short sV[64 * 72];   // V^T tile: [d][j]
    __shared__ __align__(16) unsigned short sP[64 * 72];
    __shared__ float sRel[258];

    for (int i = tid; i < 258; i += 256) sRel[i] = rel_emb[i * 16 + h];

    // stage Q tile [64 rows][64 d]
    {
        int tr = tid >> 3, tc = (tid & 7) * 8;
#pragma unroll
        for (int s = 0; s < 2; ++s) {
            int r = tr + s * 32;
            s16x8 v = *(const s16x8*)(qkv + (size_t)(n * 64 + r) * 3072 + h * 64 + tc);
            *(s16x8*)(&sQ[r * 72 + tc]) = v;
        }
    }
    __syncthreads();

    bf16x8 qf[2];
#pragma unroll
    for (int kk = 0; kk < 2; ++kk)
        qf[kk] = *(const bf16x8*)(sQ + (wv * 16 + l15) * 72 + lg * 8 + kk * 32);

    f32x4 oacc[4] = {};
    float mrow[4] = {-1e30f, -1e30f, -1e30f, -1e30f};
    float lrow[4] = {0.f, 0.f, 0.f, 0.f};

    const int w0 = (n >= 15) ? 0 : (15 - n);
    for (int w = w0; w < 16; ++w) {
        const int src = n - 15 + w;
        __syncthreads();   // previous iteration's K/V reads done
        {
            int tr = tid >> 3, tc = (tid & 7) * 8;
#pragma unroll
            for (int s = 0; s < 2; ++s) {
                int r = tr + s * 32;
                s16x8 kv = *(const s16x8*)(qkv + (size_t)(src * 64 + r) * 3072 + 1024 + h * 64 + tc);
                *(s16x8*)(&sK[r * 72 + tc]) = kv;
                s16x8 vv = *(const s16x8*)(vt + (size_t)(h * 64 + r) * 4096 + src * 64 + tc);
                *(s16x8*)(&sV[r * 72 + tc]) = vv;
            }
        }
        __syncthreads();

        // S = Q K^T   (wave's 16 rows x 64 cols)
        f32x4 s[4] = {};
#pragma unroll
        for (int t = 0; t < 4; ++t)
#pragma unroll
            for (int kk = 0; kk < 2; ++kk) {
                bf16x8 kf = *(const bf16x8*)(sK + (t * 16 + l15) * 72 + lg * 8 + kk * 32);
                s[t] = __builtin_amdgcn_mfma_f32_16x16x32_bf16(qf[kk], kf, s[t], 0, 0, 0);
            }

        // bias + mask, online softmax
        float pmax[4] = {-1e30f, -1e30f, -1e30f, -1e30f};
#pragma unroll
        for (int t = 0; t < 4; ++t)
#pragma unroll
            for (int r = 0; r < 4; ++r) {
                int i = wv * 16 + lg * 4 + r;
                int j = t * 16 + l15;
                float val;
                if (w < 15 || j <= i) {
                    int delta = (15 - w) * 64 + i - j;
                    int relid = min(delta, 256) + 1;
                    val = s[t][r] * 0.125f + sRel[relid];
                } else {
                    val = -1e30f;
                }
                s[t][r] = val;
                pmax[r] = fmaxf(pmax[r], val);
            }
#pragma unroll
        for (int r = 0; r < 4; ++r) {
#pragma unroll
            for (int m = 1; m < 16; m <<= 1) pmax[r] = fmaxf(pmax[r], __shfl_xor(pmax[r], m));
        }

        float scl[4], mnew[4];
#pragma unroll
        for (int r = 0; r < 4; ++r) {
            mnew[r] = fmaxf(mrow[r], pmax[r]);
            scl[r]  = __expf(mrow[r] - mnew[r]);
            mrow[r] = mnew[r];
        }

        float rsum[4] = {0.f, 0.f, 0.f, 0.f};
#pragma unroll
        for (int t = 0; t < 4; ++t)
#pragma unroll
            for (int r = 0; r < 4; ++r) {
                float p = __expf(s[t][r] - mnew[r]);
                rsum[r] += p;
                sP[(wv * 16 + lg * 4 + r) * 72 + t * 16 + l15] = f2bf(p);
            }
#pragma unroll
        for (int r = 0; r < 4; ++r) {
#pragma unroll
            for (int m = 1; m < 16; m <<= 1) rsum[r] += __shfl_xor(rsum[r], m);
            lrow[r] = lrow[r] * scl[r] + rsum[r];
        }
#pragma unroll
        for (int t = 0; t < 4; ++t)
#pragma unroll
            for (int r = 0; r < 4; ++r) oacc[t][r] *= scl[r];

        __syncthreads();   // P writes visible (also orders vs staging)

        // O += P V
#pragma unroll
        for (int kk = 0; kk < 2; ++kk) {
            bf16x8 pf = *(const bf16x8*)(sP + (wv * 16 + l15) * 72 + lg * 8 + kk * 32);
#pragma unroll
            for (int t = 0; t < 4; ++t) {
                bf16x8 vf = *(const bf16x8*)(sV + (t * 16 + l15) * 72 + lg * 8 + kk * 32);
                oacc[t] = __builtin_amdgcn_mfma_f32_16x16x32_bf16(pf, vf, oacc[t], 0, 0, 0);
            }
        }
    }

#pragma unroll
    for (int t = 0; t < 4; ++t)
#pragma unroll
        for (int r = 0; r < 4; ++r) {
            float inv = 1.0f / lrow[r];
            size_t idx = (size_t)(n * 64 + wv * 16 + lg * 4 + r) * 1024 + h * 64 + t * 16 + l15;
            outp[idx] = f2bf(oacc[t][r] * inv);
        }
}

// ---------- launch ----------
extern "C" void kernel_launch(void* const* d_in, const int* in_sizes, int n_in,
                              void* d_out, int out_size, void* d_ws, size_t ws_size,
                              hipStream_t stream) {
    const float* x    = (const float*)d_in[0];
    const float* Wq   = (const float*)d_in[1];
    const float* Wk   = (const float*)d_in[2];
    const float* Wv   = (const float*)d_in[3];
    const float* Wo   = (const float*)d_in[4];
    const float* rel  = (const float*)d_in[5];
    const float* ln1g = (const float*)d_in[6];
    const float* ln1b = (const float*)d_in[7];
    const float* ln2g = (const float*)d_in[8];
    const float* ln2b = (const float*)d_in[9];
    const float* W1   = (const float*)d_in[10];
    const float* b1   = (const float*)d_in[11];
    const float* W2   = (const float*)d_in[12];
    const float* b2   = (const float*)d_in[13];

    char* ws = (char*)d_ws;
    unsigned short* wqkvT = (unsigned short*)(ws + 0);          //  6 MB (WqT,WkT,WvT)
    unsigned short* woT   = (unsigned short*)(ws + 6291456);    //  2 MB
    unsigned short* w1T   = (unsigned short*)(ws + 8388608);    //  8 MB
    unsigned short* w2T   = (unsigned short*)(ws + 16777216);   //  8 MB
    float*          x2    = (float*)(ws + 25165824);            // 16 MB
    unsigned short* hbuf  = (unsigned short*)(ws + 41943040);   //  8 MB (h, later h2)
    unsigned short* qkv   = (unsigned short*)(ws + 50331648);   // 24 MB
    unsigned short* vt    = (unsigned short*)(ws + 75497472);   //  8 MB
    unsigned short* attn  = (unsigned short*)(ws + 83886080);   //  8 MB
    unsigned short* gbuf  = (unsigned short*)(ws + 50331648);   // 32 MB (reuses qkv+vt)

    dim3 tb(32, 8);
    tcvt_kernel<<<dim3(32, 32), tb, 0, stream>>>(Wq, wqkvT, 1024, 1024);
    tcvt_kernel<<<dim3(32, 32), tb, 0, stream>>>(Wk, wqkvT + 1048576, 1024, 1024);
    tcvt_kernel<<<dim3(32, 32), tb, 0, stream>>>(Wv, wqkvT + 2097152, 1024, 1024);
    tcvt_kernel<<<dim3(32, 32), tb, 0, stream>>>(Wo, woT, 1024, 1024);
    tcvt_kernel<<<dim3(128, 32), tb, 0, stream>>>(W1, w1T, 1024, 4096);
    tcvt_kernel<<<dim3(32, 128), tb, 0, stream>>>(W2, w2T, 4096, 1024);

    ln_kernel<<<4096, 256, 0, stream>>>(x, ln1g, ln1b, hbuf);

    gemm_kernel<0><<<dim3(3072 / 128, 4096 / 128), 256, 0, stream>>>(hbuf, wqkvT, qkv,
                                                                     nullptr, nullptr, 4096, 3072, 1024);

    tvt_kernel<<<dim3(64, 16), 256, 0, stream>>>(qkv, vt);

    attn_kernel<<<dim3(64, 16), 256, 0, stream>>>(qkv, vt, rel, attn);

    gemm_kernel<1><<<dim3(1024 / 128, 4096 / 128), 256, 0, stream>>>(attn, woT, x2,
                                                                     nullptr, x, 4096, 1024, 1024);

    ln_kernel<<<4096, 256, 0, stream>>>(x2, ln2g, ln2b, hbuf);

    gemm_kernel<2><<<dim3(4096 / 128, 4096 / 128), 256, 0, stream>>>(hbuf, w1T, gbuf,
                                                                     b1, nullptr, 4096, 4096, 1024);

    gemm_kernel<3><<<dim3(1024 / 128, 4096 / 128), 256, 0, stream>>>(gbuf, w2T, d_out,
                                                                     b2, x2, 4096, 1024, 4096);
}

// Round 2
// 275.029 us; speedup vs baseline: 1.2667x; 1.2667x over previous
//
#include <hip/hip_runtime.h>
#include <math.h>

// ---------- types ----------
typedef __bf16 bf16x8 __attribute__((ext_vector_type(8)));   // MFMA A/B fragment (4 VGPRs)
typedef float  f32x4  __attribute__((ext_vector_type(4)));   // MFMA C/D fragment
typedef short  s16x8  __attribute__((ext_vector_type(8)));   // raw 16B data movement

__device__ __forceinline__ unsigned short f2bf(float f) {
    unsigned int u = __float_as_uint(f);
    u += 0x7fffu + ((u >> 16) & 1u);   // round-to-nearest-even
    return (unsigned short)(u >> 16);
}

__device__ __forceinline__ float gelu_tanh(float x) {
    float x3 = x * x * x;
    float t = tanhf(0.7978845608028654f * (x + 0.044715f * x3));
    return 0.5f * x * (1.0f + t);
}

// ---------- transpose + f32->bf16 convert:  in[K][N] f32  ->  out[N][K] bf16 ----------
__global__ __launch_bounds__(256) void tcvt_kernel(const float* __restrict__ in,
                                                   unsigned short* __restrict__ out,
                                                   int K, int N) {
    __shared__ float tile[32][33];
    int tx = threadIdx.x, ty = threadIdx.y;           // 32 x 8
    int k0 = blockIdx.y * 32, n0 = blockIdx.x * 32;
#pragma unroll
    for (int s = 0; s < 4; ++s)
        tile[ty + s * 8][tx] = in[(size_t)(k0 + ty + s * 8) * N + n0 + tx];
    __syncthreads();
#pragma unroll
    for (int s = 0; s < 4; ++s)
        out[(size_t)(n0 + ty + s * 8) * K + k0 + tx] = f2bf(tile[tx][ty + s * 8]);
}

// ---------- layernorm: x[L][1024] f32 -> out bf16 ----------
__global__ __launch_bounds__(256) void ln_kernel(const float* __restrict__ x,
                                                 const float* __restrict__ g,
                                                 const float* __restrict__ b,
                                                 unsigned short* __restrict__ out) {
    int row = blockIdx.x;
    int tid = threadIdx.x;
    float4 v = ((const float4*)(x + (size_t)row * 1024))[tid];
    float s  = v.x + v.y + v.z + v.w;
    float ss = v.x * v.x + v.y * v.y + v.z * v.z + v.w * v.w;
#pragma unroll
    for (int o = 32; o > 0; o >>= 1) { s += __shfl_down(s, o); ss += __shfl_down(ss, o); }
    __shared__ float red[8];
    if ((tid & 63) == 0) { red[(tid >> 6) * 2] = s; red[(tid >> 6) * 2 + 1] = ss; }
    __syncthreads();
    s  = red[0] + red[2] + red[4] + red[6];
    ss = red[1] + red[3] + red[5] + red[7];
    float mean = s * (1.0f / 1024.0f);
    float var  = ss * (1.0f / 1024.0f) - mean * mean;
    float rs   = rsqrtf(var + 1e-5f);
    float4 gv = ((const float4*)g)[tid];
    float4 bv = ((const float4*)b)[tid];
    ushort4 o4;
    o4.x = f2bf((v.x - mean) * rs * gv.x + bv.x);
    o4.y = f2bf((v.y - mean) * rs * gv.y + bv.y);
    o4.z = f2bf((v.z - mean) * rs * gv.z + bv.z);
    o4.w = f2bf((v.w - mean) * rs * gv.w + bv.w);
    ((ushort4*)(out + (size_t)row * 1024))[tid] = o4;
}

// ---------- transpose V (bf16): qkv v-part [L=4096][ld 3072, off 2048] -> vt[1024][4096] ----------
__global__ __launch_bounds__(256) void tvt_kernel(const unsigned short* __restrict__ in,
                                                  unsigned short* __restrict__ out) {
    __shared__ unsigned short tile[64][72];
    int t = threadIdx.x;
    int l0 = blockIdx.x * 64, c0 = blockIdx.y * 64;
    int tr = t >> 3, tc = (t & 7) * 8;
#pragma unroll
    for (int s = 0; s < 2; ++s) {
        int r = tr + s * 32;
        s16x8 v = *(const s16x8*)(in + (size_t)(l0 + r) * 3072 + 2048 + c0 + tc);
        *(s16x8*)(&tile[r][tc]) = v;
    }
    __syncthreads();
#pragma unroll
    for (int s = 0; s < 2; ++s) {
        int c = tr + s * 32;
        s16x8 w;
#pragma unroll
        for (int e = 0; e < 8; ++e) w[e] = (short)tile[tc + e][c];
        *(s16x8*)(out + (size_t)(c0 + c) * 4096 + l0 + tc) = w;
    }
}

// ---------- legacy 128x128 GEMM (kept for Wo projection) ----------
#define BM 128
#define BN 128
#define BKK 64

template <int EPI>
__global__ __launch_bounds__(256) void gemm_kernel(const unsigned short* __restrict__ A,
                                                   const unsigned short* __restrict__ Bt,
                                                   void* __restrict__ C,
                                                   const float* __restrict__ bias,
                                                   const float* __restrict__ resid,
                                                   int M, int N, int K) {
    __shared__ __align__(16) unsigned short sA[BM * BKK];
    __shared__ __align__(16) unsigned short sB[BN * BKK];

    const int tid  = threadIdx.x;
    const int wv   = tid >> 6;
    const int lane = tid & 63;
    const int wr   = wv >> 1, wc = wv & 1;
    const int lg   = lane >> 4;
    const int l15  = lane & 15;

    const int brow = blockIdx.y * BM;
    const int bcol = blockIdx.x * BN;

    f32x4 acc[4][4] = {};

    const int l8 = lane >> 3;
    const int lc = (lane & 7) * 8;

    for (int kt = 0; kt < K; kt += BKK) {
        __syncthreads();
#pragma unroll
        for (int q = 0; q < 4; ++q) {
            int ch = 4 * wv + q;
            const unsigned short* srcA = A + (size_t)(brow + 8 * ch + l8) * K + kt + lc;
            __builtin_amdgcn_global_load_lds((const __attribute__((address_space(1))) void*)srcA,
                                             (__attribute__((address_space(3))) void*)(sA + ch * 512),
                                             16, 0, 0);
        }
#pragma unroll
        for (int q = 0; q < 4; ++q) {
            int ch = 4 * wv + q;
            const unsigned short* srcB = Bt + (size_t)(bcol + 8 * ch + l8) * K + kt + lc;
            __builtin_amdgcn_global_load_lds((const __attribute__((address_space(1))) void*)srcB,
                                             (__attribute__((address_space(3))) void*)(sB + ch * 512),
                                             16, 0, 0);
        }
        __syncthreads();

        bf16x8 af[4][2], bfr[4][2];
#pragma unroll
        for (int mi = 0; mi < 4; ++mi)
#pragma unroll
            for (int kk = 0; kk < 2; ++kk)
                af[mi][kk] = *(const bf16x8*)(sA + (wr * 64 + mi * 16 + l15) * BKK + lg * 8 + kk * 32);
#pragma unroll
        for (int ni = 0; ni < 4; ++ni)
#pragma unroll
            for (int kk = 0; kk < 2; ++kk)
                bfr[ni][kk] = *(const bf16x8*)(sB + (wc * 64 + ni * 16 + l15) * BKK + lg * 8 + kk * 32);

#pragma unroll
        for (int kk = 0; kk < 2; ++kk)
#pragma unroll
            for (int mi = 0; mi < 4; ++mi)
#pragma unroll
                for (int ni = 0; ni < 4; ++ni)
                    acc[mi][ni] = __builtin_amdgcn_mfma_f32_16x16x32_bf16(af[mi][kk], bfr[ni][kk],
                                                                          acc[mi][ni], 0, 0, 0);
    }

#pragma unroll
    for (int mi = 0; mi < 4; ++mi)
#pragma unroll
        for (int ni = 0; ni < 4; ++ni)
#pragma unroll
            for (int r = 0; r < 4; ++r) {
                int row = brow + wr * 64 + mi * 16 + lg * 4 + r;
                int col = bcol + wc * 64 + ni * 16 + l15;
                size_t idx = (size_t)row * N + col;
                float v = acc[mi][ni][r];
                if (EPI == 0) {
                    ((unsigned short*)C)[idx] = f2bf(v);
                } else if (EPI == 1) {
                    ((float*)C)[idx] = v + resid[idx];
                } else if (EPI == 2) {
                    v += bias[col];
                    ((unsigned short*)C)[idx] = f2bf(gelu_tanh(v));
                } else {
                    ((float*)C)[idx] = v + bias[col] + resid[idx];
                }
            }
}

// ---------- 256x256 8-phase GEMM (T1+T2+T3+T4+T5) ----------
// C[M][N] = A[M][lda] x Bt[N][ldb]^T over K range [split*NT*64, +NT*64)
// EPI 0: bf16 store; EPI 2: +bias, gelu, bf16; EPI 4: bf16 partial to slab[split]

__device__ __forceinline__ void stage64(const unsigned short* __restrict__ mat, int ld,
                                        int grow0, int kcol,
                                        unsigned short* lds_tile, int q, int wave, int lane) {
    const int l8 = lane >> 3;
    const int sc = ((lane & 7) ^ l8) << 3;      // pre-swizzled global source (rule 21)
    const unsigned short* src = mat + (size_t)(grow0 + q * 64 + wave * 8 + l8) * ld + kcol + sc;
    unsigned short* dst = lds_tile + ((q * 64 + wave * 8) << 6);   // wave-uniform, linear
    __builtin_amdgcn_global_load_lds((const __attribute__((address_space(1))) void*)src,
                                     (__attribute__((address_space(3))) void*)dst, 16, 0, 0);
}

__device__ __forceinline__ bf16x8 ldfrag(const unsigned short* tile, int row, int chunk) {
    return *(const bf16x8*)(tile + (row << 6) + ((chunk ^ (row & 7)) << 3));  // swizzled read
}

template <int EPI>
__global__ __launch_bounds__(512, 2) void gemm256_kernel(
        const unsigned short* __restrict__ A, int lda,
        const unsigned short* __restrict__ Bt, int ldb,
        void* __restrict__ Cv, const float* __restrict__ bias,
        int ldc, int NT, int gm, int gn, unsigned long long slab_stride) {
    extern __shared__ unsigned short lds[];
    unsigned short* sA = lds;                  // [2][256*64]
    unsigned short* sB = lds + 2 * 256 * 64;   // [2][256*64]

    const int tid  = threadIdx.x;
    const int wave = tid >> 6, lane = tid & 63;
    const int wr = wave >> 2, wc = wave & 3;       // 2 x 4 wave grid
    const int lg = lane >> 4, l15 = lane & 15;

    // bijective XCD swizzle (m204)
    const int nwg = gridDim.x;
    const int bid = blockIdx.x;
    const int q8 = nwg >> 3, r8 = nwg & 7;
    const int xcd = bid & 7, loc = bid >> 3;
    const int swz = (xcd < r8 ? xcd * (q8 + 1) : r8 * (q8 + 1) + (xcd - r8) * q8) + loc;
    const int split = swz / (gm * gn);
    const int rem   = swz % (gm * gn);
    const int brow = (rem / gn) << 8;
    const int bcol = (rem % gn) << 8;
    const int kbase = split * (NT << 6);

    f32x4 acc[8][4] = {};

#define STAGE_A(tt, q_, pbuf) stage64(A, lda, brow, kbase + ((tt) << 6), sA + (pbuf) * 16384, (q_), wave, lane)
#define STAGE_B(tt, q_, pbuf) stage64(Bt, ldb, bcol, kbase + ((tt) << 6), sB + (pbuf) * 16384, (q_), wave, lane)

    // prologue: full t0, t1 minus its B-q2/q3 (those come at t0.ph1)
    STAGE_A(0, 0, 0); STAGE_A(0, 1, 0); STAGE_A(0, 2, 0); STAGE_A(0, 3, 0);
    STAGE_B(0, 0, 0); STAGE_B(0, 1, 0); STAGE_B(0, 2, 0); STAGE_B(0, 3, 0);
    STAGE_A(1, 0, 1); STAGE_A(1, 1, 1); STAGE_A(1, 2, 1); STAGE_A(1, 3, 1);
    STAGE_B(1, 0, 1); STAGE_B(1, 1, 1);
    asm volatile("s_waitcnt vmcnt(6)" ::: "memory");   // t0 fully landed
    __builtin_amdgcn_s_barrier();

    for (int t = 0; t < NT; ++t) {
        const int p = t & 1;
        const unsigned short* tA = sA + p * 16384;
        const unsigned short* tB = sB + p * 16384;
        bf16x8 a0[4][2], a1[4][2], b0[2][2], b1[2][2];

        // ---- phase 1: quadrant (mh0, nh0) : reads A0(8) + B0(4)
#pragma unroll
        for (int im = 0; im < 4; ++im)
#pragma unroll
            for (int kk = 0; kk < 2; ++kk)
                a0[im][kk] = ldfrag(tA, wr * 128 + im * 16 + l15, lg + kk * 4);
#pragma unroll
        for (int in = 0; in < 2; ++in)
#pragma unroll
            for (int kk = 0; kk < 2; ++kk)
                b0[in][kk] = ldfrag(tB, wc * 64 + in * 16 + l15, lg + kk * 4);
        if (t + 1 < NT) { STAGE_B(t + 1, 2, p ^ 1); STAGE_B(t + 1, 3, p ^ 1); }
        __builtin_amdgcn_s_barrier();
        asm volatile("s_waitcnt lgkmcnt(0)" ::: "memory");
        __builtin_amdgcn_sched_barrier(0);
        __builtin_amdgcn_s_setprio(1);
#pragma unroll
        for (int kk = 0; kk < 2; ++kk)
#pragma unroll
            for (int im = 0; im < 4; ++im)
#pragma unroll
                for (int in = 0; in < 2; ++in)
                    acc[im][in] = __builtin_amdgcn_mfma_f32_16x16x32_bf16(a0[im][kk], b0[in][kk], acc[im][in], 0, 0, 0);
        __builtin_amdgcn_s_setprio(0);
        __builtin_amdgcn_s_barrier();

        // ---- phase 2: (mh1, nh0) : reads A1(8)
#pragma unroll
        for (int im = 0; im < 4; ++im)
#pragma unroll
            for (int kk = 0; kk < 2; ++kk)
                a1[im][kk] = ldfrag(tA, wr * 128 + 64 + im * 16 + l15, lg + kk * 4);
        if (t + 2 < NT) { STAGE_A(t + 2, 0, p); STAGE_A(t + 2, 2, p); }
        __builtin_amdgcn_s_barrier();
        asm volatile("s_waitcnt lgkmcnt(0)" ::: "memory");
        __builtin_amdgcn_sched_barrier(0);
        __builtin_amdgcn_s_setprio(1);
#pragma unroll
        for (int kk = 0; kk < 2; ++kk)
#pragma unroll
            for (int im = 0; im < 4; ++im)
#pragma unroll
                for (int in = 0; in < 2; ++in)
                    acc[4 + im][in] = __builtin_amdgcn_mfma_f32_16x16x32_bf16(a1[im][kk], b0[in][kk], acc[4 + im][in], 0, 0, 0);
        __builtin_amdgcn_s_setprio(0);
        __builtin_amdgcn_s_barrier();

        // ---- phase 3: (mh1, nh1) : reads B1(4)
#pragma unroll
        for (int in = 0; in < 2; ++in)
#pragma unroll
            for (int kk = 0; kk < 2; ++kk)
                b1[in][kk] = ldfrag(tB, wc * 64 + 32 + in * 16 + l15, lg + kk * 4);
        if (t + 2 < NT) { STAGE_A(t + 2, 1, p); STAGE_A(t + 2, 3, p); }
        __builtin_amdgcn_s_barrier();
        asm volatile("s_waitcnt lgkmcnt(0)" ::: "memory");
        __builtin_amdgcn_sched_barrier(0);
        __builtin_amdgcn_s_setprio(1);
#pragma unroll
        for (int kk = 0; kk < 2; ++kk)
#pragma unroll
            for (int im = 0; im < 4; ++im)
#pragma unroll
                for (int in = 0; in < 2; ++in)
                    acc[4 + im][2 + in] = __builtin_amdgcn_mfma_f32_16x16x32_bf16(a1[im][kk], b1[in][kk], acc[4 + im][2 + in], 0, 0, 0);
        __builtin_amdgcn_s_setprio(0);
        __builtin_amdgcn_s_barrier();

        // ---- phase 4: (mh0, nh1) : no reads; counted vmcnt before closing barrier
        if (t + 2 < NT) { STAGE_B(t + 2, 0, p); STAGE_B(t + 2, 1, p); }
        __builtin_amdgcn_s_barrier();
        asm volatile("s_waitcnt lgkmcnt(0)" ::: "memory");
        __builtin_amdgcn_sched_barrier(0);
        __builtin_amdgcn_s_setprio(1);
#pragma unroll
        for (int kk = 0; kk < 2; ++kk)
#pragma unroll
            for (int im = 0; im < 4; ++im)
#pragma unroll
                for (int in = 0; in < 2; ++in)
                    acc[im][2 + in] = __builtin_amdgcn_mfma_f32_16x16x32_bf16(a0[im][kk], b1[in][kk], acc[im][2 + in], 0, 0, 0);
        __builtin_amdgcn_s_setprio(0);
        if (t + 2 < NT) asm volatile("s_waitcnt vmcnt(6)" ::: "memory");
        else            asm volatile("s_waitcnt vmcnt(0)" ::: "memory");
        __builtin_amdgcn_s_barrier();
    }
#undef STAGE_A
#undef STAGE_B

    // epilogue
#pragma unroll
    for (int mi = 0; mi < 8; ++mi)
#pragma unroll
        for (int ni = 0; ni < 4; ++ni)
#pragma unroll
            for (int rr = 0; rr < 4; ++rr) {
                int row = brow + wr * 128 + mi * 16 + lg * 4 + rr;
                int col = bcol + wc * 64 + ni * 16 + l15;
                float v = acc[mi][ni][rr];
                if (EPI == 0) {
                    ((unsigned short*)Cv)[(size_t)row * ldc + col] = f2bf(v);
                } else if (EPI == 2) {
                    v += bias[col];
                    ((unsigned short*)Cv)[(size_t)row * ldc + col] = f2bf(gelu_tanh(v));
                } else {
                    ((unsigned short*)Cv)[slab_stride * split + (size_t)row * ldc + col] = f2bf(v);
                }
            }
}

// ---------- split-K reduce: out = sum(4 bf16 slabs) + bias + resid ----------
__global__ __launch_bounds__(256) void reduce4_kernel(const unsigned short* __restrict__ part,
                                                      const float* __restrict__ bias,
                                                      const float* __restrict__ resid,
                                                      float* __restrict__ out) {
    int i4 = blockIdx.x * 256 + threadIdx.x;       // float4 index over [4096][1024]
    float4 r  = ((const float4*)resid)[i4];
    float4 bb = ((const float4*)bias)[i4 & 255];
    float s0 = r.x + bb.x, s1 = r.y + bb.y, s2 = r.z + bb.z, s3 = r.w + bb.w;
#pragma unroll
    for (int s = 0; s < 4; ++s) {
        ushort4 u = ((const ushort4*)(part + (size_t)s * 4194304))[i4];
        s0 += __uint_as_float((unsigned)u.x << 16);
        s1 += __uint_as_float((unsigned)u.y << 16);
        s2 += __uint_as_float((unsigned)u.z << 16);
        s3 += __uint_as_float((unsigned)u.w << 16);
    }
    float4 o; o.x = s0; o.y = s1; o.z = s2; o.w = s3;
    ((float4*)out)[i4] = o;
}

// ---------- band attention (unchanged) ----------
__global__ __launch_bounds__(256) void attn_kernel(const unsigned short* __restrict__ qkv,
                                                   const unsigned short* __restrict__ vt,
                                                   const float* __restrict__ rel_emb,
                                                   unsigned short* __restrict__ outp) {
    const int n = blockIdx.x;
    const int h = blockIdx.y;
    const int tid  = threadIdx.x;
    const int wv   = tid >> 6;
    const int lane = tid & 63;
    const int lg   = lane >> 4;
    const int l15  = lane & 15;

    __shared__ __align__(16) unsigned short sQ[64 * 72];
    __shared__ __align__(16) unsigned short sK[64 * 72];
    __shared__ __align__(16) unsigned short sV[64 * 72];
    __shared__ __align__(16) unsigned short sP[64 * 72];
    __shared__ float sRel[258];

    for (int i = tid; i < 258; i += 256) sRel[i] = rel_emb[i * 16 + h];

    {
        int tr = tid >> 3, tc = (tid & 7) * 8;
#pragma unroll
        for (int s = 0; s < 2; ++s) {
            int r = tr + s * 32;
            s16x8 v = *(const s16x8*)(qkv + (size_t)(n * 64 + r) * 3072 + h * 64 + tc);
            *(s16x8*)(&sQ[r * 72 + tc]) = v;
        }
    }
    __syncthreads();

    bf16x8 qf[2];
#pragma unroll
    for (int kk = 0; kk < 2; ++kk)
        qf[kk] = *(const bf16x8*)(sQ + (wv * 16 + l15) * 72 + lg * 8 + kk * 32);

    f32x4 oacc[4] = {};
    float mrow[4] = {-1e30f, -1e30f, -1e30f, -1e30f};
    float lrow[4] = {0.f, 0.f, 0.f, 0.f};

    const int w0 = (n >= 15) ? 0 : (15 - n);
    for (int w = w0; w < 16; ++w) {
        const int src = n - 15 + w;
        __syncthreads();
        {
            int tr = tid >> 3, tc = (tid & 7) * 8;
#pragma unroll
            for (int s = 0; s < 2; ++s) {
                int r = tr + s * 32;
                s16x8 kv = *(const s16x8*)(qkv + (size_t)(src * 64 + r) * 3072 + 1024 + h * 64 + tc);
                *(s16x8*)(&sK[r * 72 + tc]) = kv;
                s16x8 vv = *(const s16x8*)(vt + (size_t)(h * 64 + r) * 4096 + src * 64 + tc);
                *(s16x8*)(&sV[r * 72 + tc]) = vv;
            }
        }
        __syncthreads();

        f32x4 s[4] = {};
#pragma unroll
        for (int t = 0; t < 4; ++t)
#pragma unroll
            for (int kk = 0; kk < 2; ++kk) {
                bf16x8 kf = *(const bf16x8*)(sK + (t * 16 + l15) * 72 + lg * 8 + kk * 32);
                s[t] = __builtin_amdgcn_mfma_f32_16x16x32_bf16(qf[kk], kf, s[t], 0, 0, 0);
            }

        float pmax[4] = {-1e30f, -1e30f, -1e30f, -1e30f};
#pragma unroll
        for (int t = 0; t < 4; ++t)
#pragma unroll
            for (int r = 0; r < 4; ++r) {
                int i = wv * 16 + lg * 4 + r;
                int j = t * 16 + l15;
                float val;
                if (w < 15 || j <= i) {
                    int delta = (15 - w) * 64 + i - j;
                    int relid = min(delta, 256) + 1;
                    val = s[t][r] * 0.125f + sRel[relid];
                } else {
                    val = -1e30f;
                }
                s[t][r] = val;
                pmax[r] = fmaxf(pmax[r], val);
            }
#pragma unroll
        for (int r = 0; r < 4; ++r) {
#pragma unroll
            for (int m = 1; m < 16; m <<= 1) pmax[r] = fmaxf(pmax[r], __shfl_xor(pmax[r], m));
        }

        float scl[4], mnew[4];
#pragma unroll
        for (int r = 0; r < 4; ++r) {
            mnew[r] = fmaxf(mrow[r], pmax[r]);
            scl[r]  = __expf(mrow[r] - mnew[r]);
            mrow[r] = mnew[r];
        }

        float rsum[4] = {0.f, 0.f, 0.f, 0.f};
#pragma unroll
        for (int t = 0; t < 4; ++t)
#pragma unroll
            for (int r = 0; r < 4; ++r) {
                float p = __expf(s[t][r] - mnew[r]);
                rsum[r] += p;
                sP[(wv * 16 + lg * 4 + r) * 72 + t * 16 + l15] = f2bf(p);
            }
#pragma unroll
        for (int r = 0; r < 4; ++r) {
#pragma unroll
            for (int m = 1; m < 16; m <<= 1) rsum[r] += __shfl_xor(rsum[r], m);
            lrow[r] = lrow[r] * scl[r] + rsum[r];
        }
#pragma unroll
        for (int t = 0; t < 4; ++t)
#pragma unroll
            for (int r = 0; r < 4; ++r) oacc[t][r] *= scl[r];

        __syncthreads();

#pragma unroll
        for (int kk = 0; kk < 2; ++kk) {
            bf16x8 pf = *(const bf16x8*)(sP + (wv * 16 + l15) * 72 + lg * 8 + kk * 32);
#pragma unroll
            for (int t = 0; t < 4; ++t) {
                bf16x8 vf = *(const bf16x8*)(sV + (t * 16 + l15) * 72 + lg * 8 + kk * 32);
                oacc[t] = __builtin_amdgcn_mfma_f32_16x16x32_bf16(pf, vf, oacc[t], 0, 0, 0);
            }
        }
    }

#pragma unroll
    for (int t = 0; t < 4; ++t)
#pragma unroll
        for (int r = 0; r < 4; ++r) {
            float inv = 1.0f / lrow[r];
            size_t idx = (size_t)(n * 64 + wv * 16 + lg * 4 + r) * 1024 + h * 64 + t * 16 + l15;
            outp[idx] = f2bf(oacc[t][r] * inv);
        }
}

// ---------- launch ----------
extern "C" void kernel_launch(void* const* d_in, const int* in_sizes, int n_in,
                              void* d_out, int out_size, void* d_ws, size_t ws_size,
                              hipStream_t stream) {
    const float* x    = (const float*)d_in[0];
    const float* Wq   = (const float*)d_in[1];
    const float* Wk   = (const float*)d_in[2];
    const float* Wv   = (const float*)d_in[3];
    const float* Wo   = (const float*)d_in[4];
    const float* rel  = (const float*)d_in[5];
    const float* ln1g = (const float*)d_in[6];
    const float* ln1b = (const float*)d_in[7];
    const float* ln2g = (const float*)d_in[8];
    const float* ln2b = (const float*)d_in[9];
    const float* W1   = (const float*)d_in[10];
    const float* b1   = (const float*)d_in[11];
    const float* W2   = (const float*)d_in[12];
    const float* b2   = (const float*)d_in[13];

    char* ws = (char*)d_ws;
    unsigned short* wqkvT = (unsigned short*)(ws + 0);          //  6 MB   [dead after QKV]
    unsigned short* woT   = (unsigned short*)(ws + 6291456);    //  2 MB   [dead after Wo]
    unsigned short* attnb = (unsigned short*)(ws + 8388608);    //  8 MB   [dead after Wo]
    unsigned short* w1T   = (unsigned short*)(ws + 16777216);   //  8 MB   [dead after FFN1]
    unsigned short* hbuf  = (unsigned short*)(ws + 25165824);   //  8 MB   [dead after FFN1]
    unsigned short* w2T   = (unsigned short*)(ws + 33554432);   //  8 MB
    float*          x2    = (float*)(ws + 41943040);            // 16 MB
    unsigned short* qkv   = (unsigned short*)(ws + 58720256);   // 24 MB   [dead after attn]
    unsigned short* vt    = (unsigned short*)(ws + 83886080);   //  8 MB   [dead after attn]
    unsigned short* gbuf  = (unsigned short*)(ws + 58720256);   // 32 MB   (reuses qkv+vt)
    unsigned short* part  = (unsigned short*)(ws + 0);          // 32 MB   (reuses 0..32MB)

    const int smem = 131072;
    hipFuncSetAttribute((const void*)gemm256_kernel<0>, hipFuncAttributeMaxDynamicSharedMemorySize, smem);
    hipFuncSetAttribute((const void*)gemm256_kernel<2>, hipFuncAttributeMaxDynamicSharedMemorySize, smem);
    hipFuncSetAttribute((const void*)gemm256_kernel<4>, hipFuncAttributeMaxDynamicSharedMemorySize, smem);

    dim3 tb(32, 8);
    tcvt_kernel<<<dim3(32, 32), tb, 0, stream>>>(Wq, wqkvT, 1024, 1024);
    tcvt_kernel<<<dim3(32, 32), tb, 0, stream>>>(Wk, wqkvT + 1048576, 1024, 1024);
    tcvt_kernel<<<dim3(32, 32), tb, 0, stream>>>(Wv, wqkvT + 2097152, 1024, 1024);
    tcvt_kernel<<<dim3(32, 32), tb, 0, stream>>>(Wo, woT, 1024, 1024);
    tcvt_kernel<<<dim3(128, 32), tb, 0, stream>>>(W1, w1T, 1024, 4096);
    tcvt_kernel<<<dim3(32, 128), tb, 0, stream>>>(W2, w2T, 4096, 1024);

    ln_kernel<<<4096, 256, 0, stream>>>(x, ln1g, ln1b, hbuf);

    // QKV: [4096,1024] x [3072,1024]^T -> qkv  (16x12 tiles)
    gemm256_kernel<0><<<192, 512, smem, stream>>>(hbuf, 1024, wqkvT, 1024, qkv,
                                                  nullptr, 3072, 16, 16, 12, 0ULL);

    tvt_kernel<<<dim3(64, 16), 256, 0, stream>>>(qkv, vt);

    attn_kernel<<<dim3(64, 16), 256, 0, stream>>>(qkv, vt, rel, attnb);

    // Wo projection + residual (legacy 128^2 kernel)
    gemm_kernel<1><<<dim3(1024 / 128, 4096 / 128), 256, 0, stream>>>(attnb, woT, x2,
                                                                     nullptr, x, 4096, 1024, 1024);

    ln_kernel<<<4096, 256, 0, stream>>>(x2, ln2g, ln2b, hbuf);

    // FFN1: [4096,1024] x [4096,1024]^T + b1, gelu -> gbuf  (16x16 tiles)
    gemm256_kernel<2><<<256, 512, smem, stream>>>(hbuf, 1024, w1T, 1024, gbuf,
                                                  b1, 4096, 16, 16, 16, 0ULL);

    // FFN2 split-K=4: [4096,4096] x [1024,4096]^T -> 4 bf16 partial slabs (16x4x4 blocks)
    gemm256_kernel<4><<<256, 512, smem, stream>>>(gbuf, 4096, w2T, 4096, part,
                                                  nullptr, 1024, 16, 16, 4, 4194304ULL);

    // out = sum(slabs) + b2 + x2
    reduce4_kernel<<<4096, 256, 0, stream>>>(part, b2, x2, (float*)d_out);
}

// Round 3
// 274.885 us; speedup vs baseline: 1.2674x; 1.0005x over previous
//
#include <hip/hip_runtime.h>
#include <math.h>

// ---------- types ----------
typedef __bf16 bf16x8 __attribute__((ext_vector_type(8)));   // MFMA A/B fragment (4 VGPRs)
typedef float  f32x4  __attribute__((ext_vector_type(4)));   // MFMA C/D fragment
typedef short  s16x8  __attribute__((ext_vector_type(8)));   // raw 16B data movement

__device__ __forceinline__ unsigned short f2bf(float f) {
    unsigned int u = __float_as_uint(f);
    u += 0x7fffu + ((u >> 16) & 1u);   // round-to-nearest-even
    return (unsigned short)(u >> 16);
}

__device__ __forceinline__ float gelu_tanh(float x) {
    float x3 = x * x * x;
    float t = tanhf(0.7978845608028654f * (x + 0.044715f * x3));
    return 0.5f * x * (1.0f + t);
}

// ---------- transpose + f32->bf16 convert:  in[K][N] f32  ->  out[N][K] bf16 ----------
__global__ __launch_bounds__(256) void tcvt_kernel(const float* __restrict__ in,
                                                   unsigned short* __restrict__ out,
                                                   int K, int N) {
    __shared__ float tile[32][33];
    int tx = threadIdx.x, ty = threadIdx.y;           // 32 x 8
    int k0 = blockIdx.y * 32, n0 = blockIdx.x * 32;
#pragma unroll
    for (int s = 0; s < 4; ++s)
        tile[ty + s * 8][tx] = in[(size_t)(k0 + ty + s * 8) * N + n0 + tx];
    __syncthreads();
#pragma unroll
    for (int s = 0; s < 4; ++s)
        out[(size_t)(n0 + ty + s * 8) * K + k0 + tx] = f2bf(tile[tx][ty + s * 8]);
}

// ---------- layernorm: x[L][1024] f32 -> out bf16 ----------
__global__ __launch_bounds__(256) void ln_kernel(const float* __restrict__ x,
                                                 const float* __restrict__ g,
                                                 const float* __restrict__ b,
                                                 unsigned short* __restrict__ out) {
    int row = blockIdx.x;
    int tid = threadIdx.x;
    float4 v = ((const float4*)(x + (size_t)row * 1024))[tid];
    float s  = v.x + v.y + v.z + v.w;
    float ss = v.x * v.x + v.y * v.y + v.z * v.z + v.w * v.w;
#pragma unroll
    for (int o = 32; o > 0; o >>= 1) { s += __shfl_down(s, o); ss += __shfl_down(ss, o); }
    __shared__ float red[8];
    if ((tid & 63) == 0) { red[(tid >> 6) * 2] = s; red[(tid >> 6) * 2 + 1] = ss; }
    __syncthreads();
    s  = red[0] + red[2] + red[4] + red[6];
    ss = red[1] + red[3] + red[5] + red[7];
    float mean = s * (1.0f / 1024.0f);
    float var  = ss * (1.0f / 1024.0f) - mean * mean;
    float rs   = rsqrtf(var + 1e-5f);
    float4 gv = ((const float4*)g)[tid];
    float4 bv = ((const float4*)b)[tid];
    ushort4 o4;
    o4.x = f2bf((v.x - mean) * rs * gv.x + bv.x);
    o4.y = f2bf((v.y - mean) * rs * gv.y + bv.y);
    o4.z = f2bf((v.z - mean) * rs * gv.z + bv.z);
    o4.w = f2bf((v.w - mean) * rs * gv.w + bv.w);
    ((ushort4*)(out + (size_t)row * 1024))[tid] = o4;
}

// ---------- transpose V (bf16): qkv v-part [L=4096][ld 3072, off 2048] -> vt[1024][4096] ----------
__global__ __launch_bounds__(256) void tvt_kernel(const unsigned short* __restrict__ in,
                                                  unsigned short* __restrict__ out) {
    __shared__ unsigned short tile[64][72];
    int t = threadIdx.x;
    int l0 = blockIdx.x * 64, c0 = blockIdx.y * 64;
    int tr = t >> 3, tc = (t & 7) * 8;
#pragma unroll
    for (int s = 0; s < 2; ++s) {
        int r = tr + s * 32;
        s16x8 v = *(const s16x8*)(in + (size_t)(l0 + r) * 3072 + 2048 + c0 + tc);
        *(s16x8*)(&tile[r][tc]) = v;
    }
    __syncthreads();
#pragma unroll
    for (int s = 0; s < 2; ++s) {
        int c = tr + s * 32;
        s16x8 w;
#pragma unroll
        for (int e = 0; e < 8; ++e) w[e] = (short)tile[tc + e][c];
        *(s16x8*)(out + (size_t)(c0 + c) * 4096 + l0 + tc) = w;
    }
}

// ---------- legacy 128x128 GEMM (kept for Wo projection) ----------
#define BM 128
#define BN 128
#define BKK 64

template <int EPI>
__global__ __launch_bounds__(256) void gemm_kernel(const unsigned short* __restrict__ A,
                                                   const unsigned short* __restrict__ Bt,
                                                   void* __restrict__ C,
                                                   const float* __restrict__ bias,
                                                   const float* __restrict__ resid,
                                                   int M, int N, int K) {
    __shared__ __align__(16) unsigned short sA[BM * BKK];
    __shared__ __align__(16) unsigned short sB[BN * BKK];

    const int tid  = threadIdx.x;
    const int wv   = tid >> 6;
    const int lane = tid & 63;
    const int wr   = wv >> 1, wc = wv & 1;
    const int lg   = lane >> 4;
    const int l15  = lane & 15;

    const int brow = blockIdx.y * BM;
    const int bcol = blockIdx.x * BN;

    f32x4 acc[4][4] = {};

    const int l8 = lane >> 3;
    const int lc = (lane & 7) * 8;

    for (int kt = 0; kt < K; kt += BKK) {
        __syncthreads();
#pragma unroll
        for (int q = 0; q < 4; ++q) {
            int ch = 4 * wv + q;
            const unsigned short* srcA = A + (size_t)(brow + 8 * ch + l8) * K + kt + lc;
            __builtin_amdgcn_global_load_lds((const __attribute__((address_space(1))) void*)srcA,
                                             (__attribute__((address_space(3))) void*)(sA + ch * 512),
                                             16, 0, 0);
        }
#pragma unroll
        for (int q = 0; q < 4; ++q) {
            int ch = 4 * wv + q;
            const unsigned short* srcB = Bt + (size_t)(bcol + 8 * ch + l8) * K + kt + lc;
            __builtin_amdgcn_global_load_lds((const __attribute__((address_space(1))) void*)srcB,
                                             (__attribute__((address_space(3))) void*)(sB + ch * 512),
                                             16, 0, 0);
        }
        __syncthreads();

        bf16x8 af[4][2], bfr[4][2];
#pragma unroll
        for (int mi = 0; mi < 4; ++mi)
#pragma unroll
            for (int kk = 0; kk < 2; ++kk)
                af[mi][kk] = *(const bf16x8*)(sA + (wr * 64 + mi * 16 + l15) * BKK + lg * 8 + kk * 32);
#pragma unroll
        for (int ni = 0; ni < 4; ++ni)
#pragma unroll
            for (int kk = 0; kk < 2; ++kk)
                bfr[ni][kk] = *(const bf16x8*)(sB + (wc * 64 + ni * 16 + l15) * BKK + lg * 8 + kk * 32);

#pragma unroll
        for (int kk = 0; kk < 2; ++kk)
#pragma unroll
            for (int mi = 0; mi < 4; ++mi)
#pragma unroll
                for (int ni = 0; ni < 4; ++ni)
                    acc[mi][ni] = __builtin_amdgcn_mfma_f32_16x16x32_bf16(af[mi][kk], bfr[ni][kk],
                                                                          acc[mi][ni], 0, 0, 0);
    }

#pragma unroll
    for (int mi = 0; mi < 4; ++mi)
#pragma unroll
        for (int ni = 0; ni < 4; ++ni)
#pragma unroll
            for (int r = 0; r < 4; ++r) {
                int row = brow + wr * 64 + mi * 16 + lg * 4 + r;
                int col = bcol + wc * 64 + ni * 16 + l15;
                size_t idx = (size_t)row * N + col;
                float v = acc[mi][ni][r];
                if (EPI == 0) {
                    ((unsigned short*)C)[idx] = f2bf(v);
                } else if (EPI == 1) {
                    ((float*)C)[idx] = v + resid[idx];
                } else if (EPI == 2) {
                    v += bias[col];
                    ((unsigned short*)C)[idx] = f2bf(gelu_tanh(v));
                } else {
                    ((float*)C)[idx] = v + bias[col] + resid[idx];
                }
            }
}

// ---------- 256x256 8-phase GEMM (T1+T2+T3+T4+T5) ----------
// C[M][N] = A[M][lda] x Bt[N][ldb]^T over K range [split*NT*64, +NT*64)
// EPI 0: bf16 store; EPI 2: +bias, gelu, bf16; EPI 4: bf16 partial to slab[split]

__device__ __forceinline__ void stage64(const unsigned short* __restrict__ mat, int ld,
                                        int grow0, int kcol,
                                        unsigned short* lds_tile, int q, int wave, int lane) {
    const int l8 = lane >> 3;
    const int sc = ((lane & 7) ^ l8) << 3;      // pre-swizzled global source (rule 21)
    const unsigned short* src = mat + (size_t)(grow0 + q * 64 + wave * 8 + l8) * ld + kcol + sc;
    unsigned short* dst = lds_tile + ((q * 64 + wave * 8) << 6);   // wave-uniform, linear
    __builtin_amdgcn_global_load_lds((const __attribute__((address_space(1))) void*)src,
                                     (__attribute__((address_space(3))) void*)dst, 16, 0, 0);
}

__device__ __forceinline__ bf16x8 ldfrag(const unsigned short* tile, int row, int chunk) {
    return *(const bf16x8*)(tile + (row << 6) + ((chunk ^ (row & 7)) << 3));  // swizzled read
}

template <int EPI>
__global__ __launch_bounds__(512, 2) void gemm256_kernel(
        const unsigned short* __restrict__ A, int lda,
        const unsigned short* __restrict__ Bt, int ldb,
        void* __restrict__ Cv, const float* __restrict__ bias,
        int ldc, int NT, int gm, int gn, unsigned long long slab_stride) {
    extern __shared__ unsigned short lds[];
    unsigned short* sA = lds;                  // [2][256*64]
    unsigned short* sB = lds + 2 * 256 * 64;   // [2][256*64]

    const int tid  = threadIdx.x;
    const int wave = tid >> 6, lane = tid & 63;
    const int wr = wave >> 2, wc = wave & 3;       // 2 x 4 wave grid
    const int lg = lane >> 4, l15 = lane & 15;

    // bijective XCD swizzle (m204)
    const int nwg = gridDim.x;
    const int bid = blockIdx.x;
    const int q8 = nwg >> 3, r8 = nwg & 7;
    const int xcd = bid & 7, loc = bid >> 3;
    const int swz = (xcd < r8 ? xcd * (q8 + 1) : r8 * (q8 + 1) + (xcd - r8) * q8) + loc;
    const int split = swz / (gm * gn);
    const int rem   = swz % (gm * gn);
    const int brow = (rem / gn) << 8;
    const int bcol = (rem % gn) << 8;
    const int kbase = split * (NT << 6);

    f32x4 acc[8][4] = {};

#define STAGE_A(tt, q_, pbuf) stage64(A, lda, brow, kbase + ((tt) << 6), sA + (pbuf) * 16384, (q_), wave, lane)
#define STAGE_B(tt, q_, pbuf) stage64(Bt, ldb, bcol, kbase + ((tt) << 6), sB + (pbuf) * 16384, (q_), wave, lane)

    // prologue: full t0, t1 minus its B-q2/q3 (those come at t0.ph1)
    STAGE_A(0, 0, 0); STAGE_A(0, 1, 0); STAGE_A(0, 2, 0); STAGE_A(0, 3, 0);
    STAGE_B(0, 0, 0); STAGE_B(0, 1, 0); STAGE_B(0, 2, 0); STAGE_B(0, 3, 0);
    STAGE_A(1, 0, 1); STAGE_A(1, 1, 1); STAGE_A(1, 2, 1); STAGE_A(1, 3, 1);
    STAGE_B(1, 0, 1); STAGE_B(1, 1, 1);
    asm volatile("s_waitcnt vmcnt(6)" ::: "memory");   // t0 fully landed
    __builtin_amdgcn_s_barrier();

    for (int t = 0; t < NT; ++t) {
        const int p = t & 1;
        const unsigned short* tA = sA + p * 16384;
        const unsigned short* tB = sB + p * 16384;
        bf16x8 a0[4][2], a1[4][2], b0[2][2], b1[2][2];

        // ---- phase 1: quadrant (mh0, nh0) : reads A0(8) + B0(4)
#pragma unroll
        for (int im = 0; im < 4; ++im)
#pragma unroll
            for (int kk = 0; kk < 2; ++kk)
                a0[im][kk] = ldfrag(tA, wr * 128 + im * 16 + l15, lg + kk * 4);
#pragma unroll
        for (int in = 0; in < 2; ++in)
#pragma unroll
            for (int kk = 0; kk < 2; ++kk)
                b0[in][kk] = ldfrag(tB, wc * 64 + in * 16 + l15, lg + kk * 4);
        if (t + 1 < NT) { STAGE_B(t + 1, 2, p ^ 1); STAGE_B(t + 1, 3, p ^ 1); }
        __builtin_amdgcn_s_barrier();
        asm volatile("s_waitcnt lgkmcnt(0)" ::: "memory");
        __builtin_amdgcn_sched_barrier(0);
        __builtin_amdgcn_s_setprio(1);
#pragma unroll
        for (int kk = 0; kk < 2; ++kk)
#pragma unroll
            for (int im = 0; im < 4; ++im)
#pragma unroll
                for (int in = 0; in < 2; ++in)
                    acc[im][in] = __builtin_amdgcn_mfma_f32_16x16x32_bf16(a0[im][kk], b0[in][kk], acc[im][in], 0, 0, 0);
        __builtin_amdgcn_s_setprio(0);
        __builtin_amdgcn_s_barrier();

        // ---- phase 2: (mh1, nh0) : reads A1(8)
#pragma unroll
        for (int im = 0; im < 4; ++im)
#pragma unroll
            for (int kk = 0; kk < 2; ++kk)
                a1[im][kk] = ldfrag(tA, wr * 128 + 64 + im * 16 + l15, lg + kk * 4);
        if (t + 2 < NT) { STAGE_A(t + 2, 0, p); STAGE_A(t + 2, 2, p); }
        __builtin_amdgcn_s_barrier();
        asm volatile("s_waitcnt lgkmcnt(0)" ::: "memory");
        __builtin_amdgcn_sched_barrier(0);
        __builtin_amdgcn_s_setprio(1);
#pragma unroll
        for (int kk = 0; kk < 2; ++kk)
#pragma unroll
            for (int im = 0; im < 4; ++im)
#pragma unroll
                for (int in = 0; in < 2; ++in)
                    acc[4 + im][in] = __builtin_amdgcn_mfma_f32_16x16x32_bf16(a1[im][kk], b0[in][kk], acc[4 + im][in], 0, 0, 0);
        __builtin_amdgcn_s_setprio(0);
        __builtin_amdgcn_s_barrier();

        // ---- phase 3: (mh1, nh1) : reads B1(4)
#pragma unroll
        for (int in = 0; in < 2; ++in)
#pragma unroll
            for (int kk = 0; kk < 2; ++kk)
                b1[in][kk] = ldfrag(tB, wc * 64 + 32 + in * 16 + l15, lg + kk * 4);
        if (t + 2 < NT) { STAGE_A(t + 2, 1, p); STAGE_A(t + 2, 3, p); }
        __builtin_amdgcn_s_barrier();
        asm volatile("s_waitcnt lgkmcnt(0)" ::: "memory");
        __builtin_amdgcn_sched_barrier(0);
        __builtin_amdgcn_s_setprio(1);
#pragma unroll
        for (int kk = 0; kk < 2; ++kk)
#pragma unroll
            for (int im = 0; im < 4; ++im)
#pragma unroll
                for (int in = 0; in < 2; ++in)
                    acc[4 + im][2 + in] = __builtin_amdgcn_mfma_f32_16x16x32_bf16(a1[im][kk], b1[in][kk], acc[4 + im][2 + in], 0, 0, 0);
        __builtin_amdgcn_s_setprio(0);
        __builtin_amdgcn_s_barrier();

        // ---- phase 4: (mh0, nh1) : no reads; counted vmcnt before closing barrier
        if (t + 2 < NT) { STAGE_B(t + 2, 0, p); STAGE_B(t + 2, 1, p); }
        __builtin_amdgcn_s_barrier();
        asm volatile("s_waitcnt lgkmcnt(0)" ::: "memory");
        __builtin_amdgcn_sched_barrier(0);
        __builtin_amdgcn_s_setprio(1);
#pragma unroll
        for (int kk = 0; kk < 2; ++kk)
#pragma unroll
            for (int im = 0; im < 4; ++im)
#pragma unroll
                for (int in = 0; in < 2; ++in)
                    acc[im][2 + in] = __builtin_amdgcn_mfma_f32_16x16x32_bf16(a0[im][kk], b1[in][kk], acc[im][2 + in], 0, 0, 0);
        __builtin_amdgcn_s_setprio(0);
        if (t + 2 < NT) asm volatile("s_waitcnt vmcnt(6)" ::: "memory");
        else            asm volatile("s_waitcnt vmcnt(0)" ::: "memory");
        __builtin_amdgcn_s_barrier();
    }
#undef STAGE_A
#undef STAGE_B

    // epilogue
#pragma unroll
    for (int mi = 0; mi < 8; ++mi)
#pragma unroll
        for (int ni = 0; ni < 4; ++ni)
#pragma unroll
            for (int rr = 0; rr < 4; ++rr) {
                int row = brow + wr * 128 + mi * 16 + lg * 4 + rr;
                int col = bcol + wc * 64 + ni * 16 + l15;
                float v = acc[mi][ni][rr];
                if (EPI == 0) {
                    ((unsigned short*)Cv)[(size_t)row * ldc + col] = f2bf(v);
                } else if (EPI == 2) {
                    v += bias[col];
                    ((unsigned short*)Cv)[(size_t)row * ldc + col] = f2bf(gelu_tanh(v));
                } else {
                    ((unsigned short*)Cv)[slab_stride * split + (size_t)row * ldc + col] = f2bf(v);
                }
            }
}

// ---------- split-K reduce: out = sum(4 bf16 slabs) + bias + resid ----------
__global__ __launch_bounds__(256) void reduce4_kernel(const unsigned short* __restrict__ part,
                                                      const float* __restrict__ bias,
                                                      const float* __restrict__ resid,
                                                      float* __restrict__ out) {
    int i4 = blockIdx.x * 256 + threadIdx.x;       // float4 index over [4096][1024]
    float4 r  = ((const float4*)resid)[i4];
    float4 bb = ((const float4*)bias)[i4 & 255];
    float s0 = r.x + bb.x, s1 = r.y + bb.y, s2 = r.z + bb.z, s3 = r.w + bb.w;
#pragma unroll
    for (int s = 0; s < 4; ++s) {
        ushort4 u = ((const ushort4*)(part + (size_t)s * 4194304))[i4];
        s0 += __uint_as_float((unsigned)u.x << 16);
        s1 += __uint_as_float((unsigned)u.y << 16);
        s2 += __uint_as_float((unsigned)u.z << 16);
        s3 += __uint_as_float((unsigned)u.w << 16);
    }
    float4 o; o.x = s0; o.y = s1; o.z = s2; o.w = s3;
    ((float4*)out)[i4] = o;
}

// ---------- band attention (unchanged) ----------
__global__ __launch_bounds__(256) void attn_kernel(const unsigned short* __restrict__ qkv,
                                                   const unsigned short* __restrict__ vt,
                                                   const float* __restrict__ rel_emb,
                                                   unsigned short* __restrict__ outp) {
    const int n = blockIdx.x;
    const int h = blockIdx.y;
    const int tid  = threadIdx.x;
    const int wv   = tid >> 6;
    const int lane = tid & 63;
    const int lg   = lane >> 4;
    const int l15  = lane & 15;

    __shared__ __align__(16) unsigned short sQ[64 * 72];
    __shared__ __align__(16) unsigned short sK[64 * 72];
    __shared__ __align__(16) unsigned short sV[64 * 72];
    __shared__ __align__(16) unsigned short sP[64 * 72];
    __shared__ float sRel[258];

    for (int i = tid; i < 258; i += 256) sRel[i] = rel_emb[i * 16 + h];

    {
        int tr = tid >> 3, tc = (tid & 7) * 8;
#pragma unroll
        for (int s = 0; s < 2; ++s) {
            int r = tr + s * 32;
            s16x8 v = *(const s16x8*)(qkv + (size_t)(n * 64 + r) * 3072 + h * 64 + tc);
            *(s16x8*)(&sQ[r * 72 + tc]) = v;
        }
    }
    __syncthreads();

    bf16x8 qf[2];
#pragma unroll
    for (int kk = 0; kk < 2; ++kk)
        qf[kk] = *(const bf16x8*)(sQ + (wv * 16 + l15) * 72 + lg * 8 + kk * 32);

    f32x4 oacc[4] = {};
    float mrow[4] = {-1e30f, -1e30f, -1e30f, -1e30f};
    float lrow[4] = {0.f, 0.f, 0.f, 0.f};

    const int w0 = (n >= 15) ? 0 : (15 - n);
    for (int w = w0; w < 16; ++w) {
        const int src = n - 15 + w;
        __syncthreads();
        {
            int tr = tid >> 3, tc = (tid & 7) * 8;
#pragma unroll
            for (int s = 0; s < 2; ++s) {
                int r = tr + s * 32;
                s16x8 kv = *(const s16x8*)(qkv + (size_t)(src * 64 + r) * 3072 + 1024 + h * 64 + tc);
                *(s16x8*)(&sK[r * 72 + tc]) = kv;
                s16x8 vv = *(const s16x8*)(vt + (size_t)(h * 64 + r) * 4096 + src * 64 + tc);
                *(s16x8*)(&sV[r * 72 + tc]) = vv;
            }
        }
        __syncthreads();

        f32x4 s[4] = {};
#pragma unroll
        for (int t = 0; t < 4; ++t)
#pragma unroll
            for (int kk = 0; kk < 2; ++kk) {
                bf16x8 kf = *(const bf16x8*)(sK + (t * 16 + l15) * 72 + lg * 8 + kk * 32);
                s[t] = __builtin_amdgcn_mfma_f32_16x16x32_bf16(qf[kk], kf, s[t], 0, 0, 0);
            }

        float pmax[4] = {-1e30f, -1e30f, -1e30f, -1e30f};
#pragma unroll
        for (int t = 0; t < 4; ++t)
#pragma unroll
            for (int r = 0; r < 4; ++r) {
                int i = wv * 16 + lg * 4 + r;
                int j = t * 16 + l15;
                float val;
                if (w < 15 || j <= i) {
                    int delta = (15 - w) * 64 + i - j;
                    int relid = min(delta, 256) + 1;
                    val = s[t][r] * 0.125f + sRel[relid];
                } else {
                    val = -1e30f;
                }
                s[t][r] = val;
                pmax[r] = fmaxf(pmax[r], val);
            }
#pragma unroll
        for (int r = 0; r < 4; ++r) {
#pragma unroll
            for (int m = 1; m < 16; m <<= 1) pmax[r] = fmaxf(pmax[r], __shfl_xor(pmax[r], m));
        }

        float scl[4], mnew[4];
#pragma unroll
        for (int r = 0; r < 4; ++r) {
            mnew[r] = fmaxf(mrow[r], pmax[r]);
            scl[r]  = __expf(mrow[r] - mnew[r]);
            mrow[r] = mnew[r];
        }

        float rsum[4] = {0.f, 0.f, 0.f, 0.f};
#pragma unroll
        for (int t = 0; t < 4; ++t)
#pragma unroll
            for (int r = 0; r < 4; ++r) {
                float p = __expf(s[t][r] - mnew[r]);
                rsum[r] += p;
                sP[(wv * 16 + lg * 4 + r) * 72 + t * 16 + l15] = f2bf(p);
            }
#pragma unroll
        for (int r = 0; r < 4; ++r) {
#pragma unroll
            for (int m = 1; m < 16; m <<= 1) rsum[r] += __shfl_xor(rsum[r], m);
            lrow[r] = lrow[r] * scl[r] + rsum[r];
        }
#pragma unroll
        for (int t = 0; t < 4; ++t)
#pragma unroll
            for (int r = 0; r < 4; ++r) oacc[t][r] *= scl[r];

        __syncthreads();

#pragma unroll
        for (int kk = 0; kk < 2; ++kk) {
            bf16x8 pf = *(const bf16x8*)(sP + (wv * 16 + l15) * 72 + lg * 8 + kk * 32);
#pragma unroll
            for (int t = 0; t < 4; ++t) {
                bf16x8 vf = *(const bf16x8*)(sV + (t * 16 + l15) * 72 + lg * 8 + kk * 32);
                oacc[t] = __builtin_amdgcn_mfma_f32_16x16x32_bf16(pf, vf, oacc[t], 0, 0, 0);
            }
        }
    }

#pragma unroll
    for (int t = 0; t < 4; ++t)
#pragma unroll
        for (int r = 0; r < 4; ++r) {
            float inv = 1.0f / lrow[r];
            size_t idx = (size_t)(n * 64 + wv * 16 + lg * 4 + r) * 1024 + h * 64 + t * 16 + l15;
            outp[idx] = f2bf(oacc[t][r] * inv);
        }
}

// ---------- launch ----------
extern "C" void kernel_launch(void* const* d_in, const int* in_sizes, int n_in,
                              void* d_out, int out_size, void* d_ws, size_t ws_size,
                              hipStream_t stream) {
    const float* x    = (const float*)d_in[0];
    const float* Wq   = (const float*)d_in[1];
    const float* Wk   = (const float*)d_in[2];
    const float* Wv   = (const float*)d_in[3];
    const float* Wo   = (const float*)d_in[4];
    const float* rel  = (const float*)d_in[5];
    const float* ln1g = (const float*)d_in[6];
    const float* ln1b = (const float*)d_in[7];
    const float* ln2g = (const float*)d_in[8];
    const float* ln2b = (const float*)d_in[9];
    const float* W1   = (const float*)d_in[10];
    const float* b1   = (const float*)d_in[11];
    const float* W2   = (const float*)d_in[12];
    const float* b2   = (const float*)d_in[13];

    char* ws = (char*)d_ws;
    unsigned short* wqkvT = (unsigned short*)(ws + 0);          //  6 MB   [dead after QKV]
    unsigned short* woT   = (unsigned short*)(ws + 6291456);    //  2 MB   [dead after Wo]
    unsigned short* attnb = (unsigned short*)(ws + 8388608);    //  8 MB   [dead after Wo]
    unsigned short* w1T   = (unsigned short*)(ws + 16777216);   //  8 MB   [dead after FFN1]
    unsigned short* hbuf  = (unsigned short*)(ws + 25165824);   //  8 MB   [dead after FFN1]
    unsigned short* w2T   = (unsigned short*)(ws + 33554432);   //  8 MB
    float*          x2    = (float*)(ws + 41943040);            // 16 MB
    unsigned short* qkv   = (unsigned short*)(ws + 58720256);   // 24 MB   [dead after attn]
    unsigned short* vt    = (unsigned short*)(ws + 83886080);   //  8 MB   [dead after attn]
    unsigned short* gbuf  = (unsigned short*)(ws + 58720256);   // 32 MB   (reuses qkv+vt)
    unsigned short* part  = (unsigned short*)(ws + 0);          // 32 MB   (reuses 0..32MB)

    const int smem = 131072;
    hipFuncSetAttribute((const void*)gemm256_kernel<0>, hipFuncAttributeMaxDynamicSharedMemorySize, smem);
    hipFuncSetAttribute((const void*)gemm256_kernel<2>, hipFuncAttributeMaxDynamicSharedMemorySize, smem);
    hipFuncSetAttribute((const void*)gemm256_kernel<4>, hipFuncAttributeMaxDynamicSharedMemorySize, smem);

    dim3 tb(32, 8);
    tcvt_kernel<<<dim3(32, 32), tb, 0, stream>>>(Wq, wqkvT, 1024, 1024);
    tcvt_kernel<<<dim3(32, 32), tb, 0, stream>>>(Wk, wqkvT + 1048576, 1024, 1024);
    tcvt_kernel<<<dim3(32, 32), tb, 0, stream>>>(Wv, wqkvT + 2097152, 1024, 1024);
    tcvt_kernel<<<dim3(32, 32), tb, 0, stream>>>(Wo, woT, 1024, 1024);
    tcvt_kernel<<<dim3(128, 32), tb, 0, stream>>>(W1, w1T, 1024, 4096);
    tcvt_kernel<<<dim3(32, 128), tb, 0, stream>>>(W2, w2T, 4096, 1024);

    ln_kernel<<<4096, 256, 0, stream>>>(x, ln1g, ln1b, hbuf);

    // QKV: [4096,1024] x [3072,1024]^T -> qkv  (16x12 tiles)
    gemm256_kernel<0><<<192, 512, smem, stream>>>(hbuf, 1024, wqkvT, 1024, qkv,
                                                  nullptr, 3072, 16, 16, 12, 0ULL);

    tvt_kernel<<<dim3(64, 16), 256, 0, stream>>>(qkv, vt);

    attn_kernel<<<dim3(64, 16), 256, 0, stream>>>(qkv, vt, rel, attnb);

    // Wo projection + residual (legacy 128^2 kernel)
    gemm_kernel<1><<<dim3(1024 / 128, 4096 / 128), 256, 0, stream>>>(attnb, woT, x2,
                                                                     nullptr, x, 4096, 1024, 1024);

    ln_kernel<<<4096, 256, 0, stream>>>(x2, ln2g, ln2b, hbuf);

    // FFN1: [4096,1024] x [4096,1024]^T + b1, gelu -> gbuf  (16x16 tiles)
    gemm256_kernel<2><<<256, 512, smem, stream>>>(hbuf, 1024, w1T, 1024, gbuf,
                                                  b1, 4096, 16, 16, 16, 0ULL);

    // FFN2 split-K=4: [4096,4096] x [1024,4096]^T -> 4 bf16 partial slabs (16x4x4 blocks)
    gemm256_kernel<4><<<256, 512, smem, stream>>>(gbuf, 4096, w2T, 4096, part,
                                                  nullptr, 1024, 16, 16, 4, 4194304ULL);

    // out = sum(slabs) + b2 + x2
    reduce4_kernel<<<4096, 256, 0, stream>>>(part, b2, x2, (float*)d_out);
}

// Round 4
// 274.100 us; speedup vs baseline: 1.2710x; 1.0029x over previous
//
#include <hip/hip_runtime.h>
#include <math.h>

// ---------- types ----------
typedef __bf16 bf16x8 __attribute__((ext_vector_type(8)));   // MFMA A/B fragment (4 VGPRs)
typedef float  f32x4  __attribute__((ext_vector_type(4)));   // MFMA C/D fragment
typedef short  s16x8  __attribute__((ext_vector_type(8)));   // raw 16B data movement

__device__ __forceinline__ unsigned short f2bf(float f) {
    unsigned int u = __float_as_uint(f);
    u += 0x7fffu + ((u >> 16) & 1u);   // round-to-nearest-even
    return (unsigned short)(u >> 16);
}

__device__ __forceinline__ float gelu_tanh(float x) {
    float x3 = x * x * x;
    float t = tanhf(0.7978845608028654f * (x + 0.044715f * x3));
    return 0.5f * x * (1.0f + t);
}

// ---------- transpose + f32->bf16 convert:  in[K][N] f32  ->  out[N][K] bf16 ----------
__global__ __launch_bounds__(256) void tcvt_kernel(const float* __restrict__ in,
                                                   unsigned short* __restrict__ out,
                                                   int K, int N) {
    __shared__ float tile[32][33];
    int tx = threadIdx.x, ty = threadIdx.y;           // 32 x 8
    int k0 = blockIdx.y * 32, n0 = blockIdx.x * 32;
#pragma unroll
    for (int s = 0; s < 4; ++s)
        tile[ty + s * 8][tx] = in[(size_t)(k0 + ty + s * 8) * N + n0 + tx];
    __syncthreads();
#pragma unroll
    for (int s = 0; s < 4; ++s)
        out[(size_t)(n0 + ty + s * 8) * K + k0 + tx] = f2bf(tile[tx][ty + s * 8]);
}

// ---------- layernorm: x[L][1024] f32 -> out bf16 ----------
__global__ __launch_bounds__(256) void ln_kernel(const float* __restrict__ x,
                                                 const float* __restrict__ g,
                                                 const float* __restrict__ b,
                                                 unsigned short* __restrict__ out) {
    int row = blockIdx.x;
    int tid = threadIdx.x;
    float4 v = ((const float4*)(x + (size_t)row * 1024))[tid];
    float s  = v.x + v.y + v.z + v.w;
    float ss = v.x * v.x + v.y * v.y + v.z * v.z + v.w * v.w;
#pragma unroll
    for (int o = 32; o > 0; o >>= 1) { s += __shfl_down(s, o); ss += __shfl_down(ss, o); }
    __shared__ float red[8];
    if ((tid & 63) == 0) { red[(tid >> 6) * 2] = s; red[(tid >> 6) * 2 + 1] = ss; }
    __syncthreads();
    s  = red[0] + red[2] + red[4] + red[6];
    ss = red[1] + red[3] + red[5] + red[7];
    float mean = s * (1.0f / 1024.0f);
    float var  = ss * (1.0f / 1024.0f) - mean * mean;
    float rs   = rsqrtf(var + 1e-5f);
    float4 gv = ((const float4*)g)[tid];
    float4 bv = ((const float4*)b)[tid];
    ushort4 o4;
    o4.x = f2bf((v.x - mean) * rs * gv.x + bv.x);
    o4.y = f2bf((v.y - mean) * rs * gv.y + bv.y);
    o4.z = f2bf((v.z - mean) * rs * gv.z + bv.z);
    o4.w = f2bf((v.w - mean) * rs * gv.w + bv.w);
    ((ushort4*)(out + (size_t)row * 1024))[tid] = o4;
}

// ---------- transpose V (bf16): qkv v-part [L=4096][ld 3072, off 2048] -> vt[1024][4096] ----------
__global__ __launch_bounds__(256) void tvt_kernel(const unsigned short* __restrict__ in,
                                                  unsigned short* __restrict__ out) {
    __shared__ unsigned short tile[64][72];
    int t = threadIdx.x;
    int l0 = blockIdx.x * 64, c0 = blockIdx.y * 64;
    int tr = t >> 3, tc = (t & 7) * 8;
#pragma unroll
    for (int s = 0; s < 2; ++s) {
        int r = tr + s * 32;
        s16x8 v = *(const s16x8*)(in + (size_t)(l0 + r) * 3072 + 2048 + c0 + tc);
        *(s16x8*)(&tile[r][tc]) = v;
    }
    __syncthreads();
#pragma unroll
    for (int s = 0; s < 2; ++s) {
        int c = tr + s * 32;
        s16x8 w;
#pragma unroll
        for (int e = 0; e < 8; ++e) w[e] = (short)tile[tc + e][c];
        *(s16x8*)(out + (size_t)(c0 + c) * 4096 + l0 + tc) = w;
    }
}

// ---------- legacy 128x128 GEMM (kept for Wo projection) ----------
#define BM 128
#define BN 128
#define BKK 64

template <int EPI>
__global__ __launch_bounds__(256) void gemm_kernel(const unsigned short* __restrict__ A,
                                                   const unsigned short* __restrict__ Bt,
                                                   void* __restrict__ C,
                                                   const float* __restrict__ bias,
                                                   const float* __restrict__ resid,
                                                   int M, int N, int K) {
    __shared__ __align__(16) unsigned short sA[BM * BKK];
    __shared__ __align__(16) unsigned short sB[BN * BKK];

    const int tid  = threadIdx.x;
    const int wv   = tid >> 6;
    const int lane = tid & 63;
    const int wr   = wv >> 1, wc = wv & 1;
    const int lg   = lane >> 4;
    const int l15  = lane & 15;

    const int brow = blockIdx.y * BM;
    const int bcol = blockIdx.x * BN;

    f32x4 acc[4][4] = {};

    const int l8 = lane >> 3;
    const int lc = (lane & 7) * 8;

    for (int kt = 0; kt < K; kt += BKK) {
        __syncthreads();
#pragma unroll
        for (int q = 0; q < 4; ++q) {
            int ch = 4 * wv + q;
            const unsigned short* srcA = A + (size_t)(brow + 8 * ch + l8) * K + kt + lc;
            __builtin_amdgcn_global_load_lds((const __attribute__((address_space(1))) void*)srcA,
                                             (__attribute__((address_space(3))) void*)(sA + ch * 512),
                                             16, 0, 0);
        }
#pragma unroll
        for (int q = 0; q < 4; ++q) {
            int ch = 4 * wv + q;
            const unsigned short* srcB = Bt + (size_t)(bcol + 8 * ch + l8) * K + kt + lc;
            __builtin_amdgcn_global_load_lds((const __attribute__((address_space(1))) void*)srcB,
                                             (__attribute__((address_space(3))) void*)(sB + ch * 512),
                                             16, 0, 0);
        }
        __syncthreads();

        bf16x8 af[4][2], bfr[4][2];
#pragma unroll
        for (int mi = 0; mi < 4; ++mi)
#pragma unroll
            for (int kk = 0; kk < 2; ++kk)
                af[mi][kk] = *(const bf16x8*)(sA + (wr * 64 + mi * 16 + l15) * BKK + lg * 8 + kk * 32);
#pragma unroll
        for (int ni = 0; ni < 4; ++ni)
#pragma unroll
            for (int kk = 0; kk < 2; ++kk)
                bfr[ni][kk] = *(const bf16x8*)(sB + (wc * 64 + ni * 16 + l15) * BKK + lg * 8 + kk * 32);

#pragma unroll
        for (int kk = 0; kk < 2; ++kk)
#pragma unroll
            for (int mi = 0; mi < 4; ++mi)
#pragma unroll
                for (int ni = 0; ni < 4; ++ni)
                    acc[mi][ni] = __builtin_amdgcn_mfma_f32_16x16x32_bf16(af[mi][kk], bfr[ni][kk],
                                                                          acc[mi][ni], 0, 0, 0);
    }

#pragma unroll
    for (int mi = 0; mi < 4; ++mi)
#pragma unroll
        for (int ni = 0; ni < 4; ++ni)
#pragma unroll
            for (int r = 0; r < 4; ++r) {
                int row = brow + wr * 64 + mi * 16 + lg * 4 + r;
                int col = bcol + wc * 64 + ni * 16 + l15;
                size_t idx = (size_t)row * N + col;
                float v = acc[mi][ni][r];
                if (EPI == 0) {
                    ((unsigned short*)C)[idx] = f2bf(v);
                } else if (EPI == 1) {
                    ((float*)C)[idx] = v + resid[idx];
                } else if (EPI == 2) {
                    v += bias[col];
                    ((unsigned short*)C)[idx] = f2bf(gelu_tanh(v));
                } else {
                    ((float*)C)[idx] = v + bias[col] + resid[idx];
                }
            }
}

// ---------- 256x256 8-phase GEMM (T1+T2+T3+T4+T5) ----------
// C[M][N] = A[M][lda] x Bt[N][ldb]^T over K range [split*NT*64, +NT*64)
// EPI 0: bf16 store; EPI 2: +bias, gelu, bf16; EPI 4: bf16 partial to slab[split]

__device__ __forceinline__ void stage64(const unsigned short* __restrict__ mat, int ld,
                                        int grow0, int kcol,
                                        unsigned short* lds_tile, int q, int wave, int lane) {
    const int l8 = lane >> 3;
    const int sc = ((lane & 7) ^ l8) << 3;      // pre-swizzled global source (rule 21)
    const unsigned short* src = mat + (size_t)(grow0 + q * 64 + wave * 8 + l8) * ld + kcol + sc;
    unsigned short* dst = lds_tile + ((q * 64 + wave * 8) << 6);   // wave-uniform, linear
    __builtin_amdgcn_global_load_lds((const __attribute__((address_space(1))) void*)src,
                                     (__attribute__((address_space(3))) void*)dst, 16, 0, 0);
}

__device__ __forceinline__ bf16x8 ldfrag(const unsigned short* tile, int row, int chunk) {
    return *(const bf16x8*)(tile + (row << 6) + ((chunk ^ (row & 7)) << 3));  // swizzled read
}

template <int EPI>
__global__ __launch_bounds__(512, 2) void gemm256_kernel(
        const unsigned short* __restrict__ A, int lda,
        const unsigned short* __restrict__ Bt, int ldb,
        void* __restrict__ Cv, const float* __restrict__ bias,
        int ldc, int NT, int gm, int gn, unsigned long long slab_stride) {
    extern __shared__ unsigned short lds[];
    unsigned short* sA = lds;                  // [2][256*64]
    unsigned short* sB = lds + 2 * 256 * 64;   // [2][256*64]

    const int tid  = threadIdx.x;
    const int wave = tid >> 6, lane = tid & 63;
    const int wr = wave >> 2, wc = wave & 3;       // 2 x 4 wave grid
    const int lg = lane >> 4, l15 = lane & 15;

    // bijective XCD swizzle (m204)
    const int nwg = gridDim.x;
    const int bid = blockIdx.x;
    const int q8 = nwg >> 3, r8 = nwg & 7;
    const int xcd = bid & 7, loc = bid >> 3;
    const int swz = (xcd < r8 ? xcd * (q8 + 1) : r8 * (q8 + 1) + (xcd - r8) * q8) + loc;
    const int split = swz / (gm * gn);
    const int rem   = swz % (gm * gn);
    const int brow = (rem / gn) << 8;
    const int bcol = (rem % gn) << 8;
    const int kbase = split * (NT << 6);

    f32x4 acc[8][4] = {};

#define STAGE_A(tt, q_, pbuf) stage64(A, lda, brow, kbase + ((tt) << 6), sA + (pbuf) * 16384, (q_), wave, lane)
#define STAGE_B(tt, q_, pbuf) stage64(Bt, ldb, bcol, kbase + ((tt) << 6), sB + (pbuf) * 16384, (q_), wave, lane)

    // prologue: full t0, t1 minus its B-q2/q3 (those come at t0.ph1)
    STAGE_A(0, 0, 0); STAGE_A(0, 1, 0); STAGE_A(0, 2, 0); STAGE_A(0, 3, 0);
    STAGE_B(0, 0, 0); STAGE_B(0, 1, 0); STAGE_B(0, 2, 0); STAGE_B(0, 3, 0);
    STAGE_A(1, 0, 1); STAGE_A(1, 1, 1); STAGE_A(1, 2, 1); STAGE_A(1, 3, 1);
    STAGE_B(1, 0, 1); STAGE_B(1, 1, 1);
    asm volatile("s_waitcnt vmcnt(6)" ::: "memory");   // t0 fully landed
    __builtin_amdgcn_s_barrier();

    for (int t = 0; t < NT; ++t) {
        const int p = t & 1;
        const unsigned short* tA = sA + p * 16384;
        const unsigned short* tB = sB + p * 16384;
        bf16x8 a0[4][2], a1[4][2], b0[2][2], b1[2][2];

        // ---- phase 1: quadrant (mh0, nh0) : reads A0(8) + B0(4)
#pragma unroll
        for (int im = 0; im < 4; ++im)
#pragma unroll
            for (int kk = 0; kk < 2; ++kk)
                a0[im][kk] = ldfrag(tA, wr * 128 + im * 16 + l15, lg + kk * 4);
#pragma unroll
        for (int in = 0; in < 2; ++in)
#pragma unroll
            for (int kk = 0; kk < 2; ++kk)
                b0[in][kk] = ldfrag(tB, wc * 64 + in * 16 + l15, lg + kk * 4);
        if (t + 1 < NT) { STAGE_B(t + 1, 2, p ^ 1); STAGE_B(t + 1, 3, p ^ 1); }
        __builtin_amdgcn_s_barrier();
        asm volatile("s_waitcnt lgkmcnt(0)" ::: "memory");
        __builtin_amdgcn_sched_barrier(0);
        __builtin_amdgcn_s_setprio(1);
#pragma unroll
        for (int kk = 0; kk < 2; ++kk)
#pragma unroll
            for (int im = 0; im < 4; ++im)
#pragma unroll
                for (int in = 0; in < 2; ++in)
                    acc[im][in] = __builtin_amdgcn_mfma_f32_16x16x32_bf16(a0[im][kk], b0[in][kk], acc[im][in], 0, 0, 0);
        __builtin_amdgcn_s_setprio(0);
        __builtin_amdgcn_s_barrier();

        // ---- phase 2: (mh1, nh0) : reads A1(8)
#pragma unroll
        for (int im = 0; im < 4; ++im)
#pragma unroll
            for (int kk = 0; kk < 2; ++kk)
                a1[im][kk] = ldfrag(tA, wr * 128 + 64 + im * 16 + l15, lg + kk * 4);
        if (t + 2 < NT) { STAGE_A(t + 2, 0, p); STAGE_A(t + 2, 2, p); }
        __builtin_amdgcn_s_barrier();
        asm volatile("s_waitcnt lgkmcnt(0)" ::: "memory");
        __builtin_amdgcn_sched_barrier(0);
        __builtin_amdgcn_s_setprio(1);
#pragma unroll
        for (int kk = 0; kk < 2; ++kk)
#pragma unroll
            for (int im = 0; im < 4; ++im)
#pragma unroll
                for (int in = 0; in < 2; ++in)
                    acc[4 + im][in] = __builtin_amdgcn_mfma_f32_16x16x32_bf16(a1[im][kk], b0[in][kk], acc[4 + im][in], 0, 0, 0);
        __builtin_amdgcn_s_setprio(0);
        __builtin_amdgcn_s_barrier();

        // ---- phase 3: (mh1, nh1) : reads B1(4)
#pragma unroll
        for (int in = 0; in < 2; ++in)
#pragma unroll
            for (int kk = 0; kk < 2; ++kk)
                b1[in][kk] = ldfrag(tB, wc * 64 + 32 + in * 16 + l15, lg + kk * 4);
        if (t + 2 < NT) { STAGE_A(t + 2, 1, p); STAGE_A(t + 2, 3, p); }
        __builtin_amdgcn_s_barrier();
        asm volatile("s_waitcnt lgkmcnt(0)" ::: "memory");
        __builtin_amdgcn_sched_barrier(0);
        __builtin_amdgcn_s_setprio(1);
#pragma unroll
        for (int kk = 0; kk < 2; ++kk)
#pragma unroll
            for (int im = 0; im < 4; ++im)
#pragma unroll
                for (int in = 0; in < 2; ++in)
                    acc[4 + im][2 + in] = __builtin_amdgcn_mfma_f32_16x16x32_bf16(a1[im][kk], b1[in][kk], acc[4 + im][2 + in], 0, 0, 0);
        __builtin_amdgcn_s_setprio(0);
        __builtin_amdgcn_s_barrier();

        // ---- phase 4: (mh0, nh1) : no reads; counted vmcnt before closing barrier
        if (t + 2 < NT) { STAGE_B(t + 2, 0, p); STAGE_B(t + 2, 1, p); }
        __builtin_amdgcn_s_barrier();
        asm volatile("s_waitcnt lgkmcnt(0)" ::: "memory");
        __builtin_amdgcn_sched_barrier(0);
        __builtin_amdgcn_s_setprio(1);
#pragma unroll
        for (int kk = 0; kk < 2; ++kk)
#pragma unroll
            for (int im = 0; im < 4; ++im)
#pragma unroll
                for (int in = 0; in < 2; ++in)
                    acc[im][2 + in] = __builtin_amdgcn_mfma_f32_16x16x32_bf16(a0[im][kk], b1[in][kk], acc[im][2 + in], 0, 0, 0);
        __builtin_amdgcn_s_setprio(0);
        if (t + 2 < NT) asm volatile("s_waitcnt vmcnt(6)" ::: "memory");
        else            asm volatile("s_waitcnt vmcnt(0)" ::: "memory");
        __builtin_amdgcn_s_barrier();
    }
#undef STAGE_A
#undef STAGE_B

    // epilogue
#pragma unroll
    for (int mi = 0; mi < 8; ++mi)
#pragma unroll
        for (int ni = 0; ni < 4; ++ni)
#pragma unroll
            for (int rr = 0; rr < 4; ++rr) {
                int row = brow + wr * 128 + mi * 16 + lg * 4 + rr;
                int col = bcol + wc * 64 + ni * 16 + l15;
                float v = acc[mi][ni][rr];
                if (EPI == 0) {
                    ((unsigned short*)Cv)[(size_t)row * ldc + col] = f2bf(v);
                } else if (EPI == 2) {
                    v += bias[col];
                    ((unsigned short*)Cv)[(size_t)row * ldc + col] = f2bf(gelu_tanh(v));
                } else {
                    ((unsigned short*)Cv)[slab_stride * split + (size_t)row * ldc + col] = f2bf(v);
                }
            }
}

// ---------- split-K reduce: out = sum(4 bf16 slabs) + bias + resid ----------
__global__ __launch_bounds__(256) void reduce4_kernel(const unsigned short* __restrict__ part,
                                                      const float* __restrict__ bias,
                                                      const float* __restrict__ resid,
                                                      float* __restrict__ out) {
    int i4 = blockIdx.x * 256 + threadIdx.x;       // float4 index over [4096][1024]
    float4 r  = ((const float4*)resid)[i4];
    float4 bb = ((const float4*)bias)[i4 & 255];
    float s0 = r.x + bb.x, s1 = r.y + bb.y, s2 = r.z + bb.z, s3 = r.w + bb.w;
#pragma unroll
    for (int s = 0; s < 4; ++s) {
        ushort4 u = ((const ushort4*)(part + (size_t)s * 4194304))[i4];
        s0 += __uint_as_float((unsigned)u.x << 16);
        s1 += __uint_as_float((unsigned)u.y << 16);
        s2 += __uint_as_float((unsigned)u.z << 16);
        s3 += __uint_as_float((unsigned)u.w << 16);
    }
    float4 o; o.x = s0; o.y = s1; o.z = s2; o.w = s3;
    ((float4*)out)[i4] = o;
}

// ---------- band attention (unchanged) ----------
__global__ __launch_bounds__(256) void attn_kernel(const unsigned short* __restrict__ qkv,
                                                   const unsigned short* __restrict__ vt,
                                                   const float* __restrict__ rel_emb,
                                                   unsigned short* __restrict__ outp) {
    const int n = blockIdx.x;
    const int h = blockIdx.y;
    const int tid  = threadIdx.x;
    const int wv   = tid >> 6;
    const int lane = tid & 63;
    const int lg   = lane >> 4;
    const int l15  = lane & 15;

    __shared__ __align__(16) unsigned short sQ[64 * 72];
    __shared__ __align__(16) unsigned short sK[64 * 72];
    __shared__ __align__(16) unsigned short sV[64 * 72];
    __shared__ __align__(16) unsigned short sP[64 * 72];
    __shared__ float sRel[258];

    for (int i = tid; i < 258; i += 256) sRel[i] = rel_emb[i * 16 + h];

    {
        int tr = tid >> 3, tc = (tid & 7) * 8;
#pragma unroll
        for (int s = 0; s < 2; ++s) {
            int r = tr + s * 32;
            s16x8 v = *(const s16x8*)(qkv + (size_t)(n * 64 + r) * 3072 + h * 64 + tc);
            *(s16x8*)(&sQ[r * 72 + tc]) = v;
        }
    }
    __syncthreads();

    bf16x8 qf[2];
#pragma unroll
    for (int kk = 0; kk < 2; ++kk)
        qf[kk] = *(const bf16x8*)(sQ + (wv * 16 + l15) * 72 + lg * 8 + kk * 32);

    f32x4 oacc[4] = {};
    float mrow[4] = {-1e30f, -1e30f, -1e30f, -1e30f};
    float lrow[4] = {0.f, 0.f, 0.f, 0.f};

    const int w0 = (n >= 15) ? 0 : (15 - n);
    for (int w = w0; w < 16; ++w) {
        const int src = n - 15 + w;
        __syncthreads();
        {
            int tr = tid >> 3, tc = (tid & 7) * 8;
#pragma unroll
            for (int s = 0; s < 2; ++s) {
                int r = tr + s * 32;
                s16x8 kv = *(const s16x8*)(qkv + (size_t)(src * 64 + r) * 3072 + 1024 + h * 64 + tc);
                *(s16x8*)(&sK[r * 72 + tc]) = kv;
                s16x8 vv = *(const s16x8*)(vt + (size_t)(h * 64 + r) * 4096 + src * 64 + tc);
                *(s16x8*)(&sV[r * 72 + tc]) = vv;
            }
        }
        __syncthreads();

        f32x4 s[4] = {};
#pragma unroll
        for (int t = 0; t < 4; ++t)
#pragma unroll
            for (int kk = 0; kk < 2; ++kk) {
                bf16x8 kf = *(const bf16x8*)(sK + (t * 16 + l15) * 72 + lg * 8 + kk * 32);
                s[t] = __builtin_amdgcn_mfma_f32_16x16x32_bf16(qf[kk], kf, s[t], 0, 0, 0);
            }

        float pmax[4] = {-1e30f, -1e30f, -1e30f, -1e30f};
#pragma unroll
        for (int t = 0; t < 4; ++t)
#pragma unroll
            for (int r = 0; r < 4; ++r) {
                int i = wv * 16 + lg * 4 + r;
                int j = t * 16 + l15;
                float val;
                if (w < 15 || j <= i) {
                    int delta = (15 - w) * 64 + i - j;
                    int relid = min(delta, 256) + 1;
                    val = s[t][r] * 0.125f + sRel[relid];
                } else {
                    val = -1e30f;
                }
                s[t][r] = val;
                pmax[r] = fmaxf(pmax[r], val);
            }
#pragma unroll
        for (int r = 0; r < 4; ++r) {
#pragma unroll
            for (int m = 1; m < 16; m <<= 1) pmax[r] = fmaxf(pmax[r], __shfl_xor(pmax[r], m));
        }

        float scl[4], mnew[4];
#pragma unroll
        for (int r = 0; r < 4; ++r) {
            mnew[r] = fmaxf(mrow[r], pmax[r]);
            scl[r]  = __expf(mrow[r] - mnew[r]);
            mrow[r] = mnew[r];
        }

        float rsum[4] = {0.f, 0.f, 0.f, 0.f};
#pragma unroll
        for (int t = 0; t < 4; ++t)
#pragma unroll
            for (int r = 0; r < 4; ++r) {
                float p = __expf(s[t][r] - mnew[r]);
                rsum[r] += p;
                sP[(wv * 16 + lg * 4 + r) * 72 + t * 16 + l15] = f2bf(p);
            }
#pragma unroll
        for (int r = 0; r < 4; ++r) {
#pragma unroll
            for (int m = 1; m < 16; m <<= 1) rsum[r] += __shfl_xor(rsum[r], m);
            lrow[r] = lrow[r] * scl[r] + rsum[r];
        }
#pragma unroll
        for (int t = 0; t < 4; ++t)
#pragma unroll
            for (int r = 0; r < 4; ++r) oacc[t][r] *= scl[r];

        __syncthreads();

#pragma unroll
        for (int kk = 0; kk < 2; ++kk) {
            bf16x8 pf = *(const bf16x8*)(sP + (wv * 16 + l15) * 72 + lg * 8 + kk * 32);
#pragma unroll
            for (int t = 0; t < 4; ++t) {
                bf16x8 vf = *(const bf16x8*)(sV + (t * 16 + l15) * 72 + lg * 8 + kk * 32);
                oacc[t] = __builtin_amdgcn_mfma_f32_16x16x32_bf16(pf, vf, oacc[t], 0, 0, 0);
            }
        }
    }

#pragma unroll
    for (int t = 0; t < 4; ++t)
#pragma unroll
        for (int r = 0; r < 4; ++r) {
            float inv = 1.0f / lrow[r];
            size_t idx = (size_t)(n * 64 + wv * 16 + lg * 4 + r) * 1024 + h * 64 + t * 16 + l15;
            outp[idx] = f2bf(oacc[t][r] * inv);
        }
}

// ---------- launch ----------
extern "C" void kernel_launch(void* const* d_in, const int* in_sizes, int n_in,
                              void* d_out, int out_size, void* d_ws, size_t ws_size,
                              hipStream_t stream) {
    const float* x    = (const float*)d_in[0];
    const float* Wq   = (const float*)d_in[1];
    const float* Wk   = (const float*)d_in[2];
    const float* Wv   = (const float*)d_in[3];
    const float* Wo   = (const float*)d_in[4];
    const float* rel  = (const float*)d_in[5];
    const float* ln1g = (const float*)d_in[6];
    const float* ln1b = (const float*)d_in[7];
    const float* ln2g = (const float*)d_in[8];
    const float* ln2b = (const float*)d_in[9];
    const float* W1   = (const float*)d_in[10];
    const float* b1   = (const float*)d_in[11];
    const float* W2   = (const float*)d_in[12];
    const float* b2   = (const float*)d_in[13];

    char* ws = (char*)d_ws;
    unsigned short* wqkvT = (unsigned short*)(ws + 0);          //  6 MB   [dead after QKV]
    unsigned short* woT   = (unsigned short*)(ws + 6291456);    //  2 MB   [dead after Wo]
    unsigned short* attnb = (unsigned short*)(ws + 8388608);    //  8 MB   [dead after Wo]
    unsigned short* w1T   = (unsigned short*)(ws + 16777216);   //  8 MB   [dead after FFN1]
    unsigned short* hbuf  = (unsigned short*)(ws + 25165824);   //  8 MB   [dead after FFN1]
    unsigned short* w2T   = (unsigned short*)(ws + 33554432);   //  8 MB
    float*          x2    = (float*)(ws + 41943040);            // 16 MB
    unsigned short* qkv   = (unsigned short*)(ws + 58720256);   // 24 MB   [dead after attn]
    unsigned short* vt    = (unsigned short*)(ws + 83886080);   //  8 MB   [dead after attn]
    unsigned short* gbuf  = (unsigned short*)(ws + 58720256);   // 32 MB   (reuses qkv+vt)
    unsigned short* part  = (unsigned short*)(ws + 0);          // 32 MB   (reuses 0..32MB)

    const int smem = 131072;
    hipFuncSetAttribute((const void*)gemm256_kernel<0>, hipFuncAttributeMaxDynamicSharedMemorySize, smem);
    hipFuncSetAttribute((const void*)gemm256_kernel<2>, hipFuncAttributeMaxDynamicSharedMemorySize, smem);
    hipFuncSetAttribute((const void*)gemm256_kernel<4>, hipFuncAttributeMaxDynamicSharedMemorySize, smem);

    dim3 tb(32, 8);
    tcvt_kernel<<<dim3(32, 32), tb, 0, stream>>>(Wq, wqkvT, 1024, 1024);
    tcvt_kernel<<<dim3(32, 32), tb, 0, stream>>>(Wk, wqkvT + 1048576, 1024, 1024);
    tcvt_kernel<<<dim3(32, 32), tb, 0, stream>>>(Wv, wqkvT + 2097152, 1024, 1024);
    tcvt_kernel<<<dim3(32, 32), tb, 0, stream>>>(Wo, woT, 1024, 1024);
    tcvt_kernel<<<dim3(128, 32), tb, 0, stream>>>(W1, w1T, 1024, 4096);
    tcvt_kernel<<<dim3(32, 128), tb, 0, stream>>>(W2, w2T, 4096, 1024);

    ln_kernel<<<4096, 256, 0, stream>>>(x, ln1g, ln1b, hbuf);

    // QKV: [4096,1024] x [3072,1024]^T -> qkv  (16x12 tiles)
    gemm256_kernel<0><<<192, 512, smem, stream>>>(hbuf, 1024, wqkvT, 1024, qkv,
                                                  nullptr, 3072, 16, 16, 12, 0ULL);

    tvt_kernel<<<dim3(64, 16), 256, 0, stream>>>(qkv, vt);

    attn_kernel<<<dim3(64, 16), 256, 0, stream>>>(qkv, vt, rel, attnb);

    // Wo projection + residual (legacy 128^2 kernel)
    gemm_kernel<1><<<dim3(1024 / 128, 4096 / 128), 256, 0, stream>>>(attnb, woT, x2,
                                                                     nullptr, x, 4096, 1024, 1024);

    ln_kernel<<<4096, 256, 0, stream>>>(x2, ln2g, ln2b, hbuf);

    // FFN1: [4096,1024] x [4096,1024]^T + b1, gelu -> gbuf  (16x16 tiles)
    gemm256_kernel<2><<<256, 512, smem, stream>>>(hbuf, 1024, w1T, 1024, gbuf,
                                                  b1, 4096, 16, 16, 16, 0ULL);

    // FFN2 split-K=4: [4096,4096] x [1024,4096]^T -> 4 bf16 partial slabs (16x4x4 blocks)
    gemm256_kernel<4><<<256, 512, smem, stream>>>(gbuf, 4096, w2T, 4096, part,
                                                  nullptr, 1024, 16, 16, 4, 4194304ULL);

    // out = sum(slabs) + b2 + x2
    reduce4_kernel<<<4096, 256, 0, stream>>>(part, b2, x2, (float*)d_out);
}

// Round 5
// 263.094 us; speedup vs baseline: 1.3242x; 1.0418x over previous
//
#include <hip/hip_runtime.h>
#include <math.h>

// ---------- types ----------
typedef __bf16 bf16x8 __attribute__((ext_vector_type(8)));   // MFMA A/B fragment (4 VGPRs)
typedef float  f32x4  __attribute__((ext_vector_type(4)));   // MFMA C/D fragment
typedef short  s16x8  __attribute__((ext_vector_type(8)));   // raw 16B data movement

__device__ __forceinline__ unsigned short f2bf(float f) {
    unsigned int u = __float_as_uint(f);
    u += 0x7fffu + ((u >> 16) & 1u);   // round-to-nearest-even
    return (unsigned short)(u >> 16);
}

__device__ __forceinline__ float gelu_tanh(float x) {
    float x3 = x * x * x;
    float t = tanhf(0.7978845608028654f * (x + 0.044715f * x3));
    return 0.5f * x * (1.0f + t);
}

// ---------- transpose + f32->bf16 convert:  in[K][N] f32  ->  out[N][K] bf16 ----------
__global__ __launch_bounds__(256) void tcvt_kernel(const float* __restrict__ in,
                                                   unsigned short* __restrict__ out,
                                                   int K, int N) {
    __shared__ float tile[32][33];
    int tx = threadIdx.x, ty = threadIdx.y;           // 32 x 8
    int k0 = blockIdx.y * 32, n0 = blockIdx.x * 32;
#pragma unroll
    for (int s = 0; s < 4; ++s)
        tile[ty + s * 8][tx] = in[(size_t)(k0 + ty + s * 8) * N + n0 + tx];
    __syncthreads();
#pragma unroll
    for (int s = 0; s < 4; ++s)
        out[(size_t)(n0 + ty + s * 8) * K + k0 + tx] = f2bf(tile[tx][ty + s * 8]);
}

// ---------- layernorm: x[L][1024] f32 -> out bf16 ----------
__global__ __launch_bounds__(256) void ln_kernel(const float* __restrict__ x,
                                                 const float* __restrict__ g,
                                                 const float* __restrict__ b,
                                                 unsigned short* __restrict__ out) {
    int row = blockIdx.x;
    int tid = threadIdx.x;
    float4 v = ((const float4*)(x + (size_t)row * 1024))[tid];
    float s  = v.x + v.y + v.z + v.w;
    float ss = v.x * v.x + v.y * v.y + v.z * v.z + v.w * v.w;
#pragma unroll
    for (int o = 32; o > 0; o >>= 1) { s += __shfl_down(s, o); ss += __shfl_down(ss, o); }
    __shared__ float red[8];
    if ((tid & 63) == 0) { red[(tid >> 6) * 2] = s; red[(tid >> 6) * 2 + 1] = ss; }
    __syncthreads();
    s  = red[0] + red[2] + red[4] + red[6];
    ss = red[1] + red[3] + red[5] + red[7];
    float mean = s * (1.0f / 1024.0f);
    float var  = ss * (1.0f / 1024.0f) - mean * mean;
    float rs   = rsqrtf(var + 1e-5f);
    float4 gv = ((const float4*)g)[tid];
    float4 bv = ((const float4*)b)[tid];
    ushort4 o4;
    o4.x = f2bf((v.x - mean) * rs * gv.x + bv.x);
    o4.y = f2bf((v.y - mean) * rs * gv.y + bv.y);
    o4.z = f2bf((v.z - mean) * rs * gv.z + bv.z);
    o4.w = f2bf((v.w - mean) * rs * gv.w + bv.w);
    ((ushort4*)(out + (size_t)row * 1024))[tid] = o4;
}

// ---------- transpose V (bf16): qkv v-part [L=4096][ld 3072, off 2048] -> vt[1024][4096] ----------
__global__ __launch_bounds__(256) void tvt_kernel(const unsigned short* __restrict__ in,
                                                  unsigned short* __restrict__ out) {
    __shared__ unsigned short tile[64][72];
    int t = threadIdx.x;
    int l0 = blockIdx.x * 64, c0 = blockIdx.y * 64;
    int tr = t >> 3, tc = (t & 7) * 8;
#pragma unroll
    for (int s = 0; s < 2; ++s) {
        int r = tr + s * 32;
        s16x8 v = *(const s16x8*)(in + (size_t)(l0 + r) * 3072 + 2048 + c0 + tc);
        *(s16x8*)(&tile[r][tc]) = v;
    }
    __syncthreads();
#pragma unroll
    for (int s = 0; s < 2; ++s) {
        int c = tr + s * 32;
        s16x8 w;
#pragma unroll
        for (int e = 0; e < 8; ++e) w[e] = (short)tile[tc + e][c];
        *(s16x8*)(out + (size_t)(c0 + c) * 4096 + l0 + tc) = w;
    }
}

// ---------- legacy 128x128 GEMM (kept for Wo projection) ----------
#define BM 128
#define BN 128
#define BKK 64

template <int EPI>
__global__ __launch_bounds__(256) void gemm_kernel(const unsigned short* __restrict__ A,
                                                   const unsigned short* __restrict__ Bt,
                                                   void* __restrict__ C,
                                                   const float* __restrict__ bias,
                                                   const float* __restrict__ resid,
                                                   int M, int N, int K) {
    __shared__ __align__(16) unsigned short sA[BM * BKK];
    __shared__ __align__(16) unsigned short sB[BN * BKK];

    const int tid  = threadIdx.x;
    const int wv   = tid >> 6;
    const int lane = tid & 63;
    const int wr   = wv >> 1, wc = wv & 1;
    const int lg   = lane >> 4;
    const int l15  = lane & 15;

    const int brow = blockIdx.y * BM;
    const int bcol = blockIdx.x * BN;

    f32x4 acc[4][4] = {};

    const int l8 = lane >> 3;
    const int lc = (lane & 7) * 8;

    for (int kt = 0; kt < K; kt += BKK) {
        __syncthreads();
#pragma unroll
        for (int q = 0; q < 4; ++q) {
            int ch = 4 * wv + q;
            const unsigned short* srcA = A + (size_t)(brow + 8 * ch + l8) * K + kt + lc;
            __builtin_amdgcn_global_load_lds((const __attribute__((address_space(1))) void*)srcA,
                                             (__attribute__((address_space(3))) void*)(sA + ch * 512),
                                             16, 0, 0);
        }
#pragma unroll
        for (int q = 0; q < 4; ++q) {
            int ch = 4 * wv + q;
            const unsigned short* srcB = Bt + (size_t)(bcol + 8 * ch + l8) * K + kt + lc;
            __builtin_amdgcn_global_load_lds((const __attribute__((address_space(1))) void*)srcB,
                                             (__attribute__((address_space(3))) void*)(sB + ch * 512),
                                             16, 0, 0);
        }
        __syncthreads();

        bf16x8 af[4][2], bfr[4][2];
#pragma unroll
        for (int mi = 0; mi < 4; ++mi)
#pragma unroll
            for (int kk = 0; kk < 2; ++kk)
                af[mi][kk] = *(const bf16x8*)(sA + (wr * 64 + mi * 16 + l15) * BKK + lg * 8 + kk * 32);
#pragma unroll
        for (int ni = 0; ni < 4; ++ni)
#pragma unroll
            for (int kk = 0; kk < 2; ++kk)
                bfr[ni][kk] = *(const bf16x8*)(sB + (wc * 64 + ni * 16 + l15) * BKK + lg * 8 + kk * 32);

#pragma unroll
        for (int kk = 0; kk < 2; ++kk)
#pragma unroll
            for (int mi = 0; mi < 4; ++mi)
#pragma unroll
                for (int ni = 0; ni < 4; ++ni)
                    acc[mi][ni] = __builtin_amdgcn_mfma_f32_16x16x32_bf16(af[mi][kk], bfr[ni][kk],
                                                                          acc[mi][ni], 0, 0, 0);
    }

#pragma unroll
    for (int mi = 0; mi < 4; ++mi)
#pragma unroll
        for (int ni = 0; ni < 4; ++ni)
#pragma unroll
            for (int r = 0; r < 4; ++r) {
                int row = brow + wr * 64 + mi * 16 + lg * 4 + r;
                int col = bcol + wc * 64 + ni * 16 + l15;
                size_t idx = (size_t)row * N + col;
                float v = acc[mi][ni][r];
                if (EPI == 0) {
                    ((unsigned short*)C)[idx] = f2bf(v);
                } else if (EPI == 1) {
                    ((float*)C)[idx] = v + resid[idx];
                } else if (EPI == 2) {
                    v += bias[col];
                    ((unsigned short*)C)[idx] = f2bf(gelu_tanh(v));
                } else {
                    ((float*)C)[idx] = v + bias[col] + resid[idx];
                }
            }
}

// ---------- 256x256 8-phase GEMM (T1+T2+T3+T4+T5) ----------
__device__ __forceinline__ void stage64(const unsigned short* __restrict__ mat, int ld,
                                        int grow0, int kcol,
                                        unsigned short* lds_tile, int q, int wave, int lane) {
    const int l8 = lane >> 3;
    const int sc = ((lane & 7) ^ l8) << 3;      // pre-swizzled global source (rule 21)
    const unsigned short* src = mat + (size_t)(grow0 + q * 64 + wave * 8 + l8) * ld + kcol + sc;
    unsigned short* dst = lds_tile + ((q * 64 + wave * 8) << 6);   // wave-uniform, linear
    __builtin_amdgcn_global_load_lds((const __attribute__((address_space(1))) void*)src,
                                     (__attribute__((address_space(3))) void*)dst, 16, 0, 0);
}

__device__ __forceinline__ bf16x8 ldfrag(const unsigned short* tile, int row, int chunk) {
    return *(const bf16x8*)(tile + (row << 6) + (((chunk ^ row) & 7) << 3));  // swizzled read
}

template <int EPI>
__global__ __launch_bounds__(512, 2) void gemm256_kernel(
        const unsigned short* __restrict__ A, int lda,
        const unsigned short* __restrict__ Bt, int ldb,
        void* __restrict__ Cv, const float* __restrict__ bias,
        int ldc, int NT, int gm, int gn, unsigned long long slab_stride) {
    extern __shared__ unsigned short lds[];
    unsigned short* sA = lds;                  // [2][256*64]
    unsigned short* sB = lds + 2 * 256 * 64;   // [2][256*64]

    const int tid  = threadIdx.x;
    const int wave = tid >> 6, lane = tid & 63;
    const int wr = wave >> 2, wc = wave & 3;       // 2 x 4 wave grid
    const int lg = lane >> 4, l15 = lane & 15;

    // bijective XCD swizzle (m204)
    const int nwg = gridDim.x;
    const int bid = blockIdx.x;
    const int q8 = nwg >> 3, r8 = nwg & 7;
    const int xcd = bid & 7, loc = bid >> 3;
    const int swz = (xcd < r8 ? xcd * (q8 + 1) : r8 * (q8 + 1) + (xcd - r8) * q8) + loc;
    const int split = swz / (gm * gn);
    const int rem   = swz % (gm * gn);
    const int brow = (rem / gn) << 8;
    const int bcol = (rem % gn) << 8;
    const int kbase = split * (NT << 6);

    f32x4 acc[8][4] = {};

#define STAGE_A(tt, q_, pbuf) stage64(A, lda, brow, kbase + ((tt) << 6), sA + (pbuf) * 16384, (q_), wave, lane)
#define STAGE_B(tt, q_, pbuf) stage64(Bt, ldb, bcol, kbase + ((tt) << 6), sB + (pbuf) * 16384, (q_), wave, lane)

    STAGE_A(0, 0, 0); STAGE_A(0, 1, 0); STAGE_A(0, 2, 0); STAGE_A(0, 3, 0);
    STAGE_B(0, 0, 0); STAGE_B(0, 1, 0); STAGE_B(0, 2, 0); STAGE_B(0, 3, 0);
    STAGE_A(1, 0, 1); STAGE_A(1, 1, 1); STAGE_A(1, 2, 1); STAGE_A(1, 3, 1);
    STAGE_B(1, 0, 1); STAGE_B(1, 1, 1);
    asm volatile("s_waitcnt vmcnt(6)" ::: "memory");   // t0 fully landed
    __builtin_amdgcn_s_barrier();

    for (int t = 0; t < NT; ++t) {
        const int p = t & 1;
        const unsigned short* tA = sA + p * 16384;
        const unsigned short* tB = sB + p * 16384;
        bf16x8 a0[4][2], a1[4][2], b0[2][2], b1[2][2];

        // ---- phase 1: quadrant (mh0, nh0)
#pragma unroll
        for (int im = 0; im < 4; ++im)
#pragma unroll
            for (int kk = 0; kk < 2; ++kk)
                a0[im][kk] = ldfrag(tA, wr * 128 + im * 16 + l15, lg + kk * 4);
#pragma unroll
        for (int in = 0; in < 2; ++in)
#pragma unroll
            for (int kk = 0; kk < 2; ++kk)
                b0[in][kk] = ldfrag(tB, wc * 64 + in * 16 + l15, lg + kk * 4);
        if (t + 1 < NT) { STAGE_B(t + 1, 2, p ^ 1); STAGE_B(t + 1, 3, p ^ 1); }
        __builtin_amdgcn_s_barrier();
        asm volatile("s_waitcnt lgkmcnt(0)" ::: "memory");
        __builtin_amdgcn_sched_barrier(0);
        __builtin_amdgcn_s_setprio(1);
#pragma unroll
        for (int kk = 0; kk < 2; ++kk)
#pragma unroll
            for (int im = 0; im < 4; ++im)
#pragma unroll
                for (int in = 0; in < 2; ++in)
                    acc[im][in] = __builtin_amdgcn_mfma_f32_16x16x32_bf16(a0[im][kk], b0[in][kk], acc[im][in], 0, 0, 0);
        __builtin_amdgcn_s_setprio(0);
        __builtin_amdgcn_s_barrier();

        // ---- phase 2: (mh1, nh0)
#pragma unroll
        for (int im = 0; im < 4; ++im)
#pragma unroll
            for (int kk = 0; kk < 2; ++kk)
                a1[im][kk] = ldfrag(tA, wr * 128 + 64 + im * 16 + l15, lg + kk * 4);
        if (t + 2 < NT) { STAGE_A(t + 2, 0, p); STAGE_A(t + 2, 2, p); }
        __builtin_amdgcn_s_barrier();
        asm volatile("s_waitcnt lgkmcnt(0)" ::: "memory");
        __builtin_amdgcn_sched_barrier(0);
        __builtin_amdgcn_s_setprio(1);
#pragma unroll
        for (int kk = 0; kk < 2; ++kk)
#pragma unroll
            for (int im = 0; im < 4; ++im)
#pragma unroll
                for (int in = 0; in < 2; ++in)
                    acc[4 + im][in] = __builtin_amdgcn_mfma_f32_16x16x32_bf16(a1[im][kk], b0[in][kk], acc[4 + im][in], 0, 0, 0);
        __builtin_amdgcn_s_setprio(0);
        __builtin_amdgcn_s_barrier();

        // ---- phase 3: (mh1, nh1)
#pragma unroll
        for (int in = 0; in < 2; ++in)
#pragma unroll
            for (int kk = 0; kk < 2; ++kk)
                b1[in][kk] = ldfrag(tB, wc * 64 + 32 + in * 16 + l15, lg + kk * 4);
        if (t + 2 < NT) { STAGE_A(t + 2, 1, p); STAGE_A(t + 2, 3, p); }
        __builtin_amdgcn_s_barrier();
        asm volatile("s_waitcnt lgkmcnt(0)" ::: "memory");
        __builtin_amdgcn_sched_barrier(0);
        __builtin_amdgcn_s_setprio(1);
#pragma unroll
        for (int kk = 0; kk < 2; ++kk)
#pragma unroll
            for (int im = 0; im < 4; ++im)
#pragma unroll
                for (int in = 0; in < 2; ++in)
                    acc[4 + im][2 + in] = __builtin_amdgcn_mfma_f32_16x16x32_bf16(a1[im][kk], b1[in][kk], acc[4 + im][2 + in], 0, 0, 0);
        __builtin_amdgcn_s_setprio(0);
        __builtin_amdgcn_s_barrier();

        // ---- phase 4: (mh0, nh1)
        if (t + 2 < NT) { STAGE_B(t + 2, 0, p); STAGE_B(t + 2, 1, p); }
        __builtin_amdgcn_s_barrier();
        asm volatile("s_waitcnt lgkmcnt(0)" ::: "memory");
        __builtin_amdgcn_sched_barrier(0);
        __builtin_amdgcn_s_setprio(1);
#pragma unroll
        for (int kk = 0; kk < 2; ++kk)
#pragma unroll
            for (int im = 0; im < 4; ++im)
#pragma unroll
                for (int in = 0; in < 2; ++in)
                    acc[im][2 + in] = __builtin_amdgcn_mfma_f32_16x16x32_bf16(a0[im][kk], b1[in][kk], acc[im][2 + in], 0, 0, 0);
        __builtin_amdgcn_s_setprio(0);
        if (t + 2 < NT) asm volatile("s_waitcnt vmcnt(6)" ::: "memory");
        else            asm volatile("s_waitcnt vmcnt(0)" ::: "memory");
        __builtin_amdgcn_s_barrier();
    }
#undef STAGE_A
#undef STAGE_B

#pragma unroll
    for (int mi = 0; mi < 8; ++mi)
#pragma unroll
        for (int ni = 0; ni < 4; ++ni)
#pragma unroll
            for (int rr = 0; rr < 4; ++rr) {
                int row = brow + wr * 128 + mi * 16 + lg * 4 + rr;
                int col = bcol + wc * 64 + ni * 16 + l15;
                float v = acc[mi][ni][rr];
                if (EPI == 0) {
                    ((unsigned short*)Cv)[(size_t)row * ldc + col] = f2bf(v);
                } else if (EPI == 2) {
                    v += bias[col];
                    ((unsigned short*)Cv)[(size_t)row * ldc + col] = f2bf(gelu_tanh(v));
                } else {
                    ((unsigned short*)Cv)[slab_stride * split + (size_t)row * ldc + col] = f2bf(v);
                }
            }
}

// ---------- split-K reduce: out = sum(4 bf16 slabs) + bias + resid ----------
__global__ __launch_bounds__(256) void reduce4_kernel(const unsigned short* __restrict__ part,
                                                      const float* __restrict__ bias,
                                                      const float* __restrict__ resid,
                                                      float* __restrict__ out) {
    int i4 = blockIdx.x * 256 + threadIdx.x;       // float4 index over [4096][1024]
    float4 r  = ((const float4*)resid)[i4];
    float4 bb = ((const float4*)bias)[i4 & 255];
    float s0 = r.x + bb.x, s1 = r.y + bb.y, s2 = r.z + bb.z, s3 = r.w + bb.w;
#pragma unroll
    for (int s = 0; s < 4; ++s) {
        ushort4 u = ((const ushort4*)(part + (size_t)s * 4194304))[i4];
        s0 += __uint_as_float((unsigned)u.x << 16);
        s1 += __uint_as_float((unsigned)u.y << 16);
        s2 += __uint_as_float((unsigned)u.z << 16);
        s3 += __uint_as_float((unsigned)u.w << 16);
    }
    float4 o; o.x = s0; o.y = s1; o.z = s2; o.w = s3;
    ((float4*)out)[i4] = o;
}

// ---------- band attention v2: 2 q-blocks/WG, 2 waves per q-block, dbuf K/V ----------
// stage 8 rows x 64 cols (128B/row) with chunk-swizzle; LDS dest wave-uniform
__device__ __forceinline__ void stage8(const unsigned short* __restrict__ src_row0, int ld,
                                       unsigned short* ldsdst, int lane) {
    const int r8 = lane >> 3;
    const int c  = (lane & 7) ^ r8;                 // pre-swizzled source chunk
    const unsigned short* src = src_row0 + (size_t)r8 * ld + c * 8;
    __builtin_amdgcn_global_load_lds((const __attribute__((address_space(1))) void*)src,
                                     (__attribute__((address_space(3))) void*)ldsdst, 16, 0, 0);
}

__global__ __launch_bounds__(256, 2) void attn2_kernel(const unsigned short* __restrict__ qkv, // [4096][3072]
                                                       const unsigned short* __restrict__ vt,  // [1024][4096]
                                                       const float* __restrict__ rel_emb,      // [258][16]
                                                       unsigned short* __restrict__ outp) {    // [4096][1024]
    // XCD-contiguous remap: each XCD gets 2 h-columns, strips in order
    const int lid   = blockIdx.y * gridDim.x + blockIdx.x;    // 0..511
    const int rid   = (lid & 7) * 64 + (lid >> 3);
    const int h     = rid >> 5;
    const int strip = rid & 31;
    const int n0    = strip * 2;

    const int tid  = threadIdx.x;
    const int wv   = tid >> 6;
    const int lane = tid & 63;
    const int qb   = wv >> 1;          // query block within strip (0,1)
    const int half = wv & 1;           // row half within q-block
    const int lg   = lane >> 4;
    const int l15  = lane & 15;
    const int nq   = n0 + qb;

    __shared__ __align__(16) unsigned short sK[2][4096];
    __shared__ __align__(16) unsigned short sV[2][4096];
    __shared__ __align__(16) unsigned short sP[4][2048];   // per-wave P; aliased as Q staging
    __shared__ float sRelF[258];

    unsigned short* sQ  = &sP[0][0];                       // [128][64]
    unsigned short* sPw = &sP[wv][0];                      // [32][64]

    for (int i = tid; i < 258; i += 256) sRelF[i] = rel_emb[i * 16 + h];
    const float relC = rel_emb[257 * 16 + h];              // woff>=5 constant bias

    const int tlo = (n0 >= 15) ? 0 : (15 - n0);

    // ---- prologue: stage Q (4 issues), then K/V for tlo (4 issues)
#pragma unroll
    for (int s = 0; s < 4; ++s) {
        int r0 = wv * 32 + s * 8;
        stage8(qkv + (size_t)(n0 * 64 + r0) * 3072 + h * 64, 3072, sQ + r0 * 64, lane);
    }
    {
        const int src = n0 - 15 + tlo;
#pragma unroll
        for (int s = 0; s < 2; ++s) {
            int r0 = wv * 16 + s * 8;
            stage8(qkv + (size_t)(src * 64 + r0) * 3072 + 1024 + h * 64, 3072, &sK[0][r0 * 64], lane);
            stage8(vt + (size_t)(h * 64 + r0) * 4096 + src * 64, 4096, &sV[0][r0 * 64], lane);
        }
    }
    asm volatile("s_waitcnt vmcnt(4)" ::: "memory");       // Q landed (K/V tlo in flight)
    __builtin_amdgcn_s_barrier();

    bf16x8 qf[2][2];
#pragma unroll
    for (int mi = 0; mi < 2; ++mi)
#pragma unroll
        for (int kk = 0; kk < 2; ++kk)
            qf[mi][kk] = ldfrag(sQ, qb * 64 + half * 32 + mi * 16 + l15, lg + kk * 4);
    asm volatile("s_waitcnt lgkmcnt(0)" ::: "memory");
    __builtin_amdgcn_sched_barrier(0);
    __builtin_amdgcn_s_barrier();                          // sQ region now reusable as sP

    f32x4 oacc[2][4] = {};
    float mrow[2][4], lrow[2][4];
#pragma unroll
    for (int mi = 0; mi < 2; ++mi)
#pragma unroll
        for (int rr = 0; rr < 4; ++rr) { mrow[mi][rr] = -1e30f; lrow[mi][rr] = 0.f; }

    for (int t = tlo; t <= 16; ++t) {
        const int cur = (t - tlo) & 1;
        if (t < 16) {
            const int src = n0 - 15 + (t + 1);
#pragma unroll
            for (int s = 0; s < 2; ++s) {
                int r0 = wv * 16 + s * 8;
                stage8(qkv + (size_t)(src * 64 + r0) * 3072 + 1024 + h * 64, 3072, &sK[cur ^ 1][r0 * 64], lane);
                stage8(vt + (size_t)(h * 64 + r0) * 4096 + src * 64, 4096, &sV[cur ^ 1][r0 * 64], lane);
            }
            asm volatile("s_waitcnt vmcnt(4)" ::: "memory");   // t's K/V landed, t+1 in flight
        } else {
            asm volatile("s_waitcnt vmcnt(0)" ::: "memory");
        }
        __builtin_amdgcn_s_barrier();

        const bool act = (t >= qb) && (t - qb <= 15);
        if (act) {
            const unsigned short* tK = &sK[cur][0];
            const unsigned short* tV = &sV[cur][0];
            const int woff = 15 + qb - t;                  // 0 = diagonal tile

            // ---- QK^T: 16 MFMA
            f32x4 s[2][4] = {};
            __builtin_amdgcn_s_setprio(1);
#pragma unroll
            for (int jt = 0; jt < 4; ++jt) {
                bf16x8 kf0 = ldfrag(tK, jt * 16 + l15, lg);
                bf16x8 kf1 = ldfrag(tK, jt * 16 + l15, lg + 4);
#pragma unroll
                for (int mi = 0; mi < 2; ++mi) {
                    s[mi][jt] = __builtin_amdgcn_mfma_f32_16x16x32_bf16(qf[mi][0], kf0, s[mi][jt], 0, 0, 0);
                    s[mi][jt] = __builtin_amdgcn_mfma_f32_16x16x32_bf16(qf[mi][1], kf1, s[mi][jt], 0, 0, 0);
                }
            }
            __builtin_amdgcn_s_setprio(0);

            // ---- bias + mask
            float pm[2][4];
#pragma unroll
            for (int mi = 0; mi < 2; ++mi)
#pragma unroll
                for (int rr = 0; rr < 4; ++rr) pm[mi][rr] = -1e30f;

            if (woff >= 5) {                               // constant bias, no mask
#pragma unroll
                for (int mi = 0; mi < 2; ++mi)
#pragma unroll
                    for (int jt = 0; jt < 4; ++jt)
#pragma unroll
                        for (int rr = 0; rr < 4; ++rr) {
                            float v = s[mi][jt][rr] * 0.125f + relC;
                            s[mi][jt][rr] = v;
                            pm[mi][rr] = fmaxf(pm[mi][rr], v);
                        }
            } else if (woff > 0) {                         // per-element rel lookup
#pragma unroll
                for (int mi = 0; mi < 2; ++mi)
#pragma unroll
                    for (int jt = 0; jt < 4; ++jt)
#pragma unroll
                        for (int rr = 0; rr < 4; ++rr) {
                            int i = half * 32 + mi * 16 + lg * 4 + rr;
                            int j = jt * 16 + l15;
                            int relid = min(woff * 64 + i - j, 256) + 1;
                            float v = s[mi][jt][rr] * 0.125f + sRelF[relid];
                            s[mi][jt][rr] = v;
                            pm[mi][rr] = fmaxf(pm[mi][rr], v);
                        }
            } else {                                       // diagonal: mask j>i
#pragma unroll
                for (int mi = 0; mi < 2; ++mi)
#pragma unroll
                    for (int jt = 0; jt < 4; ++jt)
#pragma unroll
                        for (int rr = 0; rr < 4; ++rr) {
                            int i = half * 32 + mi * 16 + lg * 4 + rr;
                            int j = jt * 16 + l15;
                            float v = (j <= i) ? (s[mi][jt][rr] * 0.125f + sRelF[i - j + 1]) : -1e30f;
                            s[mi][jt][rr] = v;
                            pm[mi][rr] = fmaxf(pm[mi][rr], v);
                        }
            }

            // ---- online softmax (rows keyed by (lg,rr); reduce over l15)
            float scl[2][4], rs[2][4];
#pragma unroll
            for (int mi = 0; mi < 2; ++mi)
#pragma unroll
                for (int rr = 0; rr < 4; ++rr) {
                    float v = pm[mi][rr];
                    v = fmaxf(v, __shfl_xor(v, 1)); v = fmaxf(v, __shfl_xor(v, 2));
                    v = fmaxf(v, __shfl_xor(v, 4)); v = fmaxf(v, __shfl_xor(v, 8));
                    float mn = fmaxf(mrow[mi][rr], v);
                    scl[mi][rr] = __expf(mrow[mi][rr] - mn);
                    mrow[mi][rr] = mn;
                    rs[mi][rr] = 0.f;
                }
#pragma unroll
            for (int mi = 0; mi < 2; ++mi)
#pragma unroll
                for (int jt = 0; jt < 4; ++jt)
#pragma unroll
                    for (int rr = 0; rr < 4; ++rr) {
                        float p = __expf(s[mi][jt][rr] - mrow[mi][rr]);
                        rs[mi][rr] += p;
                        int row = mi * 16 + lg * 4 + rr, col = jt * 16 + l15;
                        sPw[(row << 6) + ((((col >> 3) ^ row) & 7) << 3) + (col & 7)] = f2bf(p);
                    }
#pragma unroll
            for (int mi = 0; mi < 2; ++mi)
#pragma unroll
                for (int rr = 0; rr < 4; ++rr) {
                    float v = rs[mi][rr];
                    v += __shfl_xor(v, 1); v += __shfl_xor(v, 2);
                    v += __shfl_xor(v, 4); v += __shfl_xor(v, 8);
                    lrow[mi][rr] = lrow[mi][rr] * scl[mi][rr] + v;
                }
#pragma unroll
            for (int mi = 0; mi < 2; ++mi)
#pragma unroll
                for (int dt = 0; dt < 4; ++dt)
#pragma unroll
                    for (int rr = 0; rr < 4; ++rr)
                        oacc[mi][dt][rr] *= scl[mi][rr];

            // ---- PV: 16 MFMA (P is wave-private; compiler orders LDS write->read)
            bf16x8 pf[2][2];
#pragma unroll
            for (int mi = 0; mi < 2; ++mi)
#pragma unroll
                for (int kk = 0; kk < 2; ++kk)
                    pf[mi][kk] = ldfrag(sPw, mi * 16 + l15, lg + kk * 4);
            __builtin_amdgcn_s_setprio(1);
#pragma unroll
            for (int dt = 0; dt < 4; ++dt) {
                bf16x8 vf0 = ldfrag(tV, dt * 16 + l15, lg);
                bf16x8 vf1 = ldfrag(tV, dt * 16 + l15, lg + 4);
#pragma unroll
                for (int mi = 0; mi < 2; ++mi) {
                    oacc[mi][dt] = __builtin_amdgcn_mfma_f32_16x16x32_bf16(pf[mi][0], vf0, oacc[mi][dt], 0, 0, 0);
                    oacc[mi][dt] = __builtin_amdgcn_mfma_f32_16x16x32_bf16(pf[mi][1], vf1, oacc[mi][dt], 0, 0, 0);
                }
            }
            __builtin_amdgcn_s_setprio(0);
        }
        __builtin_amdgcn_s_barrier();                      // buf[cur] reads done before overwrite
    }

    // ---- epilogue
#pragma unroll
    for (int mi = 0; mi < 2; ++mi)
#pragma unroll
        for (int rr = 0; rr < 4; ++rr) {
            float inv = 1.0f / lrow[mi][rr];
#pragma unroll
            for (int dt = 0; dt < 4; ++dt) {
                size_t row = (size_t)(nq * 64 + half * 32 + mi * 16 + lg * 4 + rr);
                outp[row * 1024 + h * 64 + dt * 16 + l15] = f2bf(oacc[mi][dt][rr] * inv);
            }
        }
}

// ---------- launch ----------
extern "C" void kernel_launch(void* const* d_in, const int* in_sizes, int n_in,
                              void* d_out, int out_size, void* d_ws, size_t ws_size,
                              hipStream_t stream) {
    const float* x    = (const float*)d_in[0];
    const float* Wq   = (const float*)d_in[1];
    const float* Wk   = (const float*)d_in[2];
    const float* Wv   = (const float*)d_in[3];
    const float* Wo   = (const float*)d_in[4];
    const float* rel  = (const float*)d_in[5];
    const float* ln1g = (const float*)d_in[6];
    const float* ln1b = (const float*)d_in[7];
    const float* ln2g = (const float*)d_in[8];
    const float* ln2b = (const float*)d_in[9];
    const float* W1   = (const float*)d_in[10];
    const float* b1   = (const float*)d_in[11];
    const float* W2   = (const float*)d_in[12];
    const float* b2   = (const float*)d_in[13];

    char* ws = (char*)d_ws;
    unsigned short* wqkvT = (unsigned short*)(ws + 0);          //  6 MB   [dead after QKV]
    unsigned short* woT   = (unsigned short*)(ws + 6291456);    //  2 MB   [dead after Wo]
    unsigned short* attnb = (unsigned short*)(ws + 8388608);    //  8 MB   [dead after Wo]
    unsigned short* w1T   = (unsigned short*)(ws + 16777216);   //  8 MB   [dead after FFN1]
    unsigned short* hbuf  = (unsigned short*)(ws + 25165824);   //  8 MB   [dead after FFN1]
    unsigned short* w2T   = (unsigned short*)(ws + 33554432);   //  8 MB
    float*          x2    = (float*)(ws + 41943040);            // 16 MB
    unsigned short* qkv   = (unsigned short*)(ws + 58720256);   // 24 MB   [dead after attn]
    unsigned short* vt    = (unsigned short*)(ws + 83886080);   //  8 MB   [dead after attn]
    unsigned short* gbuf  = (unsigned short*)(ws + 58720256);   // 32 MB   (reuses qkv+vt)
    unsigned short* part  = (unsigned short*)(ws + 0);          // 32 MB   (reuses 0..32MB)

    const int smem = 131072;
    hipFuncSetAttribute((const void*)gemm256_kernel<0>, hipFuncAttributeMaxDynamicSharedMemorySize, smem);
    hipFuncSetAttribute((const void*)gemm256_kernel<2>, hipFuncAttributeMaxDynamicSharedMemorySize, smem);
    hipFuncSetAttribute((const void*)gemm256_kernel<4>, hipFuncAttributeMaxDynamicSharedMemorySize, smem);

    dim3 tb(32, 8);
    tcvt_kernel<<<dim3(32, 32), tb, 0, stream>>>(Wq, wqkvT, 1024, 1024);
    tcvt_kernel<<<dim3(32, 32), tb, 0, stream>>>(Wk, wqkvT + 1048576, 1024, 1024);
    tcvt_kernel<<<dim3(32, 32), tb, 0, stream>>>(Wv, wqkvT + 2097152, 1024, 1024);
    tcvt_kernel<<<dim3(32, 32), tb, 0, stream>>>(Wo, woT, 1024, 1024);
    tcvt_kernel<<<dim3(128, 32), tb, 0, stream>>>(W1, w1T, 1024, 4096);
    tcvt_kernel<<<dim3(32, 128), tb, 0, stream>>>(W2, w2T, 4096, 1024);

    ln_kernel<<<4096, 256, 0, stream>>>(x, ln1g, ln1b, hbuf);

    // QKV: [4096,1024] x [3072,1024]^T -> qkv
    gemm256_kernel<0><<<192, 512, smem, stream>>>(hbuf, 1024, wqkvT, 1024, qkv,
                                                  nullptr, 3072, 16, 16, 12, 0ULL);

    tvt_kernel<<<dim3(64, 16), 256, 0, stream>>>(qkv, vt);

    attn2_kernel<<<dim3(32, 16), 256, 0, stream>>>(qkv, vt, rel, attnb);

    // Wo projection + residual (legacy 128^2 kernel)
    gemm_kernel<1><<<dim3(1024 / 128, 4096 / 128), 256, 0, stream>>>(attnb, woT, x2,
                                                                     nullptr, x, 4096, 1024, 1024);

    ln_kernel<<<4096, 256, 0, stream>>>(x2, ln2g, ln2b, hbuf);

    // FFN1: [4096,1024] x [4096,1024]^T + b1, gelu -> gbuf
    gemm256_kernel<2><<<256, 512, smem, stream>>>(hbuf, 1024, w1T, 1024, gbuf,
                                                  b1, 4096, 16, 16, 16, 0ULL);

    // FFN2 split-K=4: [4096,4096] x [1024,4096]^T -> 4 bf16 partial slabs
    gemm256_kernel<4><<<256, 512, smem, stream>>>(gbuf, 4096, w2T, 4096, part,
                                                  nullptr, 1024, 16, 16, 4, 4194304ULL);

    // out = sum(slabs) + b2 + x2
    reduce4_kernel<<<4096, 256, 0, stream>>>(part, b2, x2, (float*)d_out);
}

// Round 7
// 246.595 us; speedup vs baseline: 1.4128x; 1.0669x over previous
//
#include <hip/hip_runtime.h>
#include <math.h>

// ---------- types ----------
typedef __bf16 bf16x8 __attribute__((ext_vector_type(8)));   // MFMA A/B fragment (4 VGPRs)
typedef short  s16x4  __attribute__((ext_vector_type(4)));   // 16x16x16 MFMA A/B fragment (2 VGPRs)
typedef float  f32x4  __attribute__((ext_vector_type(4)));   // MFMA C/D fragment
typedef short  s16x8  __attribute__((ext_vector_type(8)));   // raw 16B data movement

__device__ __forceinline__ unsigned short f2bf(float f) {
    unsigned int u = __float_as_uint(f);
    u += 0x7fffu + ((u >> 16) & 1u);   // round-to-nearest-even
    return (unsigned short)(u >> 16);
}

__device__ __forceinline__ unsigned cvt_pk_bf16(float a, float b) {
    unsigned r;
    asm volatile("v_cvt_pk_bf16_f32 %0, %1, %2" : "=v"(r) : "v"(a), "v"(b));
    return r;
}

// 16x16x16 bf16 MFMA. MUST go through a compiler-known builtin so the MAI
// hazard wait-states (VALU->MFMA SrcC, MFMA D->VALU read) are inserted.
// Inline-asm MFMA gets no hazard s_nops -> nondeterministic corruption (R6).
__device__ __forceinline__ f32x4 mfma16(s16x4 a, s16x4 b, f32x4 c) {
#if __has_builtin(__builtin_amdgcn_mfma_f32_16x16x16bf16_1k)
    return __builtin_amdgcn_mfma_f32_16x16x16bf16_1k(a, b, c, 0, 0, 0);
#else
    // fallback: explicit wait-state padding around the raw instruction
    asm volatile("s_nop 3\n\t"
                 "v_mfma_f32_16x16x16_bf16 %0, %1, %2, %0\n\t"
                 "s_nop 7\n\t"
                 "s_nop 7"
                 : "+v"(c) : "v"(a), "v"(b));
    return c;
#endif
}

__device__ __forceinline__ float gelu_tanh(float x) {
    float x3 = x * x * x;
    float t = tanhf(0.7978845608028654f * (x + 0.044715f * x3));
    return 0.5f * x * (1.0f + t);
}

// ---------- transpose + f32->bf16 convert:  in[K][N] f32  ->  out[N][K] bf16 ----------
__global__ __launch_bounds__(256) void tcvt_kernel(const float* __restrict__ in,
                                                   unsigned short* __restrict__ out,
                                                   int K, int N) {
    __shared__ float tile[32][33];
    int tx = threadIdx.x, ty = threadIdx.y;           // 32 x 8
    int k0 = blockIdx.y * 32, n0 = blockIdx.x * 32;
#pragma unroll
    for (int s = 0; s < 4; ++s)
        tile[ty + s * 8][tx] = in[(size_t)(k0 + ty + s * 8) * N + n0 + tx];
    __syncthreads();
#pragma unroll
    for (int s = 0; s < 4; ++s)
        out[(size_t)(n0 + ty + s * 8) * K + k0 + tx] = f2bf(tile[tx][ty + s * 8]);
}

// ---------- layernorm: x[L][1024] f32 -> out bf16 ----------
__global__ __launch_bounds__(256) void ln_kernel(const float* __restrict__ x,
                                                 const float* __restrict__ g,
                                                 const float* __restrict__ b,
                                                 unsigned short* __restrict__ out) {
    int row = blockIdx.x;
    int tid = threadIdx.x;
    float4 v = ((const float4*)(x + (size_t)row * 1024))[tid];
    float s  = v.x + v.y + v.z + v.w;
    float ss = v.x * v.x + v.y * v.y + v.z * v.z + v.w * v.w;
#pragma unroll
    for (int o = 32; o > 0; o >>= 1) { s += __shfl_down(s, o); ss += __shfl_down(ss, o); }
    __shared__ float red[8];
    if ((tid & 63) == 0) { red[(tid >> 6) * 2] = s; red[(tid >> 6) * 2 + 1] = ss; }
    __syncthreads();
    s  = red[0] + red[2] + red[4] + red[6];
    ss = red[1] + red[3] + red[5] + red[7];
    float mean = s * (1.0f / 1024.0f);
    float var  = ss * (1.0f / 1024.0f) - mean * mean;
    float rs   = rsqrtf(var + 1e-5f);
    float4 gv = ((const float4*)g)[tid];
    float4 bv = ((const float4*)b)[tid];
    ushort4 o4;
    o4.x = f2bf((v.x - mean) * rs * gv.x + bv.x);
    o4.y = f2bf((v.y - mean) * rs * gv.y + bv.y);
    o4.z = f2bf((v.z - mean) * rs * gv.z + bv.z);
    o4.w = f2bf((v.w - mean) * rs * gv.w + bv.w);
    ((ushort4*)(out + (size_t)row * 1024))[tid] = o4;
}

// ---------- transpose V (bf16): qkv v-part [L=4096][ld 3072, off 2048] -> vt[1024][4096] ----------
__global__ __launch_bounds__(256) void tvt_kernel(const unsigned short* __restrict__ in,
                                                  unsigned short* __restrict__ out) {
    __shared__ unsigned short tile[64][72];
    int t = threadIdx.x;
    int l0 = blockIdx.x * 64, c0 = blockIdx.y * 64;
    int tr = t >> 3, tc = (t & 7) * 8;
#pragma unroll
    for (int s = 0; s < 2; ++s) {
        int r = tr + s * 32;
        s16x8 v = *(const s16x8*)(in + (size_t)(l0 + r) * 3072 + 2048 + c0 + tc);
        *(s16x8*)(&tile[r][tc]) = v;
    }
    __syncthreads();
#pragma unroll
    for (int s = 0; s < 2; ++s) {
        int c = tr + s * 32;
        s16x8 w;
#pragma unroll
        for (int e = 0; e < 8; ++e) w[e] = (short)tile[tc + e][c];
        *(s16x8*)(out + (size_t)(c0 + c) * 4096 + l0 + tc) = w;
    }
}

// ---------- shared staging helpers (chunk-XOR swizzle, rule 21) ----------
__device__ __forceinline__ void stage8(const unsigned short* __restrict__ src_row0, int ld,
                                       unsigned short* ldsdst, int lane) {
    const int r8 = lane >> 3;
    const int c  = (lane & 7) ^ r8;                 // pre-swizzled source chunk
    const unsigned short* src = src_row0 + (size_t)r8 * ld + c * 8;
    __builtin_amdgcn_global_load_lds((const __attribute__((address_space(1))) void*)src,
                                     (__attribute__((address_space(3))) void*)ldsdst, 16, 0, 0);
}

__device__ __forceinline__ void stage64(const unsigned short* __restrict__ mat, int ld,
                                        int grow0, int kcol,
                                        unsigned short* lds_tile, int q, int wave, int lane) {
    const int l8 = lane >> 3;
    const int sc = ((lane & 7) ^ l8) << 3;
    const unsigned short* src = mat + (size_t)(grow0 + q * 64 + wave * 8 + l8) * ld + kcol + sc;
    unsigned short* dst = lds_tile + ((q * 64 + wave * 8) << 6);
    __builtin_amdgcn_global_load_lds((const __attribute__((address_space(1))) void*)src,
                                     (__attribute__((address_space(3))) void*)dst, 16, 0, 0);
}

__device__ __forceinline__ bf16x8 ldfrag(const unsigned short* tile, int row, int chunk) {
    return *(const bf16x8*)(tile + (row << 6) + (((chunk ^ row) & 7) << 3));  // swizzled read
}

__device__ __forceinline__ s16x4 ldfrag64(const unsigned short* tile, int row, int ch16, int half) {
    return *(const s16x4*)(tile + (row << 6) + (((ch16 ^ row) & 7) << 3) + (half << 2));
}

// ---------- 256x256 8-phase GEMM (T1+T2+T3+T4+T5) ----------
// EPI 0: bf16 store; EPI 2: +bias, gelu, bf16; EPI 4: bf16 partial to slab[split]
template <int EPI>
__global__ __launch_bounds__(512, 2) void gemm256_kernel(
        const unsigned short* __restrict__ A, int lda,
        const unsigned short* __restrict__ Bt, int ldb,
        void* __restrict__ Cv, const float* __restrict__ bias,
        int ldc, int NT, int gm, int gn, unsigned long long slab_stride) {
    extern __shared__ unsigned short lds[];
    unsigned short* sA = lds;                  // [2][256*64]
    unsigned short* sB = lds + 2 * 256 * 64;   // [2][256*64]

    const int tid  = threadIdx.x;
    const int wave = tid >> 6, lane = tid & 63;
    const int wr = wave >> 2, wc = wave & 3;       // 2 x 4 wave grid
    const int lg = lane >> 4, l15 = lane & 15;

    // bijective XCD swizzle (m204)
    const int nwg = gridDim.x;
    const int bid = blockIdx.x;
    const int q8 = nwg >> 3, r8 = nwg & 7;
    const int xcd = bid & 7, loc = bid >> 3;
    const int swz = (xcd < r8 ? xcd * (q8 + 1) : r8 * (q8 + 1) + (xcd - r8) * q8) + loc;
    const int split = swz / (gm * gn);
    const int rem   = swz % (gm * gn);
    const int brow = (rem / gn) << 8;
    const int bcol = (rem % gn) << 8;
    const int kbase = split * (NT << 6);

    f32x4 acc[8][4] = {};

#define STAGE_A(tt, q_, pbuf) stage64(A, lda, brow, kbase + ((tt) << 6), sA + (pbuf) * 16384, (q_), wave, lane)
#define STAGE_B(tt, q_, pbuf) stage64(Bt, ldb, bcol, kbase + ((tt) << 6), sB + (pbuf) * 16384, (q_), wave, lane)

    STAGE_A(0, 0, 0); STAGE_A(0, 1, 0); STAGE_A(0, 2, 0); STAGE_A(0, 3, 0);
    STAGE_B(0, 0, 0); STAGE_B(0, 1, 0); STAGE_B(0, 2, 0); STAGE_B(0, 3, 0);
    STAGE_A(1, 0, 1); STAGE_A(1, 1, 1); STAGE_A(1, 2, 1); STAGE_A(1, 3, 1);
    STAGE_B(1, 0, 1); STAGE_B(1, 1, 1);
    asm volatile("s_waitcnt vmcnt(6)" ::: "memory");   // t0 fully landed
    __builtin_amdgcn_s_barrier();

    for (int t = 0; t < NT; ++t) {
        const int p = t & 1;
        const unsigned short* tA = sA + p * 16384;
        const unsigned short* tB = sB + p * 16384;
        bf16x8 a0[4][2], a1[4][2], b0[2][2], b1[2][2];

        // ---- phase 1: quadrant (mh0, nh0)
#pragma unroll
        for (int im = 0; im < 4; ++im)
#pragma unroll
            for (int kk = 0; kk < 2; ++kk)
                a0[im][kk] = ldfrag(tA, wr * 128 + im * 16 + l15, lg + kk * 4);
#pragma unroll
        for (int in = 0; in < 2; ++in)
#pragma unroll
            for (int kk = 0; kk < 2; ++kk)
                b0[in][kk] = ldfrag(tB, wc * 64 + in * 16 + l15, lg + kk * 4);
        if (t + 1 < NT) { STAGE_B(t + 1, 2, p ^ 1); STAGE_B(t + 1, 3, p ^ 1); }
        __builtin_amdgcn_s_barrier();
        asm volatile("s_waitcnt lgkmcnt(0)" ::: "memory");
        __builtin_amdgcn_sched_barrier(0);
        __builtin_amdgcn_s_setprio(1);
#pragma unroll
        for (int kk = 0; kk < 2; ++kk)
#pragma unroll
            for (int im = 0; im < 4; ++im)
#pragma unroll
                for (int in = 0; in < 2; ++in)
                    acc[im][in] = __builtin_amdgcn_mfma_f32_16x16x32_bf16(a0[im][kk], b0[in][kk], acc[im][in], 0, 0, 0);
        __builtin_amdgcn_s_setprio(0);
        __builtin_amdgcn_s_barrier();

        // ---- phase 2: (mh1, nh0)
#pragma unroll
        for (int im = 0; im < 4; ++im)
#pragma unroll
            for (int kk = 0; kk < 2; ++kk)
                a1[im][kk] = ldfrag(tA, wr * 128 + 64 + im * 16 + l15, lg + kk * 4);
        if (t + 2 < NT) { STAGE_A(t + 2, 0, p); STAGE_A(t + 2, 2, p); }
        __builtin_amdgcn_s_barrier();
        asm volatile("s_waitcnt lgkmcnt(0)" ::: "memory");
        __builtin_amdgcn_sched_barrier(0);
        __builtin_amdgcn_s_setprio(1);
#pragma unroll
        for (int kk = 0; kk < 2; ++kk)
#pragma unroll
            for (int im = 0; im < 4; ++im)
#pragma unroll
                for (int in = 0; in < 2; ++in)
                    acc[4 + im][in] = __builtin_amdgcn_mfma_f32_16x16x32_bf16(a1[im][kk], b0[in][kk], acc[4 + im][in], 0, 0, 0);
        __builtin_amdgcn_s_setprio(0);
        __builtin_amdgcn_s_barrier();

        // ---- phase 3: (mh1, nh1)
#pragma unroll
        for (int in = 0; in < 2; ++in)
#pragma unroll
            for (int kk = 0; kk < 2; ++kk)
                b1[in][kk] = ldfrag(tB, wc * 64 + 32 + in * 16 + l15, lg + kk * 4);
        if (t + 2 < NT) { STAGE_A(t + 2, 1, p); STAGE_A(t + 2, 3, p); }
        __builtin_amdgcn_s_barrier();
        asm volatile("s_waitcnt lgkmcnt(0)" ::: "memory");
        __builtin_amdgcn_sched_barrier(0);
        __builtin_amdgcn_s_setprio(1);
#pragma unroll
        for (int kk = 0; kk < 2; ++kk)
#pragma unroll
            for (int im = 0; im < 4; ++im)
#pragma unroll
                for (int in = 0; in < 2; ++in)
                    acc[4 + im][2 + in] = __builtin_amdgcn_mfma_f32_16x16x32_bf16(a1[im][kk], b1[in][kk], acc[4 + im][2 + in], 0, 0, 0);
        __builtin_amdgcn_s_setprio(0);
        __builtin_amdgcn_s_barrier();

        // ---- phase 4: (mh0, nh1)
        if (t + 2 < NT) { STAGE_B(t + 2, 0, p); STAGE_B(t + 2, 1, p); }
        __builtin_amdgcn_s_barrier();
        asm volatile("s_waitcnt lgkmcnt(0)" ::: "memory");
        __builtin_amdgcn_sched_barrier(0);
        __builtin_amdgcn_s_setprio(1);
#pragma unroll
        for (int kk = 0; kk < 2; ++kk)
#pragma unroll
            for (int im = 0; im < 4; ++im)
#pragma unroll
                for (int in = 0; in < 2; ++in)
                    acc[im][2 + in] = __builtin_amdgcn_mfma_f32_16x16x32_bf16(a0[im][kk], b1[in][kk], acc[im][2 + in], 0, 0, 0);
        __builtin_amdgcn_s_setprio(0);
        if (t + 2 < NT) asm volatile("s_waitcnt vmcnt(6)" ::: "memory");
        else            asm volatile("s_waitcnt vmcnt(0)" ::: "memory");
        __builtin_amdgcn_s_barrier();
    }
#undef STAGE_A
#undef STAGE_B

#pragma unroll
    for (int mi = 0; mi < 8; ++mi)
#pragma unroll
        for (int ni = 0; ni < 4; ++ni)
#pragma unroll
            for (int rr = 0; rr < 4; ++rr) {
                int row = brow + wr * 128 + mi * 16 + lg * 4 + rr;
                int col = bcol + wc * 64 + ni * 16 + l15;
                float v = acc[mi][ni][rr];
                if (EPI == 0) {
                    ((unsigned short*)Cv)[(size_t)row * ldc + col] = f2bf(v);
                } else if (EPI == 2) {
                    v += bias[col];
                    ((unsigned short*)Cv)[(size_t)row * ldc + col] = f2bf(gelu_tanh(v));
                } else {
                    ((unsigned short*)Cv)[slab_stride * split + (size_t)row * ldc + col] = f2bf(v);
                }
            }
}

// ---------- split-K reduce: out = sum(4 bf16 slabs) [+ bias] + resid ----------
template <int HB>
__global__ __launch_bounds__(256) void reduce4_kernel(const unsigned short* __restrict__ part,
                                                      const float* __restrict__ bias,
                                                      const float* __restrict__ resid,
                                                      float* __restrict__ out) {
    int i4 = blockIdx.x * 256 + threadIdx.x;       // float4 index over [4096][1024]
    float4 r  = ((const float4*)resid)[i4];
    float s0 = r.x, s1 = r.y, s2 = r.z, s3 = r.w;
    if (HB) {
        float4 bb = ((const float4*)bias)[i4 & 255];
        s0 += bb.x; s1 += bb.y; s2 += bb.z; s3 += bb.w;
    }
#pragma unroll
    for (int s = 0; s < 4; ++s) {
        ushort4 u = ((const ushort4*)(part + (size_t)s * 4194304))[i4];
        s0 += __uint_as_float((unsigned)u.x << 16);
        s1 += __uint_as_float((unsigned)u.y << 16);
        s2 += __uint_as_float((unsigned)u.z << 16);
        s3 += __uint_as_float((unsigned)u.w << 16);
    }
    float4 o; o.x = s0; o.y = s1; o.z = s2; o.w = s3;
    ((float4*)out)[i4] = o;
}

// ---------- band attention v3: swapped QK^T, in-register P, 8 waves ----------
// grid 512 (32 strips x 16 heads), 512 threads. Wave wv owns 16 query rows.
__global__ __launch_bounds__(512, 4) void attn3_kernel(const unsigned short* __restrict__ qkv, // [4096][3072]
                                                       const unsigned short* __restrict__ vt,  // [1024][4096]
                                                       const float* __restrict__ rel_emb,      // [258][16]
                                                       unsigned short* __restrict__ outp) {    // [4096][1024]
    const int lid   = blockIdx.y * gridDim.x + blockIdx.x;    // 0..511
    const int rid   = (lid & 7) * 64 + (lid >> 3);            // XCD-contiguous
    const int h     = rid >> 5;
    const int strip = rid & 31;
    const int n0    = strip * 2;

    const int tid  = threadIdx.x;
    const int wv   = tid >> 6;         // 0..7
    const int lane = tid & 63;
    const int qb   = wv >> 2;          // q-block within strip
    const int lg   = lane >> 4;
    const int l15  = lane & 15;
    const int iq   = (wv & 3) * 16 + l15;       // query row within its 64-block
    const int q0   = n0 * 64 + wv * 16;         // wave's first global query row

    __shared__ __align__(16) unsigned short sK[2][4096];
    __shared__ __align__(16) unsigned short sV[2][4096];
    __shared__ float sRelF[258];

    // Q direct to registers as B-fragments: col i = l15 (q0+l15), k = d
    bf16x8 qf[2];
    {
        const unsigned short* qrow = qkv + (size_t)(q0 + l15) * 3072 + h * 64 + lg * 8;
        qf[0] = *(const bf16x8*)(qrow);
        qf[1] = *(const bf16x8*)(qrow + 32);
    }

    for (int i = tid; i < 258; i += 512) sRelF[i] = rel_emb[i * 16 + h];
    const float relC = rel_emb[257 * 16 + h];

    const int tlo = (n0 >= 15) ? 0 : (15 - n0);
    {
        const int src = n0 - 15 + tlo;
        stage8(qkv + (size_t)(src * 64 + wv * 8) * 3072 + 1024 + h * 64, 3072, &sK[0][wv * 8 * 64], lane);
        stage8(vt + (size_t)(h * 64 + wv * 8) * 4096 + src * 64, 4096, &sV[0][wv * 8 * 64], lane);
    }
    asm volatile("s_waitcnt lgkmcnt(0)" ::: "memory");   // sRelF visible
    __builtin_amdgcn_s_barrier();

    f32x4 oacc[4] = {};                 // O^T: d = dt*16+lg*4+rr, i = l15
    float mrow = -3e38f, lrow = 0.f;    // per-lane scalars (single query i)

    for (int t = tlo; t <= 16; ++t) {
        const int cur = (t - tlo) & 1;
        if (t < 16) {
            const int src = n0 - 15 + (t + 1);
            stage8(qkv + (size_t)(src * 64 + wv * 8) * 3072 + 1024 + h * 64, 3072, &sK[cur ^ 1][wv * 8 * 64], lane);
            stage8(vt + (size_t)(h * 64 + wv * 8) * 4096 + src * 64, 4096, &sV[cur ^ 1][wv * 8 * 64], lane);
            asm volatile("s_waitcnt vmcnt(2)" ::: "memory");   // t's K/V landed
        } else {
            asm volatile("s_waitcnt vmcnt(0)" ::: "memory");
        }
        __builtin_amdgcn_s_barrier();

        const bool act = (t >= qb) && (t - qb <= 15);
        if (act) {
            const unsigned short* tK = &sK[cur][0];
            const unsigned short* tV = &sV[cur][0];
            const int woff = 15 + qb - t;                  // 0 = diagonal tile

            // ---- S^T = K·Q^T : C[j][i], 8 MFMA; lane: j = jt*16+lg*4+rr, i = l15
            f32x4 st[4] = {};
            __builtin_amdgcn_s_setprio(1);
#pragma unroll
            for (int jt = 0; jt < 4; ++jt) {
                bf16x8 kf0 = ldfrag(tK, jt * 16 + l15, lg);
                bf16x8 kf1 = ldfrag(tK, jt * 16 + l15, lg + 4);
                st[jt] = __builtin_amdgcn_mfma_f32_16x16x32_bf16(kf0, qf[0], st[jt], 0, 0, 0);
                st[jt] = __builtin_amdgcn_mfma_f32_16x16x32_bf16(kf1, qf[1], st[jt], 0, 0, 0);
            }
            __builtin_amdgcn_s_setprio(0);

            // ---- bias + mask + in-lane max (all 16 values share query iq)
            float pm = -3e38f;
            if (woff >= 5) {
#pragma unroll
                for (int jt = 0; jt < 4; ++jt)
#pragma unroll
                    for (int rr = 0; rr < 4; ++rr) {
                        float v = st[jt][rr] * 0.125f + relC;
                        st[jt][rr] = v;
                        pm = fmaxf(pm, v);
                    }
            } else if (woff > 0) {
#pragma unroll
                for (int jt = 0; jt < 4; ++jt)
#pragma unroll
                    for (int rr = 0; rr < 4; ++rr) {
                        int j = jt * 16 + lg * 4 + rr;
                        int relid = min(woff * 64 + iq - j, 256) + 1;
                        float v = st[jt][rr] * 0.125f + sRelF[relid];
                        st[jt][rr] = v;
                        pm = fmaxf(pm, v);
                    }
            } else {
#pragma unroll
                for (int jt = 0; jt < 4; ++jt)
#pragma unroll
                    for (int rr = 0; rr < 4; ++rr) {
                        int j = jt * 16 + lg * 4 + rr;
                        float v = (j <= iq) ? (st[jt][rr] * 0.125f + sRelF[iq - j + 1]) : -1e30f;
                        st[jt][rr] = v;
                        pm = fmaxf(pm, v);
                    }
            }
            // cross-lg reduce (lanes sharing l15)
            pm = fmaxf(pm, __shfl_xor(pm, 16));
            pm = fmaxf(pm, __shfl_xor(pm, 32));
            float mn  = fmaxf(mrow, pm);
            float scl = __expf(mrow - mn);
            mrow = mn;

            // ---- exp + pack straight into PV B-fragments
            float rs = 0.f;
            unsigned pk0[4], pk1[4];
#pragma unroll
            for (int jt = 0; jt < 4; ++jt) {
                float p0 = __expf(st[jt][0] - mn);
                float p1 = __expf(st[jt][1] - mn);
                float p2 = __expf(st[jt][2] - mn);
                float p3 = __expf(st[jt][3] - mn);
                rs += (p0 + p1) + (p2 + p3);
                pk0[jt] = cvt_pk_bf16(p0, p1);
                pk1[jt] = cvt_pk_bf16(p2, p3);
            }
            rs += __shfl_xor(rs, 16);
            rs += __shfl_xor(rs, 32);
            lrow = lrow * scl + rs;
#pragma unroll
            for (int dt = 0; dt < 4; ++dt)
#pragma unroll
                for (int rr = 0; rr < 4; ++rr)
                    oacc[dt][rr] *= scl;

            // ---- O^T += V^T·P^T : 16 x mfma 16x16x16 (P stays in registers)
            __builtin_amdgcn_s_setprio(1);
#pragma unroll
            for (int ks = 0; ks < 4; ++ks) {
                union { unsigned u[2]; s16x4 v; } pu;
                pu.u[0] = pk0[ks]; pu.u[1] = pk1[ks];
#pragma unroll
                for (int dt = 0; dt < 4; ++dt) {
                    s16x4 vf = ldfrag64(tV, dt * 16 + l15, 2 * ks + (lg >> 1), lg & 1);
                    oacc[dt] = mfma16(vf, pu.v, oacc[dt]);
                }
            }
            __builtin_amdgcn_s_setprio(0);
        }
        __builtin_amdgcn_s_barrier();                      // buf[cur] reads done before overwrite
    }

    // ---- epilogue: normalize, transpose via (dead) sK, coalesced store
    float inv = 1.0f / lrow;
    unsigned short* sO = &sK[0][0] + wv * 1024;            // wave-private [16 i][64 d]
#pragma unroll
    for (int dt = 0; dt < 4; ++dt)
#pragma unroll
        for (int c = 0; c < 2; ++c) {
            unsigned pr = cvt_pk_bf16(oacc[dt][2 * c] * inv, oacc[dt][2 * c + 1] * inv);
            int d  = dt * 16 + lg * 4 + 2 * c;
            int off = (l15 << 6) + ((((d >> 3) ^ (l15 & 7)) & 7) << 3) + (d & 7);
            *(unsigned*)(sO + off) = pr;
        }
#pragma unroll
    for (int c2 = 0; c2 < 2; ++c2) {
        int ch = lg + 4 * c2;
        bf16x8 ov = ldfrag(sO, l15, ch);
        *(s16x8*)(outp + (size_t)(q0 + l15) * 1024 + h * 64 + ch * 8) = *(const s16x8*)&ov;
    }
}

// ---------- launch ----------
extern "C" void kernel_launch(void* const* d_in, const int* in_sizes, int n_in,
                              void* d_out, int out_size, void* d_ws, size_t ws_size,
                              hipStream_t stream) {
    const float* x    = (const float*)d_in[0];
    const float* Wq   = (const float*)d_in[1];
    const float* Wk   = (const float*)d_in[2];
    const float* Wv   = (const float*)d_in[3];
    const float* Wo   = (const float*)d_in[4];
    const float* rel  = (const float*)d_in[5];
    const float* ln1g = (const float*)d_in[6];
    const float* ln1b = (const float*)d_in[7];
    const float* ln2g = (const float*)d_in[8];
    const float* ln2b = (const float*)d_in[9];
    const float* W1   = (const float*)d_in[10];
    const float* b1   = (const float*)d_in[11];
    const float* W2   = (const float*)d_in[12];
    const float* b2   = (const float*)d_in[13];

    char* ws = (char*)d_ws;
    unsigned short* wqkvT  = (unsigned short*)(ws + 0);          //  6 MB   [dead after QKV]
    unsigned short* woT    = (unsigned short*)(ws + 6291456);    //  2 MB
    unsigned short* attnb  = (unsigned short*)(ws + 8388608);    //  8 MB
    unsigned short* w1T    = (unsigned short*)(ws + 16777216);   //  8 MB
    unsigned short* hbuf   = (unsigned short*)(ws + 25165824);   //  8 MB
    unsigned short* w2T    = (unsigned short*)(ws + 33554432);   //  8 MB
    float*          x2     = (float*)(ws + 41943040);            // 16 MB
    unsigned short* qkv    = (unsigned short*)(ws + 58720256);   // 24 MB   [dead after attn]
    unsigned short* vt     = (unsigned short*)(ws + 83886080);   //  8 MB   [dead after attn]
    unsigned short* wopart = (unsigned short*)(ws + 58720256);   // 32 MB   (reuses qkv+vt, after attn)
    unsigned short* gbuf   = (unsigned short*)(ws + 58720256);   // 32 MB   (after Wo reduce)
    unsigned short* part   = (unsigned short*)(ws + 0);          // 32 MB   (reuses 0..32MB)

    const int smem = 131072;
    hipFuncSetAttribute((const void*)gemm256_kernel<0>, hipFuncAttributeMaxDynamicSharedMemorySize, smem);
    hipFuncSetAttribute((const void*)gemm256_kernel<2>, hipFuncAttributeMaxDynamicSharedMemorySize, smem);
    hipFuncSetAttribute((const void*)gemm256_kernel<4>, hipFuncAttributeMaxDynamicSharedMemorySize, smem);

    dim3 tb(32, 8);
    tcvt_kernel<<<dim3(32, 32), tb, 0, stream>>>(Wq, wqkvT, 1024, 1024);
    tcvt_kernel<<<dim3(32, 32), tb, 0, stream>>>(Wk, wqkvT + 1048576, 1024, 1024);
    tcvt_kernel<<<dim3(32, 32), tb, 0, stream>>>(Wv, wqkvT + 2097152, 1024, 1024);
    tcvt_kernel<<<dim3(32, 32), tb, 0, stream>>>(Wo, woT, 1024, 1024);
    tcvt_kernel<<<dim3(128, 32), tb, 0, stream>>>(W1, w1T, 1024, 4096);
    tcvt_kernel<<<dim3(32, 128), tb, 0, stream>>>(W2, w2T, 4096, 1024);

    ln_kernel<<<4096, 256, 0, stream>>>(x, ln1g, ln1b, hbuf);

    // QKV: [4096,1024] x [3072,1024]^T -> qkv
    gemm256_kernel<0><<<192, 512, smem, stream>>>(hbuf, 1024, wqkvT, 1024, qkv,
                                                  nullptr, 3072, 16, 16, 12, 0ULL);

    tvt_kernel<<<dim3(64, 16), 256, 0, stream>>>(qkv, vt);

    attn3_kernel<<<dim3(32, 16), 512, 0, stream>>>(qkv, vt, rel, attnb);

    // Wo projection split-K=4: [4096,1024] x [1024,1024]^T -> 4 partial slabs
    gemm256_kernel<4><<<256, 512, smem, stream>>>(attnb, 1024, woT, 1024, wopart,
                                                  nullptr, 1024, 4, 16, 4, 4194304ULL);
    // x2 = sum(slabs) + x
    reduce4_kernel<0><<<4096, 256, 0, stream>>>(wopart, nullptr, x, x2);

    ln_kernel<<<4096, 256, 0, stream>>>(x2, ln2g, ln2b, hbuf);

    // FFN1: [4096,1024] x [4096,1024]^T + b1, gelu -> gbuf
    gemm256_kernel<2><<<256, 512, smem, stream>>>(hbuf, 1024, w1T, 1024, gbuf,
                                                  b1, 4096, 16, 16, 16, 0ULL);

    // FFN2 split-K=4: [4096,4096] x [1024,4096]^T -> 4 bf16 partial slabs
    gemm256_kernel<4><<<256, 512, smem, stream>>>(gbuf, 4096, w2T, 4096, part,
                                                  nullptr, 1024, 16, 16, 4, 4194304ULL);

    // out = sum(slabs) + b2 + x2
    reduce4_kernel<1><<<4096, 256, 0, stream>>>(part, b2, x2, (float*)d_out);
}

// Round 8
// 235.659 us; speedup vs baseline: 1.4783x; 1.0464x over previous
//
#include <hip/hip_runtime.h>
#include <math.h>

// ---------- types ----------
typedef __bf16 bf16x8 __attribute__((ext_vector_type(8)));   // MFMA A/B fragment (4 VGPRs)
typedef short  s16x4  __attribute__((ext_vector_type(4)));   // 16x16x16 MFMA A/B fragment (2 VGPRs)
typedef float  f32x4  __attribute__((ext_vector_type(4)));   // MFMA C/D fragment
typedef short  s16x8  __attribute__((ext_vector_type(8)));   // raw 16B data movement

__device__ __forceinline__ unsigned short f2bf(float f) {
    unsigned int u = __float_as_uint(f);
    u += 0x7fffu + ((u >> 16) & 1u);   // round-to-nearest-even
    return (unsigned short)(u >> 16);
}

__device__ __forceinline__ unsigned cvt_pk_bf16(float a, float b) {
    unsigned r;
    asm volatile("v_cvt_pk_bf16_f32 %0, %1, %2" : "=v"(r) : "v"(a), "v"(b));
    return r;
}

// 16x16x16 bf16 MFMA via compiler-known builtin (MAI hazard nops inserted; R6 lesson)
__device__ __forceinline__ f32x4 mfma16(s16x4 a, s16x4 b, f32x4 c) {
#if __has_builtin(__builtin_amdgcn_mfma_f32_16x16x16bf16_1k)
    return __builtin_amdgcn_mfma_f32_16x16x16bf16_1k(a, b, c, 0, 0, 0);
#else
    asm volatile("s_nop 3\n\t"
                 "v_mfma_f32_16x16x16_bf16 %0, %1, %2, %0\n\t"
                 "s_nop 7\n\t"
                 "s_nop 7"
                 : "+v"(c) : "v"(a), "v"(b));
    return c;
#endif
}

__device__ __forceinline__ float gelu_tanh(float x) {
    float x3 = x * x * x;
    float t = tanhf(0.7978845608028654f * (x + 0.044715f * x3));
    return 0.5f * x * (1.0f + t);
}

// ---------- transpose + f32->bf16 convert (batched x4):  in[1024][1024] f32 -> out[z][1024][1024] bf16 ----------
__global__ __launch_bounds__(256) void tcvt4_kernel(const float* __restrict__ p0,
                                                    const float* __restrict__ p1,
                                                    const float* __restrict__ p2,
                                                    const float* __restrict__ p3,
                                                    unsigned short* __restrict__ out) {
    __shared__ float tile[32][33];
    int z = blockIdx.z;
    const float* in = (z == 0) ? p0 : (z == 1) ? p1 : (z == 2) ? p2 : p3;
    unsigned short* o = out + (size_t)z * 1048576;
    int tx = threadIdx.x, ty = threadIdx.y;           // 32 x 8
    int k0 = blockIdx.y * 32, n0 = blockIdx.x * 32;
#pragma unroll
    for (int s = 0; s < 4; ++s)
        tile[ty + s * 8][tx] = in[(size_t)(k0 + ty + s * 8) * 1024 + n0 + tx];
    __syncthreads();
#pragma unroll
    for (int s = 0; s < 4; ++s)
        o[(size_t)(n0 + ty + s * 8) * 1024 + k0 + tx] = f2bf(tile[tx][ty + s * 8]);
}

// ---------- transpose + convert, generic: in[K][N] f32 -> out[N][K] bf16 ----------
__global__ __launch_bounds__(256) void tcvt_kernel(const float* __restrict__ in,
                                                   unsigned short* __restrict__ out,
                                                   int K, int N) {
    __shared__ float tile[32][33];
    int tx = threadIdx.x, ty = threadIdx.y;
    int k0 = blockIdx.y * 32, n0 = blockIdx.x * 32;
#pragma unroll
    for (int s = 0; s < 4; ++s)
        tile[ty + s * 8][tx] = in[(size_t)(k0 + ty + s * 8) * N + n0 + tx];
    __syncthreads();
#pragma unroll
    for (int s = 0; s < 4; ++s)
        out[(size_t)(n0 + ty + s * 8) * K + k0 + tx] = f2bf(tile[tx][ty + s * 8]);
}

// ---------- layernorm: x[L][1024] f32 -> out bf16 ----------
__global__ __launch_bounds__(256) void ln_kernel(const float* __restrict__ x,
                                                 const float* __restrict__ g,
                                                 const float* __restrict__ b,
                                                 unsigned short* __restrict__ out) {
    int row = blockIdx.x;
    int tid = threadIdx.x;
    float4 v = ((const float4*)(x + (size_t)row * 1024))[tid];
    float s  = v.x + v.y + v.z + v.w;
    float ss = v.x * v.x + v.y * v.y + v.z * v.z + v.w * v.w;
#pragma unroll
    for (int o = 32; o > 0; o >>= 1) { s += __shfl_down(s, o); ss += __shfl_down(ss, o); }
    __shared__ float red[8];
    if ((tid & 63) == 0) { red[(tid >> 6) * 2] = s; red[(tid >> 6) * 2 + 1] = ss; }
    __syncthreads();
    s  = red[0] + red[2] + red[4] + red[6];
    ss = red[1] + red[3] + red[5] + red[7];
    float mean = s * (1.0f / 1024.0f);
    float var  = ss * (1.0f / 1024.0f) - mean * mean;
    float rs   = rsqrtf(var + 1e-5f);
    float4 gv = ((const float4*)g)[tid];
    float4 bv = ((const float4*)b)[tid];
    ushort4 o4;
    o4.x = f2bf((v.x - mean) * rs * gv.x + bv.x);
    o4.y = f2bf((v.y - mean) * rs * gv.y + bv.y);
    o4.z = f2bf((v.z - mean) * rs * gv.z + bv.z);
    o4.w = f2bf((v.w - mean) * rs * gv.w + bv.w);
    ((ushort4*)(out + (size_t)row * 1024))[tid] = o4;
}

// ---------- fused: x2 = sum(4 slabs)+x ;  hbuf = LN(x2) ----------
__global__ __launch_bounds__(256) void reduceln_kernel(const unsigned short* __restrict__ part,
                                                       const float* __restrict__ xin,
                                                       const float* __restrict__ g,
                                                       const float* __restrict__ b,
                                                       float* __restrict__ x2,
                                                       unsigned short* __restrict__ outbf) {
    int row = blockIdx.x;
    int tid = threadIdx.x;
    int i4  = row * 256 + tid;
    float4 r = ((const float4*)xin)[i4];
    float v0 = r.x, v1 = r.y, v2 = r.z, v3 = r.w;
#pragma unroll
    for (int sl = 0; sl < 4; ++sl) {
        ushort4 u = ((const ushort4*)(part + (size_t)sl * 4194304))[i4];
        v0 += __uint_as_float((unsigned)u.x << 16);
        v1 += __uint_as_float((unsigned)u.y << 16);
        v2 += __uint_as_float((unsigned)u.z << 16);
        v3 += __uint_as_float((unsigned)u.w << 16);
    }
    float4 o; o.x = v0; o.y = v1; o.z = v2; o.w = v3;
    ((float4*)x2)[i4] = o;

    float s  = v0 + v1 + v2 + v3;
    float ss = v0 * v0 + v1 * v1 + v2 * v2 + v3 * v3;
#pragma unroll
    for (int off = 32; off > 0; off >>= 1) { s += __shfl_down(s, off); ss += __shfl_down(ss, off); }
    __shared__ float red[8];
    if ((tid & 63) == 0) { red[(tid >> 6) * 2] = s; red[(tid >> 6) * 2 + 1] = ss; }
    __syncthreads();
    s  = red[0] + red[2] + red[4] + red[6];
    ss = red[1] + red[3] + red[5] + red[7];
    float mean = s * (1.0f / 1024.0f);
    float var  = ss * (1.0f / 1024.0f) - mean * mean;
    float rs   = rsqrtf(var + 1e-5f);
    float4 gv = ((const float4*)g)[tid];
    float4 bv = ((const float4*)b)[tid];
    ushort4 o4;
    o4.x = f2bf((v0 - mean) * rs * gv.x + bv.x);
    o4.y = f2bf((v1 - mean) * rs * gv.y + bv.y);
    o4.z = f2bf((v2 - mean) * rs * gv.z + bv.z);
    o4.w = f2bf((v3 - mean) * rs * gv.w + bv.w);
    ((ushort4*)(outbf + (size_t)row * 1024))[tid] = o4;
}

// ---------- transpose V (bf16): qkv v-part -> vt[1024][4096] ----------
__global__ __launch_bounds__(256) void tvt_kernel(const unsigned short* __restrict__ in,
                                                  unsigned short* __restrict__ out) {
    __shared__ unsigned short tile[64][72];
    int t = threadIdx.x;
    int l0 = blockIdx.x * 64, c0 = blockIdx.y * 64;
    int tr = t >> 3, tc = (t & 7) * 8;
#pragma unroll
    for (int s = 0; s < 2; ++s) {
        int r = tr + s * 32;
        s16x8 v = *(const s16x8*)(in + (size_t)(l0 + r) * 3072 + 2048 + c0 + tc);
        *(s16x8*)(&tile[r][tc]) = v;
    }
    __syncthreads();
#pragma unroll
    for (int s = 0; s < 2; ++s) {
        int c = tr + s * 32;
        s16x8 w;
#pragma unroll
        for (int e = 0; e < 8; ++e) w[e] = (short)tile[tc + e][c];
        *(s16x8*)(out + (size_t)(c0 + c) * 4096 + l0 + tc) = w;
    }
}

// ---------- shared staging helpers (chunk-XOR swizzle, rule 21) ----------
__device__ __forceinline__ void stage8(const unsigned short* __restrict__ src_row0, int ld,
                                       unsigned short* ldsdst, int lane) {
    const int r8 = lane >> 3;
    const int c  = (lane & 7) ^ r8;
    const unsigned short* src = src_row0 + (size_t)r8 * ld + c * 8;
    __builtin_amdgcn_global_load_lds((const __attribute__((address_space(1))) void*)src,
                                     (__attribute__((address_space(3))) void*)ldsdst, 16, 0, 0);
}

__device__ __forceinline__ void stage64(const unsigned short* __restrict__ mat, int ld,
                                        int grow0, int kcol,
                                        unsigned short* lds_tile, int q, int wave, int lane) {
    const int l8 = lane >> 3;
    const int sc = ((lane & 7) ^ l8) << 3;
    const unsigned short* src = mat + (size_t)(grow0 + q * 64 + wave * 8 + l8) * ld + kcol + sc;
    unsigned short* dst = lds_tile + ((q * 64 + wave * 8) << 6);
    __builtin_amdgcn_global_load_lds((const __attribute__((address_space(1))) void*)src,
                                     (__attribute__((address_space(3))) void*)dst, 16, 0, 0);
}

__device__ __forceinline__ bf16x8 ldfrag(const unsigned short* tile, int row, int chunk) {
    return *(const bf16x8*)(tile + (row << 6) + (((chunk ^ row) & 7) << 3));
}

__device__ __forceinline__ s16x4 ldfrag64(const unsigned short* tile, int row, int ch16, int half) {
    return *(const s16x4*)(tile + (row << 6) + (((ch16 ^ row) & 7) << 3) + (half << 2));
}

// ---------- 256x256 8-phase GEMM (T1+T2+T3+T4+T5) ----------
// EPI 0: bf16 store; EPI 2: +bias, gelu, bf16; EPI 4: bf16 partial to slab[split]
template <int EPI>
__global__ __launch_bounds__(512, 2) void gemm256_kernel(
        const unsigned short* __restrict__ A, int lda,
        const unsigned short* __restrict__ Bt, int ldb,
        void* __restrict__ Cv, const float* __restrict__ bias,
        int ldc, int NT, int gm, int gn, unsigned long long slab_stride) {
    extern __shared__ unsigned short lds[];
    unsigned short* sA = lds;
    unsigned short* sB = lds + 2 * 256 * 64;

    const int tid  = threadIdx.x;
    const int wave = tid >> 6, lane = tid & 63;
    const int wr = wave >> 2, wc = wave & 3;
    const int lg = lane >> 4, l15 = lane & 15;

    // bijective XCD swizzle (m204)
    const int nwg = gridDim.x;
    const int bid = blockIdx.x;
    const int q8 = nwg >> 3, r8 = nwg & 7;
    const int xcd = bid & 7, loc = bid >> 3;
    const int swz = (xcd < r8 ? xcd * (q8 + 1) : r8 * (q8 + 1) + (xcd - r8) * q8) + loc;
    const int split = swz / (gm * gn);
    const int rem   = swz % (gm * gn);
    // 2D-banded mapping: 4-wide bcol bands (gn % 4 == 0) -> per-XCD L2 reuse on BOTH panels
    const int band = rem / (gm * 4);
    const int r2   = rem % (gm * 4);
    const int brow = (r2 >> 2) << 8;
    const int bcol = (band * 4 + (r2 & 3)) << 8;
    const int kbase = split * (NT << 6);

    f32x4 acc[8][4] = {};

#define STAGE_A(tt, q_, pbuf) stage64(A, lda, brow, kbase + ((tt) << 6), sA + (pbuf) * 16384, (q_), wave, lane)
#define STAGE_B(tt, q_, pbuf) stage64(Bt, ldb, bcol, kbase + ((tt) << 6), sB + (pbuf) * 16384, (q_), wave, lane)

    STAGE_A(0, 0, 0); STAGE_A(0, 1, 0); STAGE_A(0, 2, 0); STAGE_A(0, 3, 0);
    STAGE_B(0, 0, 0); STAGE_B(0, 1, 0); STAGE_B(0, 2, 0); STAGE_B(0, 3, 0);
    STAGE_A(1, 0, 1); STAGE_A(1, 1, 1); STAGE_A(1, 2, 1); STAGE_A(1, 3, 1);
    STAGE_B(1, 0, 1); STAGE_B(1, 1, 1);
    asm volatile("s_waitcnt vmcnt(6)" ::: "memory");
    __builtin_amdgcn_s_barrier();

    for (int t = 0; t < NT; ++t) {
        const int p = t & 1;
        const unsigned short* tA = sA + p * 16384;
        const unsigned short* tB = sB + p * 16384;
        bf16x8 a0[4][2], a1[4][2], b0[2][2], b1[2][2];

        // ---- phase 1: (mh0, nh0)
#pragma unroll
        for (int im = 0; im < 4; ++im)
#pragma unroll
            for (int kk = 0; kk < 2; ++kk)
                a0[im][kk] = ldfrag(tA, wr * 128 + im * 16 + l15, lg + kk * 4);
#pragma unroll
        for (int in = 0; in < 2; ++in)
#pragma unroll
            for (int kk = 0; kk < 2; ++kk)
                b0[in][kk] = ldfrag(tB, wc * 64 + in * 16 + l15, lg + kk * 4);
        if (t + 1 < NT) { STAGE_B(t + 1, 2, p ^ 1); STAGE_B(t + 1, 3, p ^ 1); }
        __builtin_amdgcn_s_barrier();
        asm volatile("s_waitcnt lgkmcnt(0)" ::: "memory");
        __builtin_amdgcn_sched_barrier(0);
        __builtin_amdgcn_s_setprio(1);
#pragma unroll
        for (int kk = 0; kk < 2; ++kk)
#pragma unroll
            for (int im = 0; im < 4; ++im)
#pragma unroll
                for (int in = 0; in < 2; ++in)
                    acc[im][in] = __builtin_amdgcn_mfma_f32_16x16x32_bf16(a0[im][kk], b0[in][kk], acc[im][in], 0, 0, 0);
        __builtin_amdgcn_s_setprio(0);
        __builtin_amdgcn_s_barrier();

        // ---- phase 2: (mh1, nh0)
#pragma unroll
        for (int im = 0; im < 4; ++im)
#pragma unroll
            for (int kk = 0; kk < 2; ++kk)
                a1[im][kk] = ldfrag(tA, wr * 128 + 64 + im * 16 + l15, lg + kk * 4);
        if (t + 2 < NT) { STAGE_A(t + 2, 0, p); STAGE_A(t + 2, 2, p); }
        __builtin_amdgcn_s_barrier();
        asm volatile("s_waitcnt lgkmcnt(0)" ::: "memory");
        __builtin_amdgcn_sched_barrier(0);
        __builtin_amdgcn_s_setprio(1);
#pragma unroll
        for (int kk = 0; kk < 2; ++kk)
#pragma unroll
            for (int im = 0; im < 4; ++im)
#pragma unroll
                for (int in = 0; in < 2; ++in)
                    acc[4 + im][in] = __builtin_amdgcn_mfma_f32_16x16x32_bf16(a1[im][kk], b0[in][kk], acc[4 + im][in], 0, 0, 0);
        __builtin_amdgcn_s_setprio(0);
        __builtin_amdgcn_s_barrier();

        // ---- phase 3: (mh1, nh1)
#pragma unroll
        for (int in = 0; in < 2; ++in)
#pragma unroll
            for (int kk = 0; kk < 2; ++kk)
                b1[in][kk] = ldfrag(tB, wc * 64 + 32 + in * 16 + l15, lg + kk * 4);
        if (t + 2 < NT) { STAGE_A(t + 2, 1, p); STAGE_A(t + 2, 3, p); }
        __builtin_amdgcn_s_barrier();
        asm volatile("s_waitcnt lgkmcnt(0)" ::: "memory");
        __builtin_amdgcn_sched_barrier(0);
        __builtin_amdgcn_s_setprio(1);
#pragma unroll
        for (int kk = 0; kk < 2; ++kk)
#pragma unroll
            for (int im = 0; im < 4; ++im)
#pragma unroll
                for (int in = 0; in < 2; ++in)
                    acc[4 + im][2 + in] = __builtin_amdgcn_mfma_f32_16x16x32_bf16(a1[im][kk], b1[in][kk], acc[4 + im][2 + in], 0, 0, 0);
        __builtin_amdgcn_s_setprio(0);
        __builtin_amdgcn_s_barrier();

        // ---- phase 4: (mh0, nh1)
        if (t + 2 < NT) { STAGE_B(t + 2, 0, p); STAGE_B(t + 2, 1, p); }
        __builtin_amdgcn_s_barrier();
        asm volatile("s_waitcnt lgkmcnt(0)" ::: "memory");
        __builtin_amdgcn_sched_barrier(0);
        __builtin_amdgcn_s_setprio(1);
#pragma unroll
        for (int kk = 0; kk < 2; ++kk)
#pragma unroll
            for (int im = 0; im < 4; ++im)
#pragma unroll
                for (int in = 0; in < 2; ++in)
                    acc[im][2 + in] = __builtin_amdgcn_mfma_f32_16x16x32_bf16(a0[im][kk], b1[in][kk], acc[im][2 + in], 0, 0, 0);
        __builtin_amdgcn_s_setprio(0);
        if (t + 2 < NT) asm volatile("s_waitcnt vmcnt(6)" ::: "memory");
        else            asm volatile("s_waitcnt vmcnt(0)" ::: "memory");
        __builtin_amdgcn_s_barrier();
    }
#undef STAGE_A
#undef STAGE_B

#pragma unroll
    for (int mi = 0; mi < 8; ++mi)
#pragma unroll
        for (int ni = 0; ni < 4; ++ni)
#pragma unroll
            for (int rr = 0; rr < 4; ++rr) {
                int row = brow + wr * 128 + mi * 16 + lg * 4 + rr;
                int col = bcol + wc * 64 + ni * 16 + l15;
                float v = acc[mi][ni][rr];
                if (EPI == 0) {
                    ((unsigned short*)Cv)[(size_t)row * ldc + col] = f2bf(v);
                } else if (EPI == 2) {
                    v += bias[col];
                    ((unsigned short*)Cv)[(size_t)row * ldc + col] = f2bf(gelu_tanh(v));
                } else {
                    ((unsigned short*)Cv)[slab_stride * split + (size_t)row * ldc + col] = f2bf(v);
                }
            }
}

// ---------- split-K reduce (final): out = sum(4 slabs) + bias + resid ----------
__global__ __launch_bounds__(256) void reduce4_kernel(const unsigned short* __restrict__ part,
                                                      const float* __restrict__ bias,
                                                      const float* __restrict__ resid,
                                                      float* __restrict__ out) {
    int i4 = blockIdx.x * 256 + threadIdx.x;
    float4 r  = ((const float4*)resid)[i4];
    float4 bb = ((const float4*)bias)[i4 & 255];
    float s0 = r.x + bb.x, s1 = r.y + bb.y, s2 = r.z + bb.z, s3 = r.w + bb.w;
#pragma unroll
    for (int s = 0; s < 4; ++s) {
        ushort4 u = ((const ushort4*)(part + (size_t)s * 4194304))[i4];
        s0 += __uint_as_float((unsigned)u.x << 16);
        s1 += __uint_as_float((unsigned)u.y << 16);
        s2 += __uint_as_float((unsigned)u.z << 16);
        s3 += __uint_as_float((unsigned)u.w << 16);
    }
    float4 o; o.x = s0; o.y = s1; o.z = s2; o.w = s3;
    ((float4*)out)[i4] = o;
}

// ---------- band attention v4: swapped QK^T, in-register P, 4 waves, 4 blocks/CU ----------
// grid 1024 (64 q-blocks x 16 heads), 256 threads. Wave wv owns 16 query rows.
__global__ __launch_bounds__(256, 4) void attn4_kernel(const unsigned short* __restrict__ qkv, // [4096][3072]
                                                       const unsigned short* __restrict__ vt,  // [1024][4096]
                                                       const float* __restrict__ rel_emb,      // [258][16]
                                                       unsigned short* __restrict__ outp) {    // [4096][1024]
    const int lid = blockIdx.y * gridDim.x + blockIdx.x;      // 0..1023
    const int rid = (lid & 7) * 128 + (lid >> 3);             // XCD-contiguous
    const int h   = rid >> 6;
    const int n   = rid & 63;

    const int tid  = threadIdx.x;
    const int wv   = tid >> 6;         // 0..3
    const int lane = tid & 63;
    const int lg   = lane >> 4;
    const int l15  = lane & 15;
    const int iq   = wv * 16 + l15;             // query row within the 64-block
    const int q0   = n * 64 + wv * 16;          // wave's first global query row

    __shared__ __align__(16) unsigned short sK[2][4096];
    __shared__ __align__(16) unsigned short sV[2][4096];
    __shared__ float sRelF[258];

    // Q direct to registers as B-fragments: col i = l15, k = d
    bf16x8 qf[2];
    {
        const unsigned short* qrow = qkv + (size_t)(q0 + l15) * 3072 + h * 64 + lg * 8;
        qf[0] = *(const bf16x8*)(qrow);
        qf[1] = *(const bf16x8*)(qrow + 32);
    }

    for (int i = tid; i < 258; i += 256) sRelF[i] = rel_emb[i * 16 + h];
    const float relC = rel_emb[257 * 16 + h];

    const int tlo = (n >= 15) ? 0 : (15 - n);
    {
        const int src = n - 15 + tlo;
#pragma unroll
        for (int s = 0; s < 2; ++s) {
            int r0 = wv * 16 + s * 8;
            stage8(qkv + (size_t)(src * 64 + r0) * 3072 + 1024 + h * 64, 3072, &sK[0][r0 * 64], lane);
            stage8(vt + (size_t)(h * 64 + r0) * 4096 + src * 64, 4096, &sV[0][r0 * 64], lane);
        }
    }
    asm volatile("s_waitcnt lgkmcnt(0)" ::: "memory");
    __builtin_amdgcn_s_barrier();

    f32x4 oacc[4] = {};                 // O^T: d = dt*16+lg*4+rr, i = l15
    float mrow = -3e38f, lrow = 0.f;

    for (int t = tlo; t < 16; ++t) {
        const int cur = (t - tlo) & 1;
        if (t < 15) {
            const int src = n - 15 + (t + 1);
#pragma unroll
            for (int s = 0; s < 2; ++s) {
                int r0 = wv * 16 + s * 8;
                stage8(qkv + (size_t)(src * 64 + r0) * 3072 + 1024 + h * 64, 3072, &sK[cur ^ 1][r0 * 64], lane);
                stage8(vt + (size_t)(h * 64 + r0) * 4096 + src * 64, 4096, &sV[cur ^ 1][r0 * 64], lane);
            }
            asm volatile("s_waitcnt vmcnt(4)" ::: "memory");   // tile t's 4 issues landed
        } else {
            asm volatile("s_waitcnt vmcnt(0)" ::: "memory");
        }
        __builtin_amdgcn_s_barrier();

        const unsigned short* tK = &sK[cur][0];
        const unsigned short* tV = &sV[cur][0];
        const int woff = 15 - t;                   // 0 = diagonal tile

        // ---- S^T = K·Q^T : C[j][i], 8 MFMA; lane: j = jt*16+lg*4+rr, i = l15
        f32x4 st[4] = {};
        __builtin_amdgcn_s_setprio(1);
#pragma unroll
        for (int jt = 0; jt < 4; ++jt) {
            bf16x8 kf0 = ldfrag(tK, jt * 16 + l15, lg);
            bf16x8 kf1 = ldfrag(tK, jt * 16 + l15, lg + 4);
            st[jt] = __builtin_amdgcn_mfma_f32_16x16x32_bf16(kf0, qf[0], st[jt], 0, 0, 0);
            st[jt] = __builtin_amdgcn_mfma_f32_16x16x32_bf16(kf1, qf[1], st[jt], 0, 0, 0);
        }
        __builtin_amdgcn_s_setprio(0);

        // ---- bias + mask + in-lane max
        float pm = -3e38f;
        if (woff >= 5) {
#pragma unroll
            for (int jt = 0; jt < 4; ++jt)
#pragma unroll
                for (int rr = 0; rr < 4; ++rr) {
                    float v = st[jt][rr] * 0.125f + relC;
                    st[jt][rr] = v;
                    pm = fmaxf(pm, v);
                }
        } else if (woff > 0) {
#pragma unroll
            for (int jt = 0; jt < 4; ++jt)
#pragma unroll
                for (int rr = 0; rr < 4; ++rr) {
                    int j = jt * 16 + lg * 4 + rr;
                    int relid = min(woff * 64 + iq - j, 256) + 1;
                    float v = st[jt][rr] * 0.125f + sRelF[relid];
                    st[jt][rr] = v;
                    pm = fmaxf(pm, v);
                }
        } else {
#pragma unroll
            for (int jt = 0; jt < 4; ++jt)
#pragma unroll
                for (int rr = 0; rr < 4; ++rr) {
                    int j = jt * 16 + lg * 4 + rr;
                    float v = (j <= iq) ? (st[jt][rr] * 0.125f + sRelF[iq - j + 1]) : -1e30f;
                    st[jt][rr] = v;
                    pm = fmaxf(pm, v);
                }
        }
        pm = fmaxf(pm, __shfl_xor(pm, 16));
        pm = fmaxf(pm, __shfl_xor(pm, 32));
        float mn  = fmaxf(mrow, pm);
        float scl = __expf(mrow - mn);
        mrow = mn;

        // ---- exp + pack straight into PV B-fragments
        float rs = 0.f;
        unsigned pk0[4], pk1[4];
#pragma unroll
        for (int jt = 0; jt < 4; ++jt) {
            float p0 = __expf(st[jt][0] - mn);
            float p1 = __expf(st[jt][1] - mn);
            float p2 = __expf(st[jt][2] - mn);
            float p3 = __expf(st[jt][3] - mn);
            rs += (p0 + p1) + (p2 + p3);
            pk0[jt] = cvt_pk_bf16(p0, p1);
            pk1[jt] = cvt_pk_bf16(p2, p3);
        }
        rs += __shfl_xor(rs, 16);
        rs += __shfl_xor(rs, 32);
        lrow = lrow * scl + rs;
#pragma unroll
        for (int dt = 0; dt < 4; ++dt)
#pragma unroll
            for (int rr = 0; rr < 4; ++rr)
                oacc[dt][rr] *= scl;

        // ---- O^T += V^T·P^T : 16 x mfma 16x16x16 (P stays in registers)
        __builtin_amdgcn_s_setprio(1);
#pragma unroll
        for (int ks = 0; ks < 4; ++ks) {
            union { unsigned u[2]; s16x4 v; } pu;
            pu.u[0] = pk0[ks]; pu.u[1] = pk1[ks];
#pragma unroll
            for (int dt = 0; dt < 4; ++dt) {
                s16x4 vf = ldfrag64(tV, dt * 16 + l15, 2 * ks + (lg >> 1), lg & 1);
                oacc[dt] = mfma16(vf, pu.v, oacc[dt]);
            }
        }
        __builtin_amdgcn_s_setprio(0);
        __builtin_amdgcn_s_barrier();              // buf[cur] reads done before overwrite
    }

    // ---- epilogue: normalize, transpose via (dead) sK, coalesced store
    float inv = 1.0f / lrow;
    unsigned short* sO = &sK[0][0] + wv * 1024;    // wave-private [16 i][64 d]
#pragma unroll
    for (int dt = 0; dt < 4; ++dt)
#pragma unroll
        for (int c = 0; c < 2; ++c) {
            unsigned pr = cvt_pk_bf16(oacc[dt][2 * c] * inv, oacc[dt][2 * c + 1] * inv);
            int d  = dt * 16 + lg * 4 + 2 * c;
            int off = (l15 << 6) + ((((d >> 3) ^ (l15 & 7)) & 7) << 3) + (d & 7);
            *(unsigned*)(sO + off) = pr;
        }
#pragma unroll
    for (int c2 = 0; c2 < 2; ++c2) {
        int ch = lg + 4 * c2;
        bf16x8 ov = ldfrag(sO, l15, ch);
        *(s16x8*)(outp + (size_t)(q0 + l15) * 1024 + h * 64 + ch * 8) = *(const s16x8*)&ov;
    }
}

// ---------- launch ----------
extern "C" void kernel_launch(void* const* d_in, const int* in_sizes, int n_in,
                              void* d_out, int out_size, void* d_ws, size_t ws_size,
                              hipStream_t stream) {
    const float* x    = (const float*)d_in[0];
    const float* Wq   = (const float*)d_in[1];
    const float* Wk   = (const float*)d_in[2];
    const float* Wv   = (const float*)d_in[3];
    const float* Wo   = (const float*)d_in[4];
    const float* rel  = (const float*)d_in[5];
    const float* ln1g = (const float*)d_in[6];
    const float* ln1b = (const float*)d_in[7];
    const float* ln2g = (const float*)d_in[8];
    const float* ln2b = (const float*)d_in[9];
    const float* W1   = (const float*)d_in[10];
    const float* b1   = (const float*)d_in[11];
    const float* W2   = (const float*)d_in[12];
    const float* b2   = (const float*)d_in[13];

    char* ws = (char*)d_ws;
    unsigned short* wqkvT  = (unsigned short*)(ws + 0);          //  8 MB (Wq,Wk,Wv,Wo transposed)
    unsigned short* woT    = wqkvT + 3145728;                    //  (inside the 8 MB block)
    unsigned short* attnb  = (unsigned short*)(ws + 8388608);    //  8 MB
    unsigned short* w1T    = (unsigned short*)(ws + 16777216);   //  8 MB
    unsigned short* hbuf   = (unsigned short*)(ws + 25165824);   //  8 MB
    unsigned short* w2T    = (unsigned short*)(ws + 33554432);   //  8 MB
    float*          x2     = (float*)(ws + 41943040);            // 16 MB
    unsigned short* qkv    = (unsigned short*)(ws + 58720256);   // 24 MB   [dead after attn]
    unsigned short* vt     = (unsigned short*)(ws + 83886080);   //  8 MB   [dead after attn]
    unsigned short* wopart = (unsigned short*)(ws + 58720256);   // 32 MB   (reuses qkv+vt, after attn)
    unsigned short* gbuf   = (unsigned short*)(ws + 58720256);   // 32 MB   (after Wo reduce)
    unsigned short* part   = (unsigned short*)(ws + 0);          // 32 MB   (reuses 0..32MB)

    const int smem = 131072;
    hipFuncSetAttribute((const void*)gemm256_kernel<0>, hipFuncAttributeMaxDynamicSharedMemorySize, smem);
    hipFuncSetAttribute((const void*)gemm256_kernel<2>, hipFuncAttributeMaxDynamicSharedMemorySize, smem);
    hipFuncSetAttribute((const void*)gemm256_kernel<4>, hipFuncAttributeMaxDynamicSharedMemorySize, smem);

    dim3 tb(32, 8);
    tcvt4_kernel<<<dim3(32, 32, 4), tb, 0, stream>>>(Wq, Wk, Wv, Wo, wqkvT);
    tcvt_kernel<<<dim3(128, 32), tb, 0, stream>>>(W1, w1T, 1024, 4096);
    tcvt_kernel<<<dim3(32, 128), tb, 0, stream>>>(W2, w2T, 4096, 1024);

    ln_kernel<<<4096, 256, 0, stream>>>(x, ln1g, ln1b, hbuf);

    // QKV: [4096,1024] x [3072,1024]^T -> qkv
    gemm256_kernel<0><<<192, 512, smem, stream>>>(hbuf, 1024, wqkvT, 1024, qkv,
                                                  nullptr, 3072, 16, 16, 12, 0ULL);

    tvt_kernel<<<dim3(64, 16), 256, 0, stream>>>(qkv, vt);

    attn4_kernel<<<dim3(64, 16), 256, 0, stream>>>(qkv, vt, rel, attnb);

    // Wo projection split-K=4: [4096,1024] x [1024,1024]^T -> 4 partial slabs
    gemm256_kernel<4><<<256, 512, smem, stream>>>(attnb, 1024, woT, 1024, wopart,
                                                  nullptr, 1024, 4, 16, 4, 4194304ULL);
    // fused: x2 = sum(slabs) + x ; hbuf = LN2(x2)
    reduceln_kernel<<<4096, 256, 0, stream>>>(wopart, x, ln2g, ln2b, x2, hbuf);

    // FFN1: [4096,1024] x [4096,1024]^T + b1, gelu -> gbuf
    gemm256_kernel<2><<<256, 512, smem, stream>>>(hbuf, 1024, w1T, 1024, gbuf,
                                                  b1, 4096, 16, 16, 16, 0ULL);

    // FFN2 split-K=4: [4096,4096] x [1024,4096]^T -> 4 bf16 partial slabs
    gemm256_kernel<4><<<256, 512, smem, stream>>>(gbuf, 4096, w2T, 4096, part,
                                                  nullptr, 1024, 16, 16, 4, 4194304ULL);

    // out = sum(slabs) + b2 + x2
    reduce4_kernel<<<4096, 256, 0, stream>>>(part, b2, x2, (float*)d_out);
}

// Round 9
// 227.249 us; speedup vs baseline: 1.5330x; 1.0370x over previous
//
#include <hip/hip_runtime.h>
#include <math.h>

// ---------- types ----------
typedef __bf16 bf16x8 __attribute__((ext_vector_type(8)));   // MFMA A/B fragment (4 VGPRs)
typedef short  s16x4  __attribute__((ext_vector_type(4)));   // 16x16x16 MFMA A/B fragment (2 VGPRs)
typedef float  f32x4  __attribute__((ext_vector_type(4)));   // MFMA C/D fragment
typedef short  s16x8  __attribute__((ext_vector_type(8)));   // raw 16B data movement

__device__ __forceinline__ unsigned short f2bf(float f) {
    unsigned int u = __float_as_uint(f);
    u += 0x7fffu + ((u >> 16) & 1u);   // round-to-nearest-even
    return (unsigned short)(u >> 16);
}

__device__ __forceinline__ unsigned cvt_pk_bf16(float a, float b) {
    unsigned r;
    asm volatile("v_cvt_pk_bf16_f32 %0, %1, %2" : "=v"(r) : "v"(a), "v"(b));
    return r;
}

// 16x16x16 bf16 MFMA via compiler-known builtin (MAI hazard nops inserted; R6 lesson)
__device__ __forceinline__ f32x4 mfma16(s16x4 a, s16x4 b, f32x4 c) {
#if __has_builtin(__builtin_amdgcn_mfma_f32_16x16x16bf16_1k)
    return __builtin_amdgcn_mfma_f32_16x16x16bf16_1k(a, b, c, 0, 0, 0);
#else
    asm volatile("s_nop 3\n\t"
                 "v_mfma_f32_16x16x16_bf16 %0, %1, %2, %0\n\t"
                 "s_nop 7\n\t"
                 "s_nop 7"
                 : "+v"(c) : "v"(a), "v"(b));
    return c;
#endif
}

// exact-equivalent sigmoid form of tanh-gelu: 0.5x(1+tanh(y)) = x * sigmoid(2y)
__device__ __forceinline__ float gelu_tanh(float x) {
    float z = 1.5957691216057308f * (x + 0.044715f * x * x * x);
    return x / (1.0f + __expf(-z));
}

// ---------- transpose + f32->bf16 convert (batched x4) ----------
__global__ __launch_bounds__(256) void tcvt4_kernel(const float* __restrict__ p0,
                                                    const float* __restrict__ p1,
                                                    const float* __restrict__ p2,
                                                    const float* __restrict__ p3,
                                                    unsigned short* __restrict__ out) {
    __shared__ float tile[32][33];
    int z = blockIdx.z;
    const float* in = (z == 0) ? p0 : (z == 1) ? p1 : (z == 2) ? p2 : p3;
    unsigned short* o = out + (size_t)z * 1048576;
    int tx = threadIdx.x, ty = threadIdx.y;           // 32 x 8
    int k0 = blockIdx.y * 32, n0 = blockIdx.x * 32;
#pragma unroll
    for (int s = 0; s < 4; ++s)
        tile[ty + s * 8][tx] = in[(size_t)(k0 + ty + s * 8) * 1024 + n0 + tx];
    __syncthreads();
#pragma unroll
    for (int s = 0; s < 4; ++s)
        o[(size_t)(n0 + ty + s * 8) * 1024 + k0 + tx] = f2bf(tile[tx][ty + s * 8]);
}

// ---------- transpose + convert, generic: in[K][N] f32 -> out[N][K] bf16 ----------
__global__ __launch_bounds__(256) void tcvt_kernel(const float* __restrict__ in,
                                                   unsigned short* __restrict__ out,
                                                   int K, int N) {
    __shared__ float tile[32][33];
    int tx = threadIdx.x, ty = threadIdx.y;
    int k0 = blockIdx.y * 32, n0 = blockIdx.x * 32;
#pragma unroll
    for (int s = 0; s < 4; ++s)
        tile[ty + s * 8][tx] = in[(size_t)(k0 + ty + s * 8) * N + n0 + tx];
    __syncthreads();
#pragma unroll
    for (int s = 0; s < 4; ++s)
        out[(size_t)(n0 + ty + s * 8) * K + k0 + tx] = f2bf(tile[tx][ty + s * 8]);
}

// ---------- layernorm: x[L][1024] f32 -> out bf16 ----------
__global__ __launch_bounds__(256) void ln_kernel(const float* __restrict__ x,
                                                 const float* __restrict__ g,
                                                 const float* __restrict__ b,
                                                 unsigned short* __restrict__ out) {
    int row = blockIdx.x;
    int tid = threadIdx.x;
    float4 v = ((const float4*)(x + (size_t)row * 1024))[tid];
    float s  = v.x + v.y + v.z + v.w;
    float ss = v.x * v.x + v.y * v.y + v.z * v.z + v.w * v.w;
#pragma unroll
    for (int o = 32; o > 0; o >>= 1) { s += __shfl_down(s, o); ss += __shfl_down(ss, o); }
    __shared__ float red[8];
    if ((tid & 63) == 0) { red[(tid >> 6) * 2] = s; red[(tid >> 6) * 2 + 1] = ss; }
    __syncthreads();
    s  = red[0] + red[2] + red[4] + red[6];
    ss = red[1] + red[3] + red[5] + red[7];
    float mean = s * (1.0f / 1024.0f);
    float var  = ss * (1.0f / 1024.0f) - mean * mean;
    float rs   = rsqrtf(var + 1e-5f);
    float4 gv = ((const float4*)g)[tid];
    float4 bv = ((const float4*)b)[tid];
    ushort4 o4;
    o4.x = f2bf((v.x - mean) * rs * gv.x + bv.x);
    o4.y = f2bf((v.y - mean) * rs * gv.y + bv.y);
    o4.z = f2bf((v.z - mean) * rs * gv.z + bv.z);
    o4.w = f2bf((v.w - mean) * rs * gv.w + bv.w);
    ((ushort4*)(out + (size_t)row * 1024))[tid] = o4;
}

// ---------- fused: x2 = sum(4 slabs)+x ;  hbuf = LN(x2) ----------
__global__ __launch_bounds__(256) void reduceln_kernel(const unsigned short* __restrict__ part,
                                                       const float* __restrict__ xin,
                                                       const float* __restrict__ g,
                                                       const float* __restrict__ b,
                                                       float* __restrict__ x2,
                                                       unsigned short* __restrict__ outbf) {
    int row = blockIdx.x;
    int tid = threadIdx.x;
    int i4  = row * 256 + tid;
    float4 r = ((const float4*)xin)[i4];
    float v0 = r.x, v1 = r.y, v2 = r.z, v3 = r.w;
#pragma unroll
    for (int sl = 0; sl < 4; ++sl) {
        ushort4 u = ((const ushort4*)(part + (size_t)sl * 4194304))[i4];
        v0 += __uint_as_float((unsigned)u.x << 16);
        v1 += __uint_as_float((unsigned)u.y << 16);
        v2 += __uint_as_float((unsigned)u.z << 16);
        v3 += __uint_as_float((unsigned)u.w << 16);
    }
    float4 o; o.x = v0; o.y = v1; o.z = v2; o.w = v3;
    ((float4*)x2)[i4] = o;

    float s  = v0 + v1 + v2 + v3;
    float ss = v0 * v0 + v1 * v1 + v2 * v2 + v3 * v3;
#pragma unroll
    for (int off = 32; off > 0; off >>= 1) { s += __shfl_down(s, off); ss += __shfl_down(ss, off); }
    __shared__ float red[8];
    if ((tid & 63) == 0) { red[(tid >> 6) * 2] = s; red[(tid >> 6) * 2 + 1] = ss; }
    __syncthreads();
    s  = red[0] + red[2] + red[4] + red[6];
    ss = red[1] + red[3] + red[5] + red[7];
    float mean = s * (1.0f / 1024.0f);
    float var  = ss * (1.0f / 1024.0f) - mean * mean;
    float rs   = rsqrtf(var + 1e-5f);
    float4 gv = ((const float4*)g)[tid];
    float4 bv = ((const float4*)b)[tid];
    ushort4 o4;
    o4.x = f2bf((v0 - mean) * rs * gv.x + bv.x);
    o4.y = f2bf((v1 - mean) * rs * gv.y + bv.y);
    o4.z = f2bf((v2 - mean) * rs * gv.z + bv.z);
    o4.w = f2bf((v3 - mean) * rs * gv.w + bv.w);
    ((ushort4*)(outbf + (size_t)row * 1024))[tid] = o4;
}

// ---------- transpose V (bf16): qkv v-part -> vt[1024][4096] ----------
__global__ __launch_bounds__(256) void tvt_kernel(const unsigned short* __restrict__ in,
                                                  unsigned short* __restrict__ out) {
    __shared__ unsigned short tile[64][72];
    int t = threadIdx.x;
    int l0 = blockIdx.x * 64, c0 = blockIdx.y * 64;
    int tr = t >> 3, tc = (t & 7) * 8;
#pragma unroll
    for (int s = 0; s < 2; ++s) {
        int r = tr + s * 32;
        s16x8 v = *(const s16x8*)(in + (size_t)(l0 + r) * 3072 + 2048 + c0 + tc);
        *(s16x8*)(&tile[r][tc]) = v;
    }
    __syncthreads();
#pragma unroll
    for (int s = 0; s < 2; ++s) {
        int c = tr + s * 32;
        s16x8 w;
#pragma unroll
        for (int e = 0; e < 8; ++e) w[e] = (short)tile[tc + e][c];
        *(s16x8*)(out + (size_t)(c0 + c) * 4096 + l0 + tc) = w;
    }
}

// ---------- shared staging helpers (chunk-XOR swizzle, rule 21) ----------
__device__ __forceinline__ void stage8(const unsigned short* __restrict__ src_row0, int ld,
                                       unsigned short* ldsdst, int lane) {
    const int r8 = lane >> 3;
    const int c  = (lane & 7) ^ r8;
    const unsigned short* src = src_row0 + (size_t)r8 * ld + c * 8;
    __builtin_amdgcn_global_load_lds((const __attribute__((address_space(1))) void*)src,
                                     (__attribute__((address_space(3))) void*)ldsdst, 16, 0, 0);
}

__device__ __forceinline__ void stage64(const unsigned short* __restrict__ mat, int ld,
                                        int grow0, int kcol,
                                        unsigned short* lds_tile, int q, int wave, int lane) {
    const int l8 = lane >> 3;
    const int sc = ((lane & 7) ^ l8) << 3;
    const unsigned short* src = mat + (size_t)(grow0 + q * 64 + wave * 8 + l8) * ld + kcol + sc;
    unsigned short* dst = lds_tile + ((q * 64 + wave * 8) << 6);
    __builtin_amdgcn_global_load_lds((const __attribute__((address_space(1))) void*)src,
                                     (__attribute__((address_space(3))) void*)dst, 16, 0, 0);
}

__device__ __forceinline__ bf16x8 ldfrag(const unsigned short* tile, int row, int chunk) {
    return *(const bf16x8*)(tile + (row << 6) + (((chunk ^ row) & 7) << 3));
}

__device__ __forceinline__ s16x4 ldfrag64(const unsigned short* tile, int row, int ch16, int half) {
    return *(const s16x4*)(tile + (row << 6) + (((ch16 ^ row) & 7) << 3) + (half << 2));
}

// ---- inline-asm ds_read (compiler-invisible: enables counted-lgkm pipelining) ----
__device__ __forceinline__ unsigned lds_byte(unsigned base, int row, int chunk) {
    return base + (row << 7) + (((chunk ^ row) & 7) << 4);
}
__device__ __forceinline__ bf16x8 ds_frag(unsigned addr) {
    bf16x8 r;
    asm volatile("ds_read_b128 %0, %1" : "=v"(r) : "v"(addr));
    return r;
}

// ---------- 256x256 pipelined-read 4-phase GEMM (T1..T5 + derived lgkm waits) ----------
// EPI 0: bf16 store; EPI 2: +bias, gelu, bf16; EPI 4: bf16 partial to slab[split]
template <int EPI>
__global__ __launch_bounds__(512, 2) void gemm256_kernel(
        const unsigned short* __restrict__ A, int lda,
        const unsigned short* __restrict__ Bt, int ldb,
        void* __restrict__ Cv, const float* __restrict__ bias,
        int ldc, int NT, int gm, int gn, unsigned long long slab_stride) {
    extern __shared__ unsigned short lds[];
    unsigned short* sA = lds;                  // [2][256*64]
    unsigned short* sB = lds + 2 * 256 * 64;   // [2][256*64]

    const int tid  = threadIdx.x;
    const int wave = tid >> 6, lane = tid & 63;
    const int wr = wave >> 2, wc = wave & 3;       // 2 x 4 wave grid
    const int lg = lane >> 4, l15 = lane & 15;

    const unsigned uA = (unsigned)(size_t)(__attribute__((address_space(3))) void*)sA;
    const unsigned uB = (unsigned)(size_t)(__attribute__((address_space(3))) void*)sB;

    // bijective XCD swizzle (m204)
    const int nwg = gridDim.x;
    const int bid = blockIdx.x;
    const int q8 = nwg >> 3, r8 = nwg & 7;
    const int xcd = bid & 7, loc = bid >> 3;
    const int swz = (xcd < r8 ? xcd * (q8 + 1) : r8 * (q8 + 1) + (xcd - r8) * q8) + loc;
    const int split = swz / (gm * gn);
    const int rem   = swz % (gm * gn);
    // 2D-banded mapping: 4-wide bcol bands
    const int band = rem / (gm * 4);
    const int r2   = rem % (gm * 4);
    const int brow = (r2 >> 2) << 8;
    const int bcol = (band * 4 + (r2 & 3)) << 8;
    const int kbase = split * (NT << 6);

    f32x4 acc[8][4] = {};
    bf16x8 a0[4][2], a1[4][2], b0[2][2], b1[2][2];

#define STAGE_A(tt, q_, pbuf) stage64(A, lda, brow, kbase + ((tt) << 6), sA + (pbuf) * 16384, (q_), wave, lane)
#define STAGE_B(tt, q_, pbuf) stage64(Bt, ldb, bcol, kbase + ((tt) << 6), sB + (pbuf) * 16384, (q_), wave, lane)

    // prologue: stage t0 -> buf0 (8), t1 -> buf1 (8); wait t0; read a0,b0(t0)
    STAGE_A(0, 0, 0); STAGE_A(0, 1, 0); STAGE_A(0, 2, 0); STAGE_A(0, 3, 0);
    STAGE_B(0, 0, 0); STAGE_B(0, 1, 0); STAGE_B(0, 2, 0); STAGE_B(0, 3, 0);
    STAGE_A(1, 0, 1); STAGE_A(1, 1, 1); STAGE_A(1, 2, 1); STAGE_A(1, 3, 1);
    STAGE_B(1, 0, 1); STAGE_B(1, 1, 1); STAGE_B(1, 2, 1); STAGE_B(1, 3, 1);
    asm volatile("s_waitcnt vmcnt(8)" ::: "memory");   // t0 landed (t1 in flight)
    __builtin_amdgcn_sched_barrier(0);
    __builtin_amdgcn_s_barrier();                      // cross-wave: t0 visible
#pragma unroll
    for (int im = 0; im < 4; ++im)
#pragma unroll
        for (int kk = 0; kk < 2; ++kk)
            a0[im][kk] = ds_frag(lds_byte(uA, wr * 128 + im * 16 + l15, lg + kk * 4));
#pragma unroll
    for (int in = 0; in < 2; ++in)
#pragma unroll
        for (int kk = 0; kk < 2; ++kk)
            b0[in][kk] = ds_frag(lds_byte(uB, wc * 64 + in * 16 + l15, lg + kk * 4));

    for (int t = 0; t < NT; ++t) {
        const int p = t & 1;
        const unsigned uAp = uA + p * 32768, uBp = uB + p * 32768;
        const unsigned uAn = uA + (p ^ 1) * 32768, uBn = uB + (p ^ 1) * 32768;

        // ---- PH1: read a1 | wait a0,b0 done | stage A(t+2,q0,q2->p) | MFMA Q1 = a0*b0
#pragma unroll
        for (int im = 0; im < 4; ++im)
#pragma unroll
            for (int kk = 0; kk < 2; ++kk)
                a1[im][kk] = ds_frag(lds_byte(uAp, wr * 128 + 64 + im * 16 + l15, lg + kk * 4));
        asm volatile("s_waitcnt lgkmcnt(8)" ::: "memory");   // a0,b0 complete; a1 outstanding
        __builtin_amdgcn_sched_barrier(0);
        __builtin_amdgcn_s_barrier();
        if (t + 2 < NT) { STAGE_A(t + 2, 0, p); STAGE_A(t + 2, 2, p); }
        __builtin_amdgcn_s_setprio(1);
#pragma unroll
        for (int kk = 0; kk < 2; ++kk)
#pragma unroll
            for (int im = 0; im < 4; ++im)
#pragma unroll
                for (int in = 0; in < 2; ++in)
                    acc[im][in] = __builtin_amdgcn_mfma_f32_16x16x32_bf16(a0[im][kk], b0[in][kk], acc[im][in], 0, 0, 0);
        __builtin_amdgcn_s_setprio(0);

        // ---- PH2: read b1 | wait a1 | stage A(t+2,q1,q3->p) | MFMA Q2 = a1*b0
#pragma unroll
        for (int in = 0; in < 2; ++in)
#pragma unroll
            for (int kk = 0; kk < 2; ++kk)
                b1[in][kk] = ds_frag(lds_byte(uBp, wc * 64 + 32 + in * 16 + l15, lg + kk * 4));
        asm volatile("s_waitcnt lgkmcnt(4)" ::: "memory");   // a1 complete; b1 outstanding
        __builtin_amdgcn_sched_barrier(0);
        __builtin_amdgcn_s_barrier();
        if (t + 2 < NT) { STAGE_A(t + 2, 1, p); STAGE_A(t + 2, 3, p); }
        __builtin_amdgcn_s_setprio(1);
#pragma unroll
        for (int kk = 0; kk < 2; ++kk)
#pragma unroll
            for (int im = 0; im < 4; ++im)
#pragma unroll
                for (int in = 0; in < 2; ++in)
                    acc[4 + im][in] = __builtin_amdgcn_mfma_f32_16x16x32_bf16(a1[im][kk], b0[in][kk], acc[4 + im][in], 0, 0, 0);
        __builtin_amdgcn_s_setprio(0);

        // ---- PH3: wait b1 | stage B(t+2,q0,q1->p) | MFMA Q3 = a0*b1
        asm volatile("s_waitcnt lgkmcnt(0)" ::: "memory");
        __builtin_amdgcn_sched_barrier(0);
        __builtin_amdgcn_s_barrier();
        if (t + 2 < NT) { STAGE_B(t + 2, 0, p); STAGE_B(t + 2, 1, p); }
        __builtin_amdgcn_s_setprio(1);
#pragma unroll
        for (int kk = 0; kk < 2; ++kk)
#pragma unroll
            for (int im = 0; im < 4; ++im)
#pragma unroll
                for (int in = 0; in < 2; ++in)
                    acc[im][2 + in] = __builtin_amdgcn_mfma_f32_16x16x32_bf16(a0[im][kk], b1[in][kk], acc[im][2 + in], 0, 0, 0);
        __builtin_amdgcn_s_setprio(0);

        // ---- PH4: vmcnt fence | barrier | stage B(t+2,q2,q3->p) | read a0,b0(t+1) | MFMA Q4 = a1*b1
        if (t + 1 < NT) {
            if (t + 2 < NT) asm volatile("s_waitcnt vmcnt(6)" ::: "memory");  // t+1 data landed
            else            asm volatile("s_waitcnt vmcnt(0)" ::: "memory");
            __builtin_amdgcn_sched_barrier(0);
        }
        __builtin_amdgcn_s_barrier();                  // cross-wave: t+1 staging visible
        if (t + 2 < NT) { STAGE_B(t + 2, 2, p); STAGE_B(t + 2, 3, p); }
        if (t + 1 < NT) {
#pragma unroll
            for (int im = 0; im < 4; ++im)
#pragma unroll
                for (int kk = 0; kk < 2; ++kk)
                    a0[im][kk] = ds_frag(lds_byte(uAn, wr * 128 + im * 16 + l15, lg + kk * 4));
#pragma unroll
            for (int in = 0; in < 2; ++in)
#pragma unroll
                for (int kk = 0; kk < 2; ++kk)
                    b0[in][kk] = ds_frag(lds_byte(uBn, wc * 64 + in * 16 + l15, lg + kk * 4));
        }
        __builtin_amdgcn_s_setprio(1);
#pragma unroll
        for (int kk = 0; kk < 2; ++kk)
#pragma unroll
            for (int im = 0; im < 4; ++im)
#pragma unroll
                for (int in = 0; in < 2; ++in)
                    acc[4 + im][2 + in] = __builtin_amdgcn_mfma_f32_16x16x32_bf16(a1[im][kk], b1[in][kk], acc[4 + im][2 + in], 0, 0, 0);
        __builtin_amdgcn_s_setprio(0);
    }
#undef STAGE_A
#undef STAGE_B

#pragma unroll
    for (int mi = 0; mi < 8; ++mi)
#pragma unroll
        for (int ni = 0; ni < 4; ++ni)
#pragma unroll
            for (int rr = 0; rr < 4; ++rr) {
                int row = brow + wr * 128 + mi * 16 + lg * 4 + rr;
                int col = bcol + wc * 64 + ni * 16 + l15;
                float v = acc[mi][ni][rr];
                if (EPI == 0) {
                    ((unsigned short*)Cv)[(size_t)row * ldc + col] = f2bf(v);
                } else if (EPI == 2) {
                    v += bias[col];
                    ((unsigned short*)Cv)[(size_t)row * ldc + col] = f2bf(gelu_tanh(v));
                } else {
                    ((unsigned short*)Cv)[slab_stride * split + (size_t)row * ldc + col] = f2bf(v);
                }
            }
}

// ---------- split-K reduce (final): out = sum(4 slabs) + bias + resid ----------
__global__ __launch_bounds__(256) void reduce4_kernel(const unsigned short* __restrict__ part,
                                                      const float* __restrict__ bias,
                                                      const float* __restrict__ resid,
                                                      float* __restrict__ out) {
    int i4 = blockIdx.x * 256 + threadIdx.x;
    float4 r  = ((const float4*)resid)[i4];
    float4 bb = ((const float4*)bias)[i4 & 255];
    float s0 = r.x + bb.x, s1 = r.y + bb.y, s2 = r.z + bb.z, s3 = r.w + bb.w;
#pragma unroll
    for (int s = 0; s < 4; ++s) {
        ushort4 u = ((const ushort4*)(part + (size_t)s * 4194304))[i4];
        s0 += __uint_as_float((unsigned)u.x << 16);
        s1 += __uint_as_float((unsigned)u.y << 16);
        s2 += __uint_as_float((unsigned)u.z << 16);
        s3 += __uint_as_float((unsigned)u.w << 16);
    }
    float4 o; o.x = s0; o.y = s1; o.z = s2; o.w = s3;
    ((float4*)out)[i4] = o;
}

// ---------- band attention v4: swapped QK^T, in-register P, 4 waves, 4 blocks/CU ----------
__global__ __launch_bounds__(256, 4) void attn4_kernel(const unsigned short* __restrict__ qkv, // [4096][3072]
                                                       const unsigned short* __restrict__ vt,  // [1024][4096]
                                                       const float* __restrict__ rel_emb,      // [258][16]
                                                       unsigned short* __restrict__ outp) {    // [4096][1024]
    const int lid = blockIdx.y * gridDim.x + blockIdx.x;      // 0..1023
    const int rid = (lid & 7) * 128 + (lid >> 3);             // XCD-contiguous
    const int h   = rid >> 6;
    const int n   = rid & 63;

    const int tid  = threadIdx.x;
    const int wv   = tid >> 6;         // 0..3
    const int lane = tid & 63;
    const int lg   = lane >> 4;
    const int l15  = lane & 15;
    const int iq   = wv * 16 + l15;
    const int q0   = n * 64 + wv * 16;

    __shared__ __align__(16) unsigned short sK[2][4096];
    __shared__ __align__(16) unsigned short sV[2][4096];
    __shared__ float sRelF[258];

    bf16x8 qf[2];
    {
        const unsigned short* qrow = qkv + (size_t)(q0 + l15) * 3072 + h * 64 + lg * 8;
        qf[0] = *(const bf16x8*)(qrow);
        qf[1] = *(const bf16x8*)(qrow + 32);
    }

    for (int i = tid; i < 258; i += 256) sRelF[i] = rel_emb[i * 16 + h];
    const float relC = rel_emb[257 * 16 + h];

    const int tlo = (n >= 15) ? 0 : (15 - n);
    {
        const int src = n - 15 + tlo;
#pragma unroll
        for (int s = 0; s < 2; ++s) {
            int r0 = wv * 16 + s * 8;
            stage8(qkv + (size_t)(src * 64 + r0) * 3072 + 1024 + h * 64, 3072, &sK[0][r0 * 64], lane);
            stage8(vt + (size_t)(h * 64 + r0) * 4096 + src * 64, 4096, &sV[0][r0 * 64], lane);
        }
    }
    asm volatile("s_waitcnt lgkmcnt(0)" ::: "memory");
    __builtin_amdgcn_s_barrier();

    f32x4 oacc[4] = {};
    float mrow = -3e38f, lrow = 0.f;

    for (int t = tlo; t < 16; ++t) {
        const int cur = (t - tlo) & 1;
        if (t < 15) {
            const int src = n - 15 + (t + 1);
#pragma unroll
            for (int s = 0; s < 2; ++s) {
                int r0 = wv * 16 + s * 8;
                stage8(qkv + (size_t)(src * 64 + r0) * 3072 + 1024 + h * 64, 3072, &sK[cur ^ 1][r0 * 64], lane);
                stage8(vt + (size_t)(h * 64 + r0) * 4096 + src * 64, 4096, &sV[cur ^ 1][r0 * 64], lane);
            }
            asm volatile("s_waitcnt vmcnt(4)" ::: "memory");
        } else {
            asm volatile("s_waitcnt vmcnt(0)" ::: "memory");
        }
        __builtin_amdgcn_s_barrier();

        const unsigned short* tK = &sK[cur][0];
        const unsigned short* tV = &sV[cur][0];
        const int woff = 15 - t;

        f32x4 st[4] = {};
        __builtin_amdgcn_s_setprio(1);
#pragma unroll
        for (int jt = 0; jt < 4; ++jt) {
            bf16x8 kf0 = ldfrag(tK, jt * 16 + l15, lg);
            bf16x8 kf1 = ldfrag(tK, jt * 16 + l15, lg + 4);
            st[jt] = __builtin_amdgcn_mfma_f32_16x16x32_bf16(kf0, qf[0], st[jt], 0, 0, 0);
            st[jt] = __builtin_amdgcn_mfma_f32_16x16x32_bf16(kf1, qf[1], st[jt], 0, 0, 0);
        }
        __builtin_amdgcn_s_setprio(0);

        float pm = -3e38f;
        if (woff >= 5) {
#pragma unroll
            for (int jt = 0; jt < 4; ++jt)
#pragma unroll
                for (int rr = 0; rr < 4; ++rr) {
                    float v = st[jt][rr] * 0.125f + relC;
                    st[jt][rr] = v;
                    pm = fmaxf(pm, v);
                }
        } else if (woff > 0) {
#pragma unroll
            for (int jt = 0; jt < 4; ++jt)
#pragma unroll
                for (int rr = 0; rr < 4; ++rr) {
                    int j = jt * 16 + lg * 4 + rr;
                    int relid = min(woff * 64 + iq - j, 256) + 1;
                    float v = st[jt][rr] * 0.125f + sRelF[relid];
                    st[jt][rr] = v;
                    pm = fmaxf(pm, v);
                }
        } else {
#pragma unroll
            for (int jt = 0; jt < 4; ++jt)
#pragma unroll
                for (int rr = 0; rr < 4; ++rr) {
                    int j = jt * 16 + lg * 4 + rr;
                    float v = (j <= iq) ? (st[jt][rr] * 0.125f + sRelF[iq - j + 1]) : -1e30f;
                    st[jt][rr] = v;
                    pm = fmaxf(pm, v);
                }
        }
        pm = fmaxf(pm, __shfl_xor(pm, 16));
        pm = fmaxf(pm, __shfl_xor(pm, 32));
        float mn  = fmaxf(mrow, pm);
        float scl = __expf(mrow - mn);
        mrow = mn;

        float rs = 0.f;
        unsigned pk0[4], pk1[4];
#pragma unroll
        for (int jt = 0; jt < 4; ++jt) {
            float p0 = __expf(st[jt][0] - mn);
            float p1 = __expf(st[jt][1] - mn);
            float p2 = __expf(st[jt][2] - mn);
            float p3 = __expf(st[jt][3] - mn);
            rs += (p0 + p1) + (p2 + p3);
            pk0[jt] = cvt_pk_bf16(p0, p1);
            pk1[jt] = cvt_pk_bf16(p2, p3);
        }
        rs += __shfl_xor(rs, 16);
        rs += __shfl_xor(rs, 32);
        lrow = lrow * scl + rs;
#pragma unroll
        for (int dt = 0; dt < 4; ++dt)
#pragma unroll
            for (int rr = 0; rr < 4; ++rr)
                oacc[dt][rr] *= scl;

        __builtin_amdgcn_s_setprio(1);
#pragma unroll
        for (int ks = 0; ks < 4; ++ks) {
            union { unsigned u[2]; s16x4 v; } pu;
            pu.u[0] = pk0[ks]; pu.u[1] = pk1[ks];
#pragma unroll
            for (int dt = 0; dt < 4; ++dt) {
                s16x4 vf = ldfrag64(tV, dt * 16 + l15, 2 * ks + (lg >> 1), lg & 1);
                oacc[dt] = mfma16(vf, pu.v, oacc[dt]);
            }
        }
        __builtin_amdgcn_s_setprio(0);
        __builtin_amdgcn_s_barrier();
    }

    float inv = 1.0f / lrow;
    unsigned short* sO = &sK[0][0] + wv * 1024;
#pragma unroll
    for (int dt = 0; dt < 4; ++dt)
#pragma unroll
        for (int c = 0; c < 2; ++c) {
            unsigned pr = cvt_pk_bf16(oacc[dt][2 * c] * inv, oacc[dt][2 * c + 1] * inv);
            int d  = dt * 16 + lg * 4 + 2 * c;
            int off = (l15 << 6) + ((((d >> 3) ^ (l15 & 7)) & 7) << 3) + (d & 7);
            *(unsigned*)(sO + off) = pr;
        }
#pragma unroll
    for (int c2 = 0; c2 < 2; ++c2) {
        int ch = lg + 4 * c2;
        bf16x8 ov = ldfrag(sO, l15, ch);
        *(s16x8*)(outp + (size_t)(q0 + l15) * 1024 + h * 64 + ch * 8) = *(const s16x8*)&ov;
    }
}

// ---------- launch ----------
extern "C" void kernel_launch(void* const* d_in, const int* in_sizes, int n_in,
                              void* d_out, int out_size, void* d_ws, size_t ws_size,
                              hipStream_t stream) {
    const float* x    = (const float*)d_in[0];
    const float* Wq   = (const float*)d_in[1];
    const float* Wk   = (const float*)d_in[2];
    const float* Wv   = (const float*)d_in[3];
    const float* Wo   = (const float*)d_in[4];
    const float* rel  = (const float*)d_in[5];
    const float* ln1g = (const float*)d_in[6];
    const float* ln1b = (const float*)d_in[7];
    const float* ln2g = (const float*)d_in[8];
    const float* ln2b = (const float*)d_in[9];
    const float* W1   = (const float*)d_in[10];
    const float* b1   = (const float*)d_in[11];
    const float* W2   = (const float*)d_in[12];
    const float* b2   = (const float*)d_in[13];

    char* ws = (char*)d_ws;
    unsigned short* wqkvT  = (unsigned short*)(ws + 0);          //  8 MB (Wq,Wk,Wv,Wo transposed)
    unsigned short* woT    = wqkvT + 3145728;
    unsigned short* attnb  = (unsigned short*)(ws + 8388608);    //  8 MB
    unsigned short* w1T    = (unsigned short*)(ws + 16777216);   //  8 MB
    unsigned short* hbuf   = (unsigned short*)(ws + 25165824);   //  8 MB
    unsigned short* w2T    = (unsigned short*)(ws + 33554432);   //  8 MB
    float*          x2     = (float*)(ws + 41943040);            // 16 MB
    unsigned short* qkv    = (unsigned short*)(ws + 58720256);   // 24 MB   [dead after attn]
    unsigned short* vt     = (unsigned short*)(ws + 83886080);   //  8 MB   [dead after attn]
    unsigned short* wopart = (unsigned short*)(ws + 58720256);   // 32 MB   (reuses qkv+vt)
    unsigned short* gbuf   = (unsigned short*)(ws + 58720256);   // 32 MB   (after Wo reduce)
    unsigned short* part   = (unsigned short*)(ws + 0);          // 32 MB   (reuses 0..32MB)

    const int smem = 131072;
    hipFuncSetAttribute((const void*)gemm256_kernel<0>, hipFuncAttributeMaxDynamicSharedMemorySize, smem);
    hipFuncSetAttribute((const void*)gemm256_kernel<2>, hipFuncAttributeMaxDynamicSharedMemorySize, smem);
    hipFuncSetAttribute((const void*)gemm256_kernel<4>, hipFuncAttributeMaxDynamicSharedMemorySize, smem);

    dim3 tb(32, 8);
    tcvt4_kernel<<<dim3(32, 32, 4), tb, 0, stream>>>(Wq, Wk, Wv, Wo, wqkvT);
    tcvt_kernel<<<dim3(128, 32), tb, 0, stream>>>(W1, w1T, 1024, 4096);
    tcvt_kernel<<<dim3(32, 128), tb, 0, stream>>>(W2, w2T, 4096, 1024);

    ln_kernel<<<4096, 256, 0, stream>>>(x, ln1g, ln1b, hbuf);

    // QKV: [4096,1024] x [3072,1024]^T -> qkv
    gemm256_kernel<0><<<192, 512, smem, stream>>>(hbuf, 1024, wqkvT, 1024, qkv,
                                                  nullptr, 3072, 16, 16, 12, 0ULL);

    tvt_kernel<<<dim3(64, 16), 256, 0, stream>>>(qkv, vt);

    attn4_kernel<<<dim3(64, 16), 256, 0, stream>>>(qkv, vt, rel, attnb);

    // Wo projection split-K=4: [4096,1024] x [1024,1024]^T -> 4 partial slabs
    gemm256_kernel<4><<<256, 512, smem, stream>>>(attnb, 1024, woT, 1024, wopart,
                                                  nullptr, 1024, 4, 16, 4, 4194304ULL);
    // fused: x2 = sum(slabs) + x ; hbuf = LN2(x2)
    reduceln_kernel<<<4096, 256, 0, stream>>>(wopart, x, ln2g, ln2b, x2, hbuf);

    // FFN1: [4096,1024] x [4096,1024]^T + b1, gelu -> gbuf
    gemm256_kernel<2><<<256, 512, smem, stream>>>(hbuf, 1024, w1T, 1024, gbuf,
                                                  b1, 4096, 16, 16, 16, 0ULL);

    // FFN2 split-K=4: [4096,4096] x [1024,4096]^T -> 4 bf16 partial slabs
    gemm256_kernel<4><<<256, 512, smem, stream>>>(gbuf, 4096, w2T, 4096, part,
                                                  nullptr, 1024, 16, 16, 4, 4194304ULL);

    // out = sum(slabs) + b2 + x2
    reduce4_kernel<<<4096, 256, 0, stream>>>(part, b2, x2, (float*)d_out);
}

// Round 10
// 220.359 us; speedup vs baseline: 1.5810x; 1.0313x over previous
//
#include <hip/hip_runtime.h>
#include <math.h>

// ---------- types ----------
typedef __bf16 bf16x8 __attribute__((ext_vector_type(8)));   // MFMA A/B fragment (4 VGPRs)
typedef short  s16x4  __attribute__((ext_vector_type(4)));   // 16x16x16 MFMA A/B fragment (2 VGPRs)
typedef float  f32x4  __attribute__((ext_vector_type(4)));   // MFMA C/D fragment
typedef short  s16x8  __attribute__((ext_vector_type(8)));   // raw 16B data movement

__device__ __forceinline__ unsigned short f2bf(float f) {
    unsigned int u = __float_as_uint(f);
    u += 0x7fffu + ((u >> 16) & 1u);   // round-to-nearest-even
    return (unsigned short)(u >> 16);
}

__device__ __forceinline__ unsigned cvt_pk_bf16(float a, float b) {
    unsigned r;
    asm volatile("v_cvt_pk_bf16_f32 %0, %1, %2" : "=v"(r) : "v"(a), "v"(b));
    return r;
}

// 16x16x16 bf16 MFMA via compiler-known builtin (MAI hazard nops inserted; R6 lesson)
__device__ __forceinline__ f32x4 mfma16(s16x4 a, s16x4 b, f32x4 c) {
#if __has_builtin(__builtin_amdgcn_mfma_f32_16x16x16bf16_1k)
    return __builtin_amdgcn_mfma_f32_16x16x16bf16_1k(a, b, c, 0, 0, 0);
#else
    asm volatile("s_nop 3\n\t"
                 "v_mfma_f32_16x16x16_bf16 %0, %1, %2, %0\n\t"
                 "s_nop 7\n\t"
                 "s_nop 7"
                 : "+v"(c) : "v"(a), "v"(b));
    return c;
#endif
}

// exact-equivalent sigmoid form of tanh-gelu: 0.5x(1+tanh(y)) = x * sigmoid(2y)
__device__ __forceinline__ float gelu_tanh(float x) {
    float z = 1.5957691216057308f * (x + 0.044715f * x * x * x);
    return x / (1.0f + __expf(-z));
}

// ---------- transpose + f32->bf16 convert (batched x4) ----------
__global__ __launch_bounds__(256) void tcvt4_kernel(const float* __restrict__ p0,
                                                    const float* __restrict__ p1,
                                                    const float* __restrict__ p2,
                                                    const float* __restrict__ p3,
                                                    unsigned short* __restrict__ out) {
    __shared__ float tile[32][33];
    int z = blockIdx.z;
    const float* in = (z == 0) ? p0 : (z == 1) ? p1 : (z == 2) ? p2 : p3;
    unsigned short* o = out + (size_t)z * 1048576;
    int tx = threadIdx.x, ty = threadIdx.y;           // 32 x 8
    int k0 = blockIdx.y * 32, n0 = blockIdx.x * 32;
#pragma unroll
    for (int s = 0; s < 4; ++s)
        tile[ty + s * 8][tx] = in[(size_t)(k0 + ty + s * 8) * 1024 + n0 + tx];
    __syncthreads();
#pragma unroll
    for (int s = 0; s < 4; ++s)
        o[(size_t)(n0 + ty + s * 8) * 1024 + k0 + tx] = f2bf(tile[tx][ty + s * 8]);
}

// ---------- transpose + convert, generic: in[K][N] f32 -> out[N][K] bf16 ----------
__global__ __launch_bounds__(256) void tcvt_kernel(const float* __restrict__ in,
                                                   unsigned short* __restrict__ out,
                                                   int K, int N) {
    __shared__ float tile[32][33];
    int tx = threadIdx.x, ty = threadIdx.y;
    int k0 = blockIdx.y * 32, n0 = blockIdx.x * 32;
#pragma unroll
    for (int s = 0; s < 4; ++s)
        tile[ty + s * 8][tx] = in[(size_t)(k0 + ty + s * 8) * N + n0 + tx];
    __syncthreads();
#pragma unroll
    for (int s = 0; s < 4; ++s)
        out[(size_t)(n0 + ty + s * 8) * K + k0 + tx] = f2bf(tile[tx][ty + s * 8]);
}

// ---------- layernorm: x[L][1024] f32 -> out bf16 ----------
__global__ __launch_bounds__(256) void ln_kernel(const float* __restrict__ x,
                                                 const float* __restrict__ g,
                                                 const float* __restrict__ b,
                                                 unsigned short* __restrict__ out) {
    int row = blockIdx.x;
    int tid = threadIdx.x;
    float4 v = ((const float4*)(x + (size_t)row * 1024))[tid];
    float s  = v.x + v.y + v.z + v.w;
    float ss = v.x * v.x + v.y * v.y + v.z * v.z + v.w * v.w;
#pragma unroll
    for (int o = 32; o > 0; o >>= 1) { s += __shfl_down(s, o); ss += __shfl_down(ss, o); }
    __shared__ float red[8];
    if ((tid & 63) == 0) { red[(tid >> 6) * 2] = s; red[(tid >> 6) * 2 + 1] = ss; }
    __syncthreads();
    s  = red[0] + red[2] + red[4] + red[6];
    ss = red[1] + red[3] + red[5] + red[7];
    float mean = s * (1.0f / 1024.0f);
    float var  = ss * (1.0f / 1024.0f) - mean * mean;
    float rs   = rsqrtf(var + 1e-5f);
    float4 gv = ((const float4*)g)[tid];
    float4 bv = ((const float4*)b)[tid];
    ushort4 o4;
    o4.x = f2bf((v.x - mean) * rs * gv.x + bv.x);
    o4.y = f2bf((v.y - mean) * rs * gv.y + bv.y);
    o4.z = f2bf((v.z - mean) * rs * gv.z + bv.z);
    o4.w = f2bf((v.w - mean) * rs * gv.w + bv.w);
    ((ushort4*)(out + (size_t)row * 1024))[tid] = o4;
}

// ---------- fused: x2 = sum(4 slabs)+x ;  hbuf = LN(x2) ----------
__global__ __launch_bounds__(256) void reduceln_kernel(const unsigned short* __restrict__ part,
                                                       const float* __restrict__ xin,
                                                       const float* __restrict__ g,
                                                       const float* __restrict__ b,
                                                       float* __restrict__ x2,
                                                       unsigned short* __restrict__ outbf) {
    int row = blockIdx.x;
    int tid = threadIdx.x;
    int i4  = row * 256 + tid;
    float4 r = ((const float4*)xin)[i4];
    float v0 = r.x, v1 = r.y, v2 = r.z, v3 = r.w;
#pragma unroll
    for (int sl = 0; sl < 4; ++sl) {
        ushort4 u = ((const ushort4*)(part + (size_t)sl * 4194304))[i4];
        v0 += __uint_as_float((unsigned)u.x << 16);
        v1 += __uint_as_float((unsigned)u.y << 16);
        v2 += __uint_as_float((unsigned)u.z << 16);
        v3 += __uint_as_float((unsigned)u.w << 16);
    }
    float4 o; o.x = v0; o.y = v1; o.z = v2; o.w = v3;
    ((float4*)x2)[i4] = o;

    float s  = v0 + v1 + v2 + v3;
    float ss = v0 * v0 + v1 * v1 + v2 * v2 + v3 * v3;
#pragma unroll
    for (int off = 32; off > 0; off >>= 1) { s += __shfl_down(s, off); ss += __shfl_down(ss, off); }
    __shared__ float red[8];
    if ((tid & 63) == 0) { red[(tid >> 6) * 2] = s; red[(tid >> 6) * 2 + 1] = ss; }
    __syncthreads();
    s  = red[0] + red[2] + red[4] + red[6];
    ss = red[1] + red[3] + red[5] + red[7];
    float mean = s * (1.0f / 1024.0f);
    float var  = ss * (1.0f / 1024.0f) - mean * mean;
    float rs   = rsqrtf(var + 1e-5f);
    float4 gv = ((const float4*)g)[tid];
    float4 bv = ((const float4*)b)[tid];
    ushort4 o4;
    o4.x = f2bf((v0 - mean) * rs * gv.x + bv.x);
    o4.y = f2bf((v1 - mean) * rs * gv.y + bv.y);
    o4.z = f2bf((v2 - mean) * rs * gv.z + bv.z);
    o4.w = f2bf((v3 - mean) * rs * gv.w + bv.w);
    ((ushort4*)(outbf + (size_t)row * 1024))[tid] = o4;
}

// ---------- transpose V (bf16): qkv v-part -> vt[1024][4096] ----------
__global__ __launch_bounds__(256) void tvt_kernel(const unsigned short* __restrict__ in,
                                                  unsigned short* __restrict__ out) {
    __shared__ unsigned short tile[64][72];
    int t = threadIdx.x;
    int l0 = blockIdx.x * 64, c0 = blockIdx.y * 64;
    int tr = t >> 3, tc = (t & 7) * 8;
#pragma unroll
    for (int s = 0; s < 2; ++s) {
        int r = tr + s * 32;
        s16x8 v = *(const s16x8*)(in + (size_t)(l0 + r) * 3072 + 2048 + c0 + tc);
        *(s16x8*)(&tile[r][tc]) = v;
    }
    __syncthreads();
#pragma unroll
    for (int s = 0; s < 2; ++s) {
        int c = tr + s * 32;
        s16x8 w;
#pragma unroll
        for (int e = 0; e < 8; ++e) w[e] = (short)tile[tc + e][c];
        *(s16x8*)(out + (size_t)(c0 + c) * 4096 + l0 + tc) = w;
    }
}

// ---------- shared staging helpers (chunk-XOR swizzle, rule 21) ----------
__device__ __forceinline__ void stage8(const unsigned short* __restrict__ src_row0, int ld,
                                       unsigned short* ldsdst, int lane) {
    const int r8 = lane >> 3;
    const int c  = (lane & 7) ^ r8;
    const unsigned short* src = src_row0 + (size_t)r8 * ld + c * 8;
    __builtin_amdgcn_global_load_lds((const __attribute__((address_space(1))) void*)src,
                                     (__attribute__((address_space(3))) void*)ldsdst, 16, 0, 0);
}

__device__ __forceinline__ void stage64(const unsigned short* __restrict__ mat, int ld,
                                        int grow0, int kcol,
                                        unsigned short* lds_tile, int q, int wave, int lane) {
    const int l8 = lane >> 3;
    const int sc = ((lane & 7) ^ l8) << 3;
    const unsigned short* src = mat + (size_t)(grow0 + q * 64 + wave * 8 + l8) * ld + kcol + sc;
    unsigned short* dst = lds_tile + ((q * 64 + wave * 8) << 6);
    __builtin_amdgcn_global_load_lds((const __attribute__((address_space(1))) void*)src,
                                     (__attribute__((address_space(3))) void*)dst, 16, 0, 0);
}

__device__ __forceinline__ bf16x8 ldfrag(const unsigned short* tile, int row, int chunk) {
    return *(const bf16x8*)(tile + (row << 6) + (((chunk ^ row) & 7) << 3));
}

__device__ __forceinline__ s16x4 ldfrag64(const unsigned short* tile, int row, int ch16, int half) {
    return *(const s16x4*)(tile + (row << 6) + (((ch16 ^ row) & 7) << 3) + (half << 2));
}

// ---- inline-asm ds_read (compiler-invisible: enables counted-lgkm pipelining) ----
__device__ __forceinline__ unsigned lds_byte(unsigned base, int row, int chunk) {
    return base + (row << 7) + (((chunk ^ row) & 7) << 4);
}
__device__ __forceinline__ bf16x8 ds_frag(unsigned addr) {
    bf16x8 r;
    asm volatile("ds_read_b128 %0, %1" : "=v"(r) : "v"(addr));
    return r;
}

// ---------- 256x256 pipelined-read 4-phase GEMM (T1..T5 + derived lgkm waits) ----------
// EPI 0: bf16 store; EPI 2: +bias, gelu, bf16; EPI 4: bf16 partial to slab[split]
template <int EPI>
__global__ __launch_bounds__(512, 2) void gemm256_kernel(
        const unsigned short* __restrict__ A, int lda,
        const unsigned short* __restrict__ Bt, int ldb,
        void* __restrict__ Cv, const float* __restrict__ bias,
        int ldc, int NT, int gm, int gn, unsigned long long slab_stride) {
    extern __shared__ unsigned short lds[];
    unsigned short* sA = lds;                  // [2][256*64]
    unsigned short* sB = lds + 2 * 256 * 64;   // [2][256*64]

    const int tid  = threadIdx.x;
    const int wave = tid >> 6, lane = tid & 63;
    const int wr = wave >> 2, wc = wave & 3;       // 2 x 4 wave grid
    const int lg = lane >> 4, l15 = lane & 15;

    const unsigned uA = (unsigned)(size_t)(__attribute__((address_space(3))) void*)sA;
    const unsigned uB = (unsigned)(size_t)(__attribute__((address_space(3))) void*)sB;

    // bijective XCD swizzle (m204)
    const int nwg = gridDim.x;
    const int bid = blockIdx.x;
    const int q8 = nwg >> 3, r8 = nwg & 7;
    const int xcd = bid & 7, loc = bid >> 3;
    const int swz = (xcd < r8 ? xcd * (q8 + 1) : r8 * (q8 + 1) + (xcd - r8) * q8) + loc;
    const int split = swz / (gm * gn);
    const int rem   = swz % (gm * gn);
    // 2D-banded mapping: 4-wide bcol bands
    const int band = rem / (gm * 4);
    const int r2   = rem % (gm * 4);
    const int brow = (r2 >> 2) << 8;
    const int bcol = (band * 4 + (r2 & 3)) << 8;
    const int kbase = split * (NT << 6);

    f32x4 acc[8][4] = {};
    bf16x8 a0[4][2], a1[4][2], b0[2][2], b1[2][2];

#define STAGE_A(tt, q_, pbuf) stage64(A, lda, brow, kbase + ((tt) << 6), sA + (pbuf) * 16384, (q_), wave, lane)
#define STAGE_B(tt, q_, pbuf) stage64(Bt, ldb, bcol, kbase + ((tt) << 6), sB + (pbuf) * 16384, (q_), wave, lane)

    // prologue: stage t0 -> buf0 (8), t1 -> buf1 (8); wait t0; read a0,b0(t0)
    STAGE_A(0, 0, 0); STAGE_A(0, 1, 0); STAGE_A(0, 2, 0); STAGE_A(0, 3, 0);
    STAGE_B(0, 0, 0); STAGE_B(0, 1, 0); STAGE_B(0, 2, 0); STAGE_B(0, 3, 0);
    STAGE_A(1, 0, 1); STAGE_A(1, 1, 1); STAGE_A(1, 2, 1); STAGE_A(1, 3, 1);
    STAGE_B(1, 0, 1); STAGE_B(1, 1, 1); STAGE_B(1, 2, 1); STAGE_B(1, 3, 1);
    asm volatile("s_waitcnt vmcnt(8)" ::: "memory");   // t0 landed (t1 in flight)
    __builtin_amdgcn_sched_barrier(0);
    __builtin_amdgcn_s_barrier();                      // cross-wave: t0 visible
#pragma unroll
    for (int im = 0; im < 4; ++im)
#pragma unroll
        for (int kk = 0; kk < 2; ++kk)
            a0[im][kk] = ds_frag(lds_byte(uA, wr * 128 + im * 16 + l15, lg + kk * 4));
#pragma unroll
    for (int in = 0; in < 2; ++in)
#pragma unroll
        for (int kk = 0; kk < 2; ++kk)
            b0[in][kk] = ds_frag(lds_byte(uB, wc * 64 + in * 16 + l15, lg + kk * 4));

    for (int t = 0; t < NT; ++t) {
        const int p = t & 1;
        const unsigned uAp = uA + p * 32768, uBp = uB + p * 32768;
        const unsigned uAn = uA + (p ^ 1) * 32768, uBn = uB + (p ^ 1) * 32768;

        // ---- PH1: read a1 | wait a0,b0 done | stage A(t+2,q0,q2->p) | MFMA Q1 = a0*b0
#pragma unroll
        for (int im = 0; im < 4; ++im)
#pragma unroll
            for (int kk = 0; kk < 2; ++kk)
                a1[im][kk] = ds_frag(lds_byte(uAp, wr * 128 + 64 + im * 16 + l15, lg + kk * 4));
        asm volatile("s_waitcnt lgkmcnt(8)" ::: "memory");   // a0,b0 complete; a1 outstanding
        __builtin_amdgcn_sched_barrier(0);
        __builtin_amdgcn_s_barrier();
        if (t + 2 < NT) { STAGE_A(t + 2, 0, p); STAGE_A(t + 2, 2, p); }
        __builtin_amdgcn_s_setprio(1);
#pragma unroll
        for (int kk = 0; kk < 2; ++kk)
#pragma unroll
            for (int im = 0; im < 4; ++im)
#pragma unroll
                for (int in = 0; in < 2; ++in)
                    acc[im][in] = __builtin_amdgcn_mfma_f32_16x16x32_bf16(a0[im][kk], b0[in][kk], acc[im][in], 0, 0, 0);
        __builtin_amdgcn_s_setprio(0);

        // ---- PH2: read b1 | wait a1 | stage A(t+2,q1,q3->p) | MFMA Q2 = a1*b0
#pragma unroll
        for (int in = 0; in < 2; ++in)
#pragma unroll
            for (int kk = 0; kk < 2; ++kk)
                b1[in][kk] = ds_frag(lds_byte(uBp, wc * 64 + 32 + in * 16 + l15, lg + kk * 4));
        asm volatile("s_waitcnt lgkmcnt(4)" ::: "memory");   // a1 complete; b1 outstanding
        __builtin_amdgcn_sched_barrier(0);
        __builtin_amdgcn_s_barrier();
        if (t + 2 < NT) { STAGE_A(t + 2, 1, p); STAGE_A(t + 2, 3, p); }
        __builtin_amdgcn_s_setprio(1);
#pragma unroll
        for (int kk = 0; kk < 2; ++kk)
#pragma unroll
            for (int im = 0; im < 4; ++im)
#pragma unroll
                for (int in = 0; in < 2; ++in)
                    acc[4 + im][in] = __builtin_amdgcn_mfma_f32_16x16x32_bf16(a1[im][kk], b0[in][kk], acc[4 + im][in], 0, 0, 0);
        __builtin_amdgcn_s_setprio(0);

        // ---- PH3: wait b1 | stage B(t+2,q0,q1->p) | MFMA Q3 = a0*b1
        asm volatile("s_waitcnt lgkmcnt(0)" ::: "memory");
        __builtin_amdgcn_sched_barrier(0);
        __builtin_amdgcn_s_barrier();
        if (t + 2 < NT) { STAGE_B(t + 2, 0, p); STAGE_B(t + 2, 1, p); }
        __builtin_amdgcn_s_setprio(1);
#pragma unroll
        for (int kk = 0; kk < 2; ++kk)
#pragma unroll
            for (int im = 0; im < 4; ++im)
#pragma unroll
                for (int in = 0; in < 2; ++in)
                    acc[im][2 + in] = __builtin_amdgcn_mfma_f32_16x16x32_bf16(a0[im][kk], b1[in][kk], acc[im][2 + in], 0, 0, 0);
        __builtin_amdgcn_s_setprio(0);

        // ---- PH4: vmcnt fence | barrier | stage B(t+2,q2,q3->p) | read a0,b0(t+1) | MFMA Q4 = a1*b1
        if (t + 1 < NT) {
            if (t + 2 < NT) asm volatile("s_waitcnt vmcnt(6)" ::: "memory");  // t+1 data landed
            else            asm volatile("s_waitcnt vmcnt(0)" ::: "memory");
            __builtin_amdgcn_sched_barrier(0);
        }
        __builtin_amdgcn_s_barrier();                  // cross-wave: t+1 staging visible
        if (t + 2 < NT) { STAGE_B(t + 2, 2, p); STAGE_B(t + 2, 3, p); }
        if (t + 1 < NT) {
#pragma unroll
            for (int im = 0; im < 4; ++im)
#pragma unroll
                for (int kk = 0; kk < 2; ++kk)
                    a0[im][kk] = ds_frag(lds_byte(uAn, wr * 128 + im * 16 + l15, lg + kk * 4));
#pragma unroll
            for (int in = 0; in < 2; ++in)
#pragma unroll
                for (int kk = 0; kk < 2; ++kk)
                    b0[in][kk] = ds_frag(lds_byte(uBn, wc * 64 + in * 16 + l15, lg + kk * 4));
        }
        __builtin_amdgcn_s_setprio(1);
#pragma unroll
        for (int kk = 0; kk < 2; ++kk)
#pragma unroll
            for (int im = 0; im < 4; ++im)
#pragma unroll
                for (int in = 0; in < 2; ++in)
                    acc[4 + im][2 + in] = __builtin_amdgcn_mfma_f32_16x16x32_bf16(a1[im][kk], b1[in][kk], acc[4 + im][2 + in], 0, 0, 0);
        __builtin_amdgcn_s_setprio(0);
    }
#undef STAGE_A
#undef STAGE_B

#pragma unroll
    for (int mi = 0; mi < 8; ++mi)
#pragma unroll
        for (int ni = 0; ni < 4; ++ni)
#pragma unroll
            for (int rr = 0; rr < 4; ++rr) {
                int row = brow + wr * 128 + mi * 16 + lg * 4 + rr;
                int col = bcol + wc * 64 + ni * 16 + l15;
                float v = acc[mi][ni][rr];
                if (EPI == 0) {
                    ((unsigned short*)Cv)[(size_t)row * ldc + col] = f2bf(v);
                } else if (EPI == 2) {
                    v += bias[col];
                    ((unsigned short*)Cv)[(size_t)row * ldc + col] = f2bf(gelu_tanh(v));
                } else {
                    ((unsigned short*)Cv)[slab_stride * split + (size_t)row * ldc + col] = f2bf(v);
                }
            }
}

// ---------- split-K reduce (final): out = sum(4 slabs) + bias + resid ----------
__global__ __launch_bounds__(256) void reduce4_kernel(const unsigned short* __restrict__ part,
                                                      const float* __restrict__ bias,
                                                      const float* __restrict__ resid,
                                                      float* __restrict__ out) {
    int i4 = blockIdx.x * 256 + threadIdx.x;
    float4 r  = ((const float4*)resid)[i4];
    float4 bb = ((const float4*)bias)[i4 & 255];
    float s0 = r.x + bb.x, s1 = r.y + bb.y, s2 = r.z + bb.z, s3 = r.w + bb.w;
#pragma unroll
    for (int s = 0; s < 4; ++s) {
        ushort4 u = ((const ushort4*)(part + (size_t)s * 4194304))[i4];
        s0 += __uint_as_float((unsigned)u.x << 16);
        s1 += __uint_as_float((unsigned)u.y << 16);
        s2 += __uint_as_float((unsigned)u.z << 16);
        s3 += __uint_as_float((unsigned)u.w << 16);
    }
    float4 o; o.x = s0; o.y = s1; o.z = s2; o.w = s3;
    ((float4*)out)[i4] = o;
}

// ---------- band attention v5: no-max softmax (scores bounded), deferred row-sum ----------
// grid 1024 (64 q-blocks x 16 heads), 256 threads (4 waves), 4 blocks/CU.
// softmax without max-subtraction is exact here: |score| = |q.k|*0.125 + |bias| < ~8,
// so exp() cannot overflow; the max-shift cancels in P/sum(P). Removes the per-tile
// max-reduce + rescale serial chain entirely; one shfl-pair reduction at the end.
__global__ __launch_bounds__(256, 4) void attn5_kernel(const unsigned short* __restrict__ qkv, // [4096][3072]
                                                       const unsigned short* __restrict__ vt,  // [1024][4096]
                                                       const float* __restrict__ rel_emb,      // [258][16]
                                                       unsigned short* __restrict__ outp) {    // [4096][1024]
    const int lid = blockIdx.y * gridDim.x + blockIdx.x;      // 0..1023
    const int rid = (lid & 7) * 128 + (lid >> 3);             // XCD-contiguous
    const int h   = rid >> 6;
    const int n   = rid & 63;

    const int tid  = threadIdx.x;
    const int wv   = tid >> 6;         // 0..3
    const int lane = tid & 63;
    const int lg   = lane >> 4;
    const int l15  = lane & 15;
    const int iq   = wv * 16 + l15;
    const int q0   = n * 64 + wv * 16;

    __shared__ __align__(16) unsigned short sK[2][4096];
    __shared__ __align__(16) unsigned short sV[2][4096];
    __shared__ float sRelF[258];

    bf16x8 qf[2];
    {
        const unsigned short* qrow = qkv + (size_t)(q0 + l15) * 3072 + h * 64 + lg * 8;
        qf[0] = *(const bf16x8*)(qrow);
        qf[1] = *(const bf16x8*)(qrow + 32);
    }

    for (int i = tid; i < 258; i += 256) sRelF[i] = rel_emb[i * 16 + h];
    const float relC = rel_emb[257 * 16 + h];

    const int tlo = (n >= 15) ? 0 : (15 - n);
    {
        const int src = n - 15 + tlo;
#pragma unroll
        for (int s = 0; s < 2; ++s) {
            int r0 = wv * 16 + s * 8;
            stage8(qkv + (size_t)(src * 64 + r0) * 3072 + 1024 + h * 64, 3072, &sK[0][r0 * 64], lane);
            stage8(vt + (size_t)(h * 64 + r0) * 4096 + src * 64, 4096, &sV[0][r0 * 64], lane);
        }
    }
    asm volatile("s_waitcnt lgkmcnt(0)" ::: "memory");
    __builtin_amdgcn_s_barrier();

    f32x4 oacc[4] = {};                 // O^T (unnormalized): d = dt*16+lg*4+rr, i = l15
    float rsum = 0.f;                   // per-lane partial of sum_j exp(score)

    for (int t = tlo; t < 16; ++t) {
        const int cur = (t - tlo) & 1;
        if (t < 15) {
            const int src = n - 15 + (t + 1);
#pragma unroll
            for (int s = 0; s < 2; ++s) {
                int r0 = wv * 16 + s * 8;
                stage8(qkv + (size_t)(src * 64 + r0) * 3072 + 1024 + h * 64, 3072, &sK[cur ^ 1][r0 * 64], lane);
                stage8(vt + (size_t)(h * 64 + r0) * 4096 + src * 64, 4096, &sV[cur ^ 1][r0 * 64], lane);
            }
            asm volatile("s_waitcnt vmcnt(4)" ::: "memory");
        } else {
            asm volatile("s_waitcnt vmcnt(0)" ::: "memory");
        }
        __builtin_amdgcn_s_barrier();

        const unsigned short* tK = &sK[cur][0];
        const unsigned short* tV = &sV[cur][0];
        const int woff = 15 - t;

        // ---- S^T = K.Q^T : C[j][i], 8 MFMA; lane: j = jt*16+lg*4+rr, i = l15
        f32x4 st[4] = {};
        __builtin_amdgcn_s_setprio(1);
#pragma unroll
        for (int jt = 0; jt < 4; ++jt) {
            bf16x8 kf0 = ldfrag(tK, jt * 16 + l15, lg);
            bf16x8 kf1 = ldfrag(tK, jt * 16 + l15, lg + 4);
            st[jt] = __builtin_amdgcn_mfma_f32_16x16x32_bf16(kf0, qf[0], st[jt], 0, 0, 0);
            st[jt] = __builtin_amdgcn_mfma_f32_16x16x32_bf16(kf1, qf[1], st[jt], 0, 0, 0);
        }
        __builtin_amdgcn_s_setprio(0);

        // ---- bias + exp (no max-subtraction), pack into PV B-fragments
        unsigned pk0[4], pk1[4];
        if (woff >= 5) {
#pragma unroll
            for (int jt = 0; jt < 4; ++jt) {
                float p0 = __expf(st[jt][0] * 0.125f + relC);
                float p1 = __expf(st[jt][1] * 0.125f + relC);
                float p2 = __expf(st[jt][2] * 0.125f + relC);
                float p3 = __expf(st[jt][3] * 0.125f + relC);
                rsum += (p0 + p1) + (p2 + p3);
                pk0[jt] = cvt_pk_bf16(p0, p1);
                pk1[jt] = cvt_pk_bf16(p2, p3);
            }
        } else if (woff > 0) {
#pragma unroll
            for (int jt = 0; jt < 4; ++jt) {
                float p[4];
#pragma unroll
                for (int rr = 0; rr < 4; ++rr) {
                    int j = jt * 16 + lg * 4 + rr;
                    int relid = min(woff * 64 + iq - j, 256) + 1;
                    p[rr] = __expf(st[jt][rr] * 0.125f + sRelF[relid]);
                    rsum += p[rr];
                }
                pk0[jt] = cvt_pk_bf16(p[0], p[1]);
                pk1[jt] = cvt_pk_bf16(p[2], p[3]);
            }
        } else {
#pragma unroll
            for (int jt = 0; jt < 4; ++jt) {
                float p[4];
#pragma unroll
                for (int rr = 0; rr < 4; ++rr) {
                    int j = jt * 16 + lg * 4 + rr;
                    p[rr] = (j <= iq) ? __expf(st[jt][rr] * 0.125f + sRelF[iq - j + 1]) : 0.0f;
                    rsum += p[rr];
                }
                pk0[jt] = cvt_pk_bf16(p[0], p[1]);
                pk1[jt] = cvt_pk_bf16(p[2], p[3]);
            }
        }

        // ---- O^T += V^T.P^T : 16 x mfma 16x16x16 (P stays in registers)
        __builtin_amdgcn_s_setprio(1);
#pragma unroll
        for (int ks = 0; ks < 4; ++ks) {
            union { unsigned u[2]; s16x4 v; } pu;
            pu.u[0] = pk0[ks]; pu.u[1] = pk1[ks];
#pragma unroll
            for (int dt = 0; dt < 4; ++dt) {
                s16x4 vf = ldfrag64(tV, dt * 16 + l15, 2 * ks + (lg >> 1), lg & 1);
                oacc[dt] = mfma16(vf, pu.v, oacc[dt]);
            }
        }
        __builtin_amdgcn_s_setprio(0);
        __builtin_amdgcn_s_barrier();              // buf[cur] reads done before overwrite
    }

    // ---- single end-of-loop row-sum reduction (lanes sharing l15)
    rsum += __shfl_xor(rsum, 16);
    rsum += __shfl_xor(rsum, 32);
    float inv = 1.0f / rsum;

    // ---- epilogue: normalize, transpose via (dead) sK, coalesced store
    unsigned short* sO = &sK[0][0] + wv * 1024;
#pragma unroll
    for (int dt = 0; dt < 4; ++dt)
#pragma unroll
        for (int c = 0; c < 2; ++c) {
            unsigned pr = cvt_pk_bf16(oacc[dt][2 * c] * inv, oacc[dt][2 * c + 1] * inv);
            int d  = dt * 16 + lg * 4 + 2 * c;
            int off = (l15 << 6) + ((((d >> 3) ^ (l15 & 7)) & 7) << 3) + (d & 7);
            *(unsigned*)(sO + off) = pr;
        }
#pragma unroll
    for (int c2 = 0; c2 < 2; ++c2) {
        int ch = lg + 4 * c2;
        bf16x8 ov = ldfrag(sO, l15, ch);
        *(s16x8*)(outp + (size_t)(q0 + l15) * 1024 + h * 64 + ch * 8) = *(const s16x8*)&ov;
    }
}

// ---------- launch ----------
extern "C" void kernel_launch(void* const* d_in, const int* in_sizes, int n_in,
                              void* d_out, int out_size, void* d_ws, size_t ws_size,
                              hipStream_t stream) {
    const float* x    = (const float*)d_in[0];
    const float* Wq   = (const float*)d_in[1];
    const float* Wk   = (const float*)d_in[2];
    const float* Wv   = (const float*)d_in[3];
    const float* Wo   = (const float*)d_in[4];
    const float* rel  = (const float*)d_in[5];
    const float* ln1g = (const float*)d_in[6];
    const float* ln1b = (const float*)d_in[7];
    const float* ln2g = (const float*)d_in[8];
    const float* ln2b = (const float*)d_in[9];
    const float* W1   = (const float*)d_in[10];
    const float* b1   = (const float*)d_in[11];
    const float* W2   = (const float*)d_in[12];
    const float* b2   = (const float*)d_in[13];

    char* ws = (char*)d_ws;
    unsigned short* wqkvT  = (unsigned short*)(ws + 0);          //  8 MB (Wq,Wk,Wv,Wo transposed)
    unsigned short* woT    = wqkvT + 3145728;
    unsigned short* attnb  = (unsigned short*)(ws + 8388608);    //  8 MB
    unsigned short* w1T    = (unsigned short*)(ws + 16777216);   //  8 MB
    unsigned short* hbuf   = (unsigned short*)(ws + 25165824);   //  8 MB
    unsigned short* w2T    = (unsigned short*)(ws + 33554432);   //  8 MB
    float*          x2     = (float*)(ws + 41943040);            // 16 MB
    unsigned short* qkv    = (unsigned short*)(ws + 58720256);   // 24 MB   [dead after attn]
    unsigned short* vt     = (unsigned short*)(ws + 83886080);   //  8 MB   [dead after attn]
    unsigned short* wopart = (unsigned short*)(ws + 58720256);   // 32 MB   (reuses qkv+vt)
    unsigned short* gbuf   = (unsigned short*)(ws + 58720256);   // 32 MB   (after Wo reduce)
    unsigned short* part   = (unsigned short*)(ws + 0);          // 32 MB   (reuses 0..32MB)

    const int smem = 131072;
    hipFuncSetAttribute((const void*)gemm256_kernel<0>, hipFuncAttributeMaxDynamicSharedMemorySize, smem);
    hipFuncSetAttribute((const void*)gemm256_kernel<2>, hipFuncAttributeMaxDynamicSharedMemorySize, smem);
    hipFuncSetAttribute((const void*)gemm256_kernel<4>, hipFuncAttributeMaxDynamicSharedMemorySize, smem);

    dim3 tb(32, 8);
    tcvt4_kernel<<<dim3(32, 32, 4), tb, 0, stream>>>(Wq, Wk, Wv, Wo, wqkvT);
    tcvt_kernel<<<dim3(128, 32), tb, 0, stream>>>(W1, w1T, 1024, 4096);
    tcvt_kernel<<<dim3(32, 128), tb, 0, stream>>>(W2, w2T, 4096, 1024);

    ln_kernel<<<4096, 256, 0, stream>>>(x, ln1g, ln1b, hbuf);

    // QKV: [4096,1024] x [3072,1024]^T -> qkv
    gemm256_kernel<0><<<192, 512, smem, stream>>>(hbuf, 1024, wqkvT, 1024, qkv,
                                                  nullptr, 3072, 16, 16, 12, 0ULL);

    tvt_kernel<<<dim3(64, 16), 256, 0, stream>>>(qkv, vt);

    attn5_kernel<<<dim3(64, 16), 256, 0, stream>>>(qkv, vt, rel, attnb);

    // Wo projection split-K=4: [4096,1024] x [1024,1024]^T -> 4 partial slabs
    gemm256_kernel<4><<<256, 512, smem, stream>>>(attnb, 1024, woT, 1024, wopart,
                                                  nullptr, 1024, 4, 16, 4, 4194304ULL);
    // fused: x2 = sum(slabs) + x ; hbuf = LN2(x2)
    reduceln_kernel<<<4096, 256, 0, stream>>>(wopart, x, ln2g, ln2b, x2, hbuf);

    // FFN1: [4096,1024] x [4096,1024]^T + b1, gelu -> gbuf
    gemm256_kernel<2><<<256, 512, smem, stream>>>(hbuf, 1024, w1T, 1024, gbuf,
                                                  b1, 4096, 16, 16, 16, 0ULL);

    // FFN2 split-K=4: [4096,4096] x [1024,4096]^T -> 4 bf16 partial slabs
    gemm256_kernel<4><<<256, 512, smem, stream>>>(gbuf, 4096, w2T, 4096, part,
                                                  nullptr, 1024, 16, 16, 4, 4194304ULL);

    // out = sum(slabs) + b2 + x2
    reduce4_kernel<<<4096, 256, 0, stream>>>(part, b2, x2, (float*)d_out);
}